// Round 1
// baseline (1181.553 us; speedup 1.0000x reference)
//
#include <hip/hip_runtime.h>
#include <math.h>

#define N_NODES 100000
#define N_EDGES 1600000
#define NEG_SLOPE 0.2f

__device__ __forceinline__ float lrelu(float x) { return x > 0.f ? x : NEG_SLOPE * x; }
__device__ __forceinline__ float eluf(float x)  { return x > 0.f ? x : expm1f(x); }

__device__ __forceinline__ float wred_max(float v) {
#pragma unroll
  for (int i = 1; i < 64; i <<= 1) v = fmaxf(v, __shfl_xor(v, i, 64));
  return v;
}
__device__ __forceinline__ float wred_sum(float v) {
#pragma unroll
  for (int i = 1; i < 64; i <<= 1) v += __shfl_xor(v, i, 64);
  return v;
}

// ---------------- CSR build (by dst) ----------------
__global__ void count_kernel(const int* __restrict__ dst, int* __restrict__ deg) {
  int e = blockIdx.x * 256 + threadIdx.x;
  if (e < N_EDGES) atomicAdd(&deg[dst[e]], 1);
}

__global__ __launch_bounds__(1024) void scan_kernel(const int* __restrict__ deg,
                                                    int* __restrict__ rowstart) {
  __shared__ int sums[1024];
  int t = threadIdx.x;
  const int chunk = (N_NODES + 1023) / 1024;  // 98
  int s = t * chunk, e = min(s + chunk, N_NODES);
  int acc = 0;
  for (int i = s; i < e; i++) acc += deg[i];
  sums[t] = acc;
  __syncthreads();
  for (int off = 1; off < 1024; off <<= 1) {
    int v = (t >= off) ? sums[t - off] : 0;
    __syncthreads();
    sums[t] += v;
    __syncthreads();
  }
  int run = sums[t] - acc;  // exclusive prefix for this chunk
  for (int i = s; i < e; i++) { rowstart[i] = run; run += deg[i]; }
  if (t == 1023) rowstart[N_NODES] = sums[1023];
}

__global__ void scatter_kernel(const int* __restrict__ src, const int* __restrict__ dst,
                               const int* __restrict__ rowstart, int* __restrict__ cursor,
                               int* __restrict__ csr_src) {
  int e = blockIdx.x * 256 + threadIdx.x;
  if (e < N_EDGES) {
    int d = dst[e];
    int pos = rowstart[d] + atomicAdd(&cursor[d], 1);
    csr_src[pos] = src[e];
  }
}

// ---------------- GEMM: C[N,128] = A[N,128] @ W[128,128] ----------------
// block 256 threads, 64 rows/block. W (64KB) + A-tile (33KB) in LDS.
__global__ __launch_bounds__(256) void gemm128(const float* __restrict__ A,
                                               const float* __restrict__ W,
                                               float* __restrict__ C, int N) {
  __shared__ float Ws[128 * 128];
  __shared__ float As[64 * 132];  // pad 128->132 floats: A-reads 2-way-free banks
  int tid = threadIdx.x;
  int rowBase = blockIdx.x * 64;

  const float4* W4 = (const float4*)W;
  float4* Ws4 = (float4*)Ws;
#pragma unroll
  for (int i = 0; i < 16; i++) Ws4[tid + 256 * i] = W4[tid + 256 * i];

#pragma unroll
  for (int j = 0; j < 8; j++) {
    int v = tid + 256 * j;
    int r = v >> 5, c4 = v & 31;
    int gr = rowBase + r;
    float4 val = (gr < N) ? ((const float4*)A)[gr * 32 + c4] : make_float4(0.f, 0.f, 0.f, 0.f);
    *(float4*)&As[r * 132 + c4 * 4] = val;
  }
  __syncthreads();

  int rg = tid >> 4, cg = tid & 15;  // rows rg+16i (i<4), cols cg*8..cg*8+7
  float acc[4][8] = {};
#pragma unroll 4
  for (int k = 0; k < 128; k++) {
    float a[4];
#pragma unroll
    for (int i = 0; i < 4; i++) a[i] = As[(rg + 16 * i) * 132 + k];
    float4 w0 = *(const float4*)&Ws[k * 128 + cg * 8];
    float4 w1 = *(const float4*)&Ws[k * 128 + cg * 8 + 4];
    float w[8] = {w0.x, w0.y, w0.z, w0.w, w1.x, w1.y, w1.z, w1.w};
#pragma unroll
    for (int i = 0; i < 4; i++)
#pragma unroll
      for (int j = 0; j < 8; j++) acc[i][j] = fmaf(a[i], w[j], acc[i][j]);
  }
#pragma unroll
  for (int i = 0; i < 4; i++) {
    int r = rowBase + rg + 16 * i;
    if (r < N) {
      float4 o0 = make_float4(acc[i][0], acc[i][1], acc[i][2], acc[i][3]);
      float4 o1 = make_float4(acc[i][4], acc[i][5], acc[i][6], acc[i][7]);
      *(float4*)&C[r * 128 + cg * 8] = o0;
      *(float4*)&C[r * 128 + cg * 8 + 4] = o1;
    }
  }
}

// ---------------- el/er: [N,4] attention dots ----------------
// 16 lanes per node; lane covers 8 features.
__global__ __launch_bounds__(256) void elr_kernel(const float* __restrict__ h,
                                                  const float* __restrict__ al,
                                                  const float* __restrict__ ar,
                                                  float* __restrict__ el, float* __restrict__ er) {
  __shared__ float als[128], ars[128];
  if (threadIdx.x < 128) { als[threadIdx.x] = al[threadIdx.x]; ars[threadIdx.x] = ar[threadIdx.x]; }
  __syncthreads();
  int g = blockIdx.x * 256 + threadIdx.x;
  int node = g >> 4;
  int l = g & 15;
  if (node >= N_NODES) return;
  int f = l * 8;
  float4 h0 = *(const float4*)&h[node * 128 + f];
  float4 h1 = *(const float4*)&h[node * 128 + f + 4];
  float hv[8] = {h0.x, h0.y, h0.z, h0.w, h1.x, h1.y, h1.z, h1.w};
  float pel = 0.f, per = 0.f;
#pragma unroll
  for (int j = 0; j < 8; j++) {
    pel = fmaf(hv[j], als[f + j], pel);
    per = fmaf(hv[j], ars[f + j], per);
  }
  // reduce across the 4 lanes of each head (head = l/4)
  pel += __shfl_xor(pel, 1, 64); pel += __shfl_xor(pel, 2, 64);
  per += __shfl_xor(per, 1, 64); per += __shfl_xor(per, 2, 64);
  if ((l & 3) == 0) {
    int hd = l >> 2;
    el[node * 4 + hd] = pel;
    er[node * 4 + hd] = per;
  }
}

// ---------------- aggregation: one 64-lane wave per node ----------------
// softmax over incoming edges + weighted sum of h[src], + bias, + ELU
__global__ __launch_bounds__(256) void aggregate(const float* __restrict__ h,
                                                 const float* __restrict__ el,
                                                 const float* __restrict__ er,
                                                 const int* __restrict__ rowstart,
                                                 const int* __restrict__ csr_src,
                                                 const float* __restrict__ bias,
                                                 float* __restrict__ out) {
  int wid = (blockIdx.x * 256 + threadIdx.x) >> 6;  // node
  int lane = threadIdx.x & 63;
  if (wid >= N_NODES) return;
  int n = wid;
  int base = rowstart[n];
  int deg = rowstart[n + 1] - base;
  int f0 = lane * 2;
  float acc0 = 0.f, acc1 = 0.f;

  if (deg > 0) {
    float4 erv = *(const float4*)&er[n * 4];
    float m0 = -INFINITY, m1 = -INFINITY, m2 = -INFINITY, m3 = -INFINITY;
    float l0 = 0.f, l1 = 0.f, l2 = 0.f, l3 = 0.f;

    for (int c0 = 0; c0 < deg; c0 += 64) {
      int e = c0 + lane;
      bool act = e < deg;
      int s = act ? csr_src[base + e] : 0;
      float sc0 = -INFINITY, sc1 = -INFINITY, sc2 = -INFINITY, sc3 = -INFINITY;
      if (act) {
        float4 elv = *(const float4*)&el[s * 4];
        sc0 = lrelu(elv.x + erv.x); sc1 = lrelu(elv.y + erv.y);
        sc2 = lrelu(elv.z + erv.z); sc3 = lrelu(elv.w + erv.w);
      }
      float nm0 = fmaxf(m0, wred_max(sc0));
      float nm1 = fmaxf(m1, wred_max(sc1));
      float nm2 = fmaxf(m2, wred_max(sc2));
      float nm3 = fmaxf(m3, wred_max(sc3));
      float p0 = act ? __expf(sc0 - nm0) : 0.f;
      float p1 = act ? __expf(sc1 - nm1) : 0.f;
      float p2 = act ? __expf(sc2 - nm2) : 0.f;
      float p3 = act ? __expf(sc3 - nm3) : 0.f;
      float cs0 = wred_sum(p0), cs1 = wred_sum(p1), cs2 = wred_sum(p2), cs3 = wred_sum(p3);
      l0 = l0 * __expf(m0 - nm0) + cs0; m0 = nm0;
      l1 = l1 * __expf(m1 - nm1) + cs1; m1 = nm1;
      l2 = l2 * __expf(m2 - nm2) + cs2; m2 = nm2;
      l3 = l3 * __expf(m3 - nm3) + cs3; m3 = nm3;
    }
    float rl0 = 1.f / l0, rl1 = 1.f / l1, rl2 = 1.f / l2, rl3 = 1.f / l3;
    int head = lane >> 4;  // features 2*lane, 2*lane+1 both in head lane/16

    for (int e = 0; e < deg; e++) {
      int s = csr_src[base + e];          // wave-uniform
      float4 elv = *(const float4*)&el[s * 4];
      float a0 = __expf(lrelu(elv.x + erv.x) - m0) * rl0;
      float a1 = __expf(lrelu(elv.y + erv.y) - m1) * rl1;
      float a2 = __expf(lrelu(elv.z + erv.z) - m2) * rl2;
      float a3 = __expf(lrelu(elv.w + erv.w) - m3) * rl3;
      float av = (head == 0) ? a0 : (head == 1) ? a1 : (head == 2) ? a2 : a3;
      float2 hv = *(const float2*)&h[s * 128 + f0];
      acc0 = fmaf(hv.x, av, acc0);
      acc1 = fmaf(hv.y, av, acc1);
    }
  }
  float b0 = bias[f0], b1 = bias[f0 + 1];
  float2 o;
  o.x = eluf(acc0 + b0);
  o.y = eluf(acc1 + b1);
  *(float2*)&out[n * 128 + f0] = o;
}

// ---------------- final linear: C[N,40] = A[N,128] @ Wo[128,40] + bo ----------------
__global__ __launch_bounds__(256) void gemm_out_k(const float* __restrict__ A,
                                                  const float* __restrict__ Wo,
                                                  const float* __restrict__ bo,
                                                  float* __restrict__ C, int N) {
  __shared__ float As[64 * 132];
  __shared__ float Ws[128 * 44];
  int tid = threadIdx.x;
  int rowBase = blockIdx.x * 64;
  for (int i = tid; i < 128 * 40; i += 256) {
    int r = i / 40, c = i % 40;
    Ws[r * 44 + c] = Wo[i];
  }
#pragma unroll
  for (int j = 0; j < 8; j++) {
    int v = tid + 256 * j;
    int r = v >> 5, c4 = v & 31;
    int gr = rowBase + r;
    float4 val = (gr < N) ? ((const float4*)A)[gr * 32 + c4] : make_float4(0.f, 0.f, 0.f, 0.f);
    *(float4*)&As[r * 132 + c4 * 4] = val;
  }
  __syncthreads();
  int rg = tid >> 4, cg = tid & 15;
  if (cg < 10) {
    float acc[4][4] = {};
#pragma unroll 4
    for (int k = 0; k < 128; k++) {
      float a[4];
#pragma unroll
      for (int i = 0; i < 4; i++) a[i] = As[(rg + 16 * i) * 132 + k];
      float4 w = *(const float4*)&Ws[k * 44 + cg * 4];
#pragma unroll
      for (int i = 0; i < 4; i++) {
        acc[i][0] = fmaf(a[i], w.x, acc[i][0]);
        acc[i][1] = fmaf(a[i], w.y, acc[i][1]);
        acc[i][2] = fmaf(a[i], w.z, acc[i][2]);
        acc[i][3] = fmaf(a[i], w.w, acc[i][3]);
      }
    }
    float4 bv = *(const float4*)&bo[cg * 4];
#pragma unroll
    for (int i = 0; i < 4; i++) {
      int r = rowBase + rg + 16 * i;
      if (r < N) {
        float4 o = make_float4(acc[i][0] + bv.x, acc[i][1] + bv.y,
                               acc[i][2] + bv.z, acc[i][3] + bv.w);
        *(float4*)&C[r * 40 + cg * 4] = o;
      }
    }
  }
}

extern "C" void kernel_launch(void* const* d_in, const int* in_sizes, int n_in,
                              void* d_out, int out_size, void* d_ws, size_t ws_size,
                              hipStream_t stream) {
  const float* x    = (const float*)d_in[0];
  const int*   src  = (const int*)d_in[1];
  const int*   dst  = (const int*)d_in[2];
  const float* W1   = (const float*)d_in[3];
  const float* al1  = (const float*)d_in[4];
  const float* ar1  = (const float*)d_in[5];
  const float* b1   = (const float*)d_in[6];
  const float* W2   = (const float*)d_in[7];
  const float* al2  = (const float*)d_in[8];
  const float* ar2  = (const float*)d_in[9];
  const float* b2   = (const float*)d_in[10];
  const float* Wout = (const float*)d_in[11];
  const float* bout = (const float*)d_in[12];
  float* out = (float*)d_out;

  const int N = N_NODES, E = N_EDGES;
  size_t off = 0;
  auto alloc = [&](size_t bytes) {
    void* p = (char*)d_ws + off;
    off += (bytes + 255) & ~(size_t)255;
    return p;
  };
  float* h   = (float*)alloc((size_t)N * 128 * 4);
  float* o   = (float*)alloc((size_t)N * 128 * 4);
  float* el  = (float*)alloc((size_t)N * 4 * 4);
  float* er  = (float*)alloc((size_t)N * 4 * 4);
  int* rowstart = (int*)alloc((size_t)(N + 1) * 4);
  int* deg      = (int*)alloc((size_t)N * 4);
  int* cursor   = (int*)alloc((size_t)N * 4);
  int* csr_src  = (int*)alloc((size_t)E * 4);
  (void)ws_size; (void)in_sizes; (void)n_in; (void)out_size;

  // zero deg + cursor (contiguous region from deg to end of cursor)
  size_t zbytes = (size_t)((char*)cursor - (char*)deg) + (size_t)N * 4;
  hipMemsetAsync(deg, 0, zbytes, stream);

  // CSR build
  count_kernel<<<(E + 255) / 256, 256, 0, stream>>>(dst, deg);
  scan_kernel<<<1, 1024, 0, stream>>>(deg, rowstart);
  scatter_kernel<<<(E + 255) / 256, 256, 0, stream>>>(src, dst, rowstart, cursor, csr_src);

  int gemmGrid = (N + 63) / 64;
  int elrGrid  = (N * 16 + 255) / 256;
  int aggGrid  = (N * 64 + 255) / 256;

  // layer 1
  gemm128<<<gemmGrid, 256, 0, stream>>>(x, W1, h, N);
  elr_kernel<<<elrGrid, 256, 0, stream>>>(h, al1, ar1, el, er);
  aggregate<<<aggGrid, 256, 0, stream>>>(h, el, er, rowstart, csr_src, b1, o);

  // layer 2 (h reused as the GEMM output buffer)
  gemm128<<<gemmGrid, 256, 0, stream>>>(o, W2, h, N);
  elr_kernel<<<elrGrid, 256, 0, stream>>>(h, al2, ar2, el, er);
  aggregate<<<aggGrid, 256, 0, stream>>>(h, el, er, rowstart, csr_src, b2, o);

  // output linear
  gemm_out_k<<<gemmGrid, 256, 0, stream>>>(o, Wout, bout, out, N);
}

// Round 2
// 914.715 us; speedup vs baseline: 1.2917x; 1.2917x over previous
//
#include <hip/hip_runtime.h>
#include <math.h>

#define N_NODES 100000
#define N_EDGES 1600000
#define NEG_SLOPE 0.2f

__device__ __forceinline__ float lrelu(float x) { return x > 0.f ? x : NEG_SLOPE * x; }
__device__ __forceinline__ float eluf(float x)  { return x > 0.f ? x : expm1f(x); }

__device__ __forceinline__ float wred_max(float v) {
#pragma unroll
  for (int i = 1; i < 64; i <<= 1) v = fmaxf(v, __shfl_xor(v, i, 64));
  return v;
}
__device__ __forceinline__ float wred_sum(float v) {
#pragma unroll
  for (int i = 1; i < 64; i <<= 1) v += __shfl_xor(v, i, 64);
  return v;
}

// ---------------- CSR build (by dst) ----------------
__global__ void count_kernel(const int* __restrict__ dst, int* __restrict__ deg) {
  int e = blockIdx.x * 256 + threadIdx.x;
  if (e < N_EDGES) atomicAdd(&deg[dst[e]], 1);
}

__global__ __launch_bounds__(1024) void scan_kernel(const int* __restrict__ deg,
                                                    int* __restrict__ rowstart) {
  __shared__ int sums[1024];
  int t = threadIdx.x;
  const int chunk = (N_NODES + 1023) / 1024;  // 98
  int s = t * chunk, e = min(s + chunk, N_NODES);
  int acc = 0;
  for (int i = s; i < e; i++) acc += deg[i];
  sums[t] = acc;
  __syncthreads();
  for (int off = 1; off < 1024; off <<= 1) {
    int v = (t >= off) ? sums[t - off] : 0;
    __syncthreads();
    sums[t] += v;
    __syncthreads();
  }
  int run = sums[t] - acc;  // exclusive prefix for this chunk
  for (int i = s; i < e; i++) { rowstart[i] = run; run += deg[i]; }
  if (t == 1023) rowstart[N_NODES] = sums[1023];
}

__global__ void scatter_kernel(const int* __restrict__ src, const int* __restrict__ dst,
                               const int* __restrict__ rowstart, int* __restrict__ cursor,
                               int* __restrict__ csr_src, int* __restrict__ csr_dst) {
  int e = blockIdx.x * 256 + threadIdx.x;
  if (e < N_EDGES) {
    int d = dst[e];
    int pos = rowstart[d] + atomicAdd(&cursor[d], 1);
    csr_src[pos] = src[e];
    csr_dst[pos] = d;
  }
}

// ---------------- GEMM: C[N,128] = A[N,128] @ W[128,128], fused el/er ----------------
// block 256 threads, 64 rows/block. W (64KB) + A-tile (33KB) in LDS.
__global__ __launch_bounds__(256) void gemm128_elr(const float* __restrict__ A,
                                                   const float* __restrict__ W,
                                                   const float* __restrict__ al,
                                                   const float* __restrict__ ar,
                                                   float* __restrict__ C,
                                                   float* __restrict__ el,
                                                   float* __restrict__ er, int N) {
  __shared__ float Ws[128 * 128];
  __shared__ float As[64 * 132];
  __shared__ float als[128], ars[128];
  int tid = threadIdx.x;
  int rowBase = blockIdx.x * 64;

  if (tid < 128) { als[tid] = al[tid]; ars[tid] = ar[tid]; }

  const float4* W4 = (const float4*)W;
  float4* Ws4 = (float4*)Ws;
#pragma unroll
  for (int i = 0; i < 16; i++) Ws4[tid + 256 * i] = W4[tid + 256 * i];

#pragma unroll
  for (int j = 0; j < 8; j++) {
    int v = tid + 256 * j;
    int r = v >> 5, c4 = v & 31;
    int gr = rowBase + r;
    float4 val = (gr < N) ? ((const float4*)A)[gr * 32 + c4] : make_float4(0.f, 0.f, 0.f, 0.f);
    *(float4*)&As[r * 132 + c4 * 4] = val;
  }
  __syncthreads();

  int rg = tid >> 4, cg = tid & 15;  // rows rg+16i (i<4), cols cg*8..cg*8+7
  float acc[4][8] = {};
#pragma unroll 4
  for (int k = 0; k < 128; k++) {
    float a[4];
#pragma unroll
    for (int i = 0; i < 4; i++) a[i] = As[(rg + 16 * i) * 132 + k];
    float4 w0 = *(const float4*)&Ws[k * 128 + cg * 8];
    float4 w1 = *(const float4*)&Ws[k * 128 + cg * 8 + 4];
    float w[8] = {w0.x, w0.y, w0.z, w0.w, w1.x, w1.y, w1.z, w1.w};
#pragma unroll
    for (int i = 0; i < 4; i++)
#pragma unroll
      for (int j = 0; j < 8; j++) acc[i][j] = fmaf(a[i], w[j], acc[i][j]);
  }

  float alr[8], arr[8];
#pragma unroll
  for (int j = 0; j < 8; j++) { alr[j] = als[cg * 8 + j]; arr[j] = ars[cg * 8 + j]; }

#pragma unroll
  for (int i = 0; i < 4; i++) {
    int r = rowBase + rg + 16 * i;
    float pel = 0.f, per = 0.f;
#pragma unroll
    for (int j = 0; j < 8; j++) {
      pel = fmaf(acc[i][j], alr[j], pel);
      per = fmaf(acc[i][j], arr[j], per);
    }
    pel += __shfl_xor(pel, 1, 64); pel += __shfl_xor(pel, 2, 64);
    per += __shfl_xor(per, 1, 64); per += __shfl_xor(per, 2, 64);
    if (r < N) {
      float4 o0 = make_float4(acc[i][0], acc[i][1], acc[i][2], acc[i][3]);
      float4 o1 = make_float4(acc[i][4], acc[i][5], acc[i][6], acc[i][7]);
      *(float4*)&C[r * 128 + cg * 8] = o0;
      *(float4*)&C[r * 128 + cg * 8 + 4] = o1;
      if ((cg & 3) == 0) {
        int hd = cg >> 2;
        el[r * 4 + hd] = pel;
        er[r * 4 + hd] = per;
      }
    }
  }
}

// ---------------- per-node softmax stats: m and 1/l per head ----------------
__global__ __launch_bounds__(256) void stats_kernel(const float* __restrict__ el,
                                                    const float* __restrict__ er,
                                                    const int* __restrict__ rowstart,
                                                    const int* __restrict__ csr_src,
                                                    float2* __restrict__ stats) {
  int n = (blockIdx.x * 256 + threadIdx.x) >> 6;
  int lane = threadIdx.x & 63;
  if (n >= N_NODES) return;
  int base = rowstart[n];
  int deg = rowstart[n + 1] - base;
  if (deg == 0) return;
  float4 erv = *(const float4*)&er[n * 4];
  float m0 = -INFINITY, m1 = -INFINITY, m2 = -INFINITY, m3 = -INFINITY;
  float l0 = 0.f, l1 = 0.f, l2 = 0.f, l3 = 0.f;

  for (int c0 = 0; c0 < deg; c0 += 64) {
    int e = c0 + lane;
    bool act = e < deg;
    int s = act ? csr_src[base + e] : 0;
    float sc0 = -INFINITY, sc1 = -INFINITY, sc2 = -INFINITY, sc3 = -INFINITY;
    if (act) {
      float4 elv = *(const float4*)&el[s * 4];
      sc0 = lrelu(elv.x + erv.x); sc1 = lrelu(elv.y + erv.y);
      sc2 = lrelu(elv.z + erv.z); sc3 = lrelu(elv.w + erv.w);
    }
    float nm0 = fmaxf(m0, wred_max(sc0));
    float nm1 = fmaxf(m1, wred_max(sc1));
    float nm2 = fmaxf(m2, wred_max(sc2));
    float nm3 = fmaxf(m3, wred_max(sc3));
    float p0 = act ? __expf(sc0 - nm0) : 0.f;
    float p1 = act ? __expf(sc1 - nm1) : 0.f;
    float p2 = act ? __expf(sc2 - nm2) : 0.f;
    float p3 = act ? __expf(sc3 - nm3) : 0.f;
    float cs0 = wred_sum(p0), cs1 = wred_sum(p1), cs2 = wred_sum(p2), cs3 = wred_sum(p3);
    l0 = l0 * __expf(m0 - nm0) + cs0; m0 = nm0;
    l1 = l1 * __expf(m1 - nm1) + cs1; m1 = nm1;
    l2 = l2 * __expf(m2 - nm2) + cs2; m2 = nm2;
    l3 = l3 * __expf(m3 - nm3) + cs3; m3 = nm3;
  }
  if (lane == 0) {
    stats[n * 4 + 0] = make_float2(m0, 1.f / l0);
    stats[n * 4 + 1] = make_float2(m1, 1.f / l1);
    stats[n * 4 + 2] = make_float2(m2, 1.f / l2);
    stats[n * 4 + 3] = make_float2(m3, 1.f / l3);
  }
}

// ---------------- edge-parallel normalized attention ----------------
__global__ __launch_bounds__(256) void edge_att(const float* __restrict__ el,
                                                const float* __restrict__ er,
                                                const float2* __restrict__ stats,
                                                const int* __restrict__ csr_src,
                                                const int* __restrict__ csr_dst,
                                                float* __restrict__ att) {
  int p = blockIdx.x * 256 + threadIdx.x;
  if (p >= N_EDGES) return;
  int s = csr_src[p], d = csr_dst[p];
  float4 elv = *(const float4*)&el[s * 4];
  float4 erv = *(const float4*)&er[d * 4];
  float2 st0 = stats[d * 4 + 0];
  float2 st1 = stats[d * 4 + 1];
  float2 st2 = stats[d * 4 + 2];
  float2 st3 = stats[d * 4 + 3];
  float4 a;
  a.x = __expf(lrelu(elv.x + erv.x) - st0.x) * st0.y;
  a.y = __expf(lrelu(elv.y + erv.y) - st1.x) * st1.y;
  a.z = __expf(lrelu(elv.z + erv.z) - st2.x) * st2.y;
  a.w = __expf(lrelu(elv.w + erv.w) - st3.x) * st3.y;
  *(float4*)&att[p * 4] = a;
}

// ---------------- aggregation: one 64-lane wave per node ----------------
__global__ __launch_bounds__(256) void aggregate(const float* __restrict__ h,
                                                 const float* __restrict__ att,
                                                 const int* __restrict__ rowstart,
                                                 const int* __restrict__ csr_src,
                                                 const float* __restrict__ bias,
                                                 float* __restrict__ out) {
  int n = (blockIdx.x * 256 + threadIdx.x) >> 6;
  int lane = threadIdx.x & 63;
  if (n >= N_NODES) return;
  int base = rowstart[n];
  int end = rowstart[n + 1];
  int f0 = lane * 2;
  int head = lane >> 4;
  float acc0 = 0.f, acc1 = 0.f;

  int e = base;
  for (; e + 4 <= end; e += 4) {
    int s0 = csr_src[e], s1 = csr_src[e + 1], s2 = csr_src[e + 2], s3 = csr_src[e + 3];
    float a0 = att[e * 4 + head];
    float a1 = att[(e + 1) * 4 + head];
    float a2 = att[(e + 2) * 4 + head];
    float a3 = att[(e + 3) * 4 + head];
    float2 h0 = *(const float2*)&h[(size_t)s0 * 128 + f0];
    float2 h1 = *(const float2*)&h[(size_t)s1 * 128 + f0];
    float2 h2 = *(const float2*)&h[(size_t)s2 * 128 + f0];
    float2 h3 = *(const float2*)&h[(size_t)s3 * 128 + f0];
    acc0 = fmaf(h0.x, a0, acc0); acc1 = fmaf(h0.y, a0, acc1);
    acc0 = fmaf(h1.x, a1, acc0); acc1 = fmaf(h1.y, a1, acc1);
    acc0 = fmaf(h2.x, a2, acc0); acc1 = fmaf(h2.y, a2, acc1);
    acc0 = fmaf(h3.x, a3, acc0); acc1 = fmaf(h3.y, a3, acc1);
  }
  for (; e < end; e++) {
    int s = csr_src[e];
    float a = att[e * 4 + head];
    float2 hv = *(const float2*)&h[(size_t)s * 128 + f0];
    acc0 = fmaf(hv.x, a, acc0);
    acc1 = fmaf(hv.y, a, acc1);
  }
  float2 o;
  o.x = eluf(acc0 + bias[f0]);
  o.y = eluf(acc1 + bias[f0 + 1]);
  *(float2*)&out[n * 128 + f0] = o;
}

// ---------------- final linear: C[N,40] = A[N,128] @ Wo[128,40] + bo ----------------
__global__ __launch_bounds__(256) void gemm_out_k(const float* __restrict__ A,
                                                  const float* __restrict__ Wo,
                                                  const float* __restrict__ bo,
                                                  float* __restrict__ C, int N) {
  __shared__ float As[64 * 132];
  __shared__ float Ws[128 * 44];
  int tid = threadIdx.x;
  int rowBase = blockIdx.x * 64;
  for (int i = tid; i < 128 * 40; i += 256) {
    int r = i / 40, c = i % 40;
    Ws[r * 44 + c] = Wo[i];
  }
#pragma unroll
  for (int j = 0; j < 8; j++) {
    int v = tid + 256 * j;
    int r = v >> 5, c4 = v & 31;
    int gr = rowBase + r;
    float4 val = (gr < N) ? ((const float4*)A)[gr * 32 + c4] : make_float4(0.f, 0.f, 0.f, 0.f);
    *(float4*)&As[r * 132 + c4 * 4] = val;
  }
  __syncthreads();
  int rg = tid >> 4, cg = tid & 15;
  if (cg < 10) {
    float acc[4][4] = {};
#pragma unroll 4
    for (int k = 0; k < 128; k++) {
      float a[4];
#pragma unroll
      for (int i = 0; i < 4; i++) a[i] = As[(rg + 16 * i) * 132 + k];
      float4 w = *(const float4*)&Ws[k * 44 + cg * 4];
#pragma unroll
      for (int i = 0; i < 4; i++) {
        acc[i][0] = fmaf(a[i], w.x, acc[i][0]);
        acc[i][1] = fmaf(a[i], w.y, acc[i][1]);
        acc[i][2] = fmaf(a[i], w.z, acc[i][2]);
        acc[i][3] = fmaf(a[i], w.w, acc[i][3]);
      }
    }
    float4 bv = *(const float4*)&bo[cg * 4];
#pragma unroll
    for (int i = 0; i < 4; i++) {
      int r = rowBase + rg + 16 * i;
      if (r < N) {
        float4 o = make_float4(acc[i][0] + bv.x, acc[i][1] + bv.y,
                               acc[i][2] + bv.z, acc[i][3] + bv.w);
        *(float4*)&C[r * 40 + cg * 4] = o;
      }
    }
  }
}

extern "C" void kernel_launch(void* const* d_in, const int* in_sizes, int n_in,
                              void* d_out, int out_size, void* d_ws, size_t ws_size,
                              hipStream_t stream) {
  const float* x    = (const float*)d_in[0];
  const int*   src  = (const int*)d_in[1];
  const int*   dst  = (const int*)d_in[2];
  const float* W1   = (const float*)d_in[3];
  const float* al1  = (const float*)d_in[4];
  const float* ar1  = (const float*)d_in[5];
  const float* b1   = (const float*)d_in[6];
  const float* W2   = (const float*)d_in[7];
  const float* al2  = (const float*)d_in[8];
  const float* ar2  = (const float*)d_in[9];
  const float* b2   = (const float*)d_in[10];
  const float* Wout = (const float*)d_in[11];
  const float* bout = (const float*)d_in[12];
  float* out = (float*)d_out;

  const int N = N_NODES, E = N_EDGES;
  size_t off = 0;
  auto alloc = [&](size_t bytes) {
    void* p = (char*)d_ws + off;
    off += (bytes + 255) & ~(size_t)255;
    return p;
  };
  float* h   = (float*)alloc((size_t)N * 128 * 4);
  float* o   = (float*)alloc((size_t)N * 128 * 4);
  float* el  = (float*)alloc((size_t)N * 4 * 4);
  float* er  = (float*)alloc((size_t)N * 4 * 4);
  float2* stats = (float2*)alloc((size_t)N * 4 * 8);
  float* att = (float*)alloc((size_t)E * 4 * 4);
  int* rowstart = (int*)alloc((size_t)(N + 1) * 4);
  int* deg      = (int*)alloc((size_t)N * 4);
  int* cursor   = (int*)alloc((size_t)N * 4);
  int* csr_src  = (int*)alloc((size_t)E * 4);
  int* csr_dst  = (int*)alloc((size_t)E * 4);
  (void)ws_size; (void)in_sizes; (void)n_in; (void)out_size;

  // zero deg + cursor (contiguous region from deg to end of cursor)
  size_t zbytes = (size_t)((char*)cursor - (char*)deg) + (size_t)N * 4;
  hipMemsetAsync(deg, 0, zbytes, stream);

  // CSR build
  count_kernel<<<(E + 255) / 256, 256, 0, stream>>>(dst, deg);
  scan_kernel<<<1, 1024, 0, stream>>>(deg, rowstart);
  scatter_kernel<<<(E + 255) / 256, 256, 0, stream>>>(src, dst, rowstart, cursor,
                                                      csr_src, csr_dst);

  int gemmGrid = (N + 63) / 64;
  int nodeWaveGrid = (N * 64 + 255) / 256;
  int edgeGrid = (E + 255) / 256;

  // layer 1
  gemm128_elr<<<gemmGrid, 256, 0, stream>>>(x, W1, al1, ar1, h, el, er, N);
  stats_kernel<<<nodeWaveGrid, 256, 0, stream>>>(el, er, rowstart, csr_src, stats);
  edge_att<<<edgeGrid, 256, 0, stream>>>(el, er, stats, csr_src, csr_dst, att);
  aggregate<<<nodeWaveGrid, 256, 0, stream>>>(h, att, rowstart, csr_src, b1, o);

  // layer 2 (h reused as the GEMM output buffer)
  gemm128_elr<<<gemmGrid, 256, 0, stream>>>(o, W2, al2, ar2, h, el, er, N);
  stats_kernel<<<nodeWaveGrid, 256, 0, stream>>>(el, er, rowstart, csr_src, stats);
  edge_att<<<edgeGrid, 256, 0, stream>>>(el, er, stats, csr_src, csr_dst, att);
  aggregate<<<nodeWaveGrid, 256, 0, stream>>>(h, att, rowstart, csr_src, b2, o);

  // output linear
  gemm_out_k<<<gemmGrid, 256, 0, stream>>>(o, Wout, bout, out, N);
}

// Round 3
// 758.830 us; speedup vs baseline: 1.5571x; 1.2054x over previous
//
#include <hip/hip_runtime.h>
#include <math.h>

#define N_NODES 100000
#define N_EDGES 1600000
#define NEG_SLOPE 0.2f

#define SCAN_SEG 1024                       // elements per scan block (mult of 1024)
#define SCAN_BLOCKS ((N_NODES + SCAN_SEG - 1) / SCAN_SEG)  // 98

__device__ __forceinline__ float lrelu(float x) { return x > 0.f ? x : NEG_SLOPE * x; }
__device__ __forceinline__ float eluf(float x)  { return x > 0.f ? x : expm1f(x); }

__device__ __forceinline__ float wred_max(float v) {
#pragma unroll
  for (int i = 1; i < 64; i <<= 1) v = fmaxf(v, __shfl_xor(v, i, 64));
  return v;
}
__device__ __forceinline__ float wred_sum(float v) {
#pragma unroll
  for (int i = 1; i < 64; i <<= 1) v += __shfl_xor(v, i, 64);
  return v;
}

// ---------------- CSR build (by dst) ----------------
__global__ void count_kernel(const int* __restrict__ dst, int* __restrict__ deg) {
  int e = blockIdx.x * 256 + threadIdx.x;
  if (e < N_EDGES) atomicAdd(&deg[dst[e]], 1);
}

// Device-wide exclusive scan of deg -> rowstart, in 3 small kernels.
__global__ __launch_bounds__(256) void scan_part(const int* __restrict__ deg,
                                                 int* __restrict__ blockSums) {
  int b = blockIdx.x, t = threadIdx.x;
  int i0 = b * SCAN_SEG + t * 4;
  int4 v = make_int4(0, 0, 0, 0);
  if (i0 < N_NODES) v = *(const int4*)&deg[i0];   // N_NODES % 4 == 0: whole int4 valid
  int acc = v.x + v.y + v.z + v.w;
#pragma unroll
  for (int i = 1; i < 64; i <<= 1) acc += __shfl_xor(acc, i, 64);
  __shared__ int ws[4];
  if ((t & 63) == 0) ws[t >> 6] = acc;
  __syncthreads();
  if (t == 0) blockSums[b] = ws[0] + ws[1] + ws[2] + ws[3];
}

__global__ __launch_bounds__(128) void scan_top(const int* __restrict__ blockSums,
                                                int* __restrict__ blockOffs) {
  __shared__ int sh[128];
  int t = threadIdx.x;
  int own = (t < SCAN_BLOCKS) ? blockSums[t] : 0;
  sh[t] = own;
  __syncthreads();
  for (int off = 1; off < 128; off <<= 1) {
    int v = (t >= off) ? sh[t - off] : 0;
    __syncthreads();
    sh[t] += v;
    __syncthreads();
  }
  if (t < SCAN_BLOCKS) blockOffs[t] = sh[t] - own;  // exclusive
}

__global__ __launch_bounds__(256) void scan_final(const int* __restrict__ deg,
                                                  const int* __restrict__ blockOffs,
                                                  int* __restrict__ rowstart) {
  int b = blockIdx.x, t = threadIdx.x;
  int i0 = b * SCAN_SEG + t * 4;
  int4 v = make_int4(0, 0, 0, 0);
  bool act = i0 < N_NODES;
  if (act) v = *(const int4*)&deg[i0];
  int tsum = v.x + v.y + v.z + v.w;
  __shared__ int sh[256];
  sh[t] = tsum;
  __syncthreads();
  for (int off = 1; off < 256; off <<= 1) {
    int u = (t >= off) ? sh[t - off] : 0;
    __syncthreads();
    sh[t] += u;
    __syncthreads();
  }
  int r0 = sh[t] - tsum + blockOffs[b];
  if (act) {
    int4 o;
    o.x = r0;
    o.y = r0 + v.x;
    o.z = o.y + v.y;
    o.w = o.z + v.z;
    *(int4*)&rowstart[i0] = o;
  }
  if (b == 0 && t == 0) rowstart[N_NODES] = N_EDGES;
}

__global__ void scatter_kernel(const int* __restrict__ src, const int* __restrict__ dst,
                               const int* __restrict__ rowstart, int* __restrict__ cursor,
                               int* __restrict__ csr_src, int* __restrict__ csr_dst) {
  int e = blockIdx.x * 256 + threadIdx.x;
  if (e < N_EDGES) {
    int d = dst[e];
    int pos = rowstart[d] + atomicAdd(&cursor[d], 1);
    csr_src[pos] = src[e];
    csr_dst[pos] = d;
  }
}

// ---------------- GEMM: C[N,128] = A[N,128] @ W[128,128], fused el/er ----------------
__global__ __launch_bounds__(256) void gemm128_elr(const float* __restrict__ A,
                                                   const float* __restrict__ W,
                                                   const float* __restrict__ al,
                                                   const float* __restrict__ ar,
                                                   float* __restrict__ C,
                                                   float* __restrict__ el,
                                                   float* __restrict__ er, int N) {
  __shared__ float Ws[128 * 128];
  __shared__ float As[64 * 132];
  __shared__ float als[128], ars[128];
  int tid = threadIdx.x;
  int rowBase = blockIdx.x * 64;

  if (tid < 128) { als[tid] = al[tid]; ars[tid] = ar[tid]; }

  const float4* W4 = (const float4*)W;
  float4* Ws4 = (float4*)Ws;
#pragma unroll
  for (int i = 0; i < 16; i++) Ws4[tid + 256 * i] = W4[tid + 256 * i];

#pragma unroll
  for (int j = 0; j < 8; j++) {
    int v = tid + 256 * j;
    int r = v >> 5, c4 = v & 31;
    int gr = rowBase + r;
    float4 val = (gr < N) ? ((const float4*)A)[gr * 32 + c4] : make_float4(0.f, 0.f, 0.f, 0.f);
    *(float4*)&As[r * 132 + c4 * 4] = val;
  }
  __syncthreads();

  int rg = tid >> 4, cg = tid & 15;
  float acc[4][8] = {};
#pragma unroll 4
  for (int k = 0; k < 128; k++) {
    float a[4];
#pragma unroll
    for (int i = 0; i < 4; i++) a[i] = As[(rg + 16 * i) * 132 + k];
    float4 w0 = *(const float4*)&Ws[k * 128 + cg * 8];
    float4 w1 = *(const float4*)&Ws[k * 128 + cg * 8 + 4];
    float w[8] = {w0.x, w0.y, w0.z, w0.w, w1.x, w1.y, w1.z, w1.w};
#pragma unroll
    for (int i = 0; i < 4; i++)
#pragma unroll
      for (int j = 0; j < 8; j++) acc[i][j] = fmaf(a[i], w[j], acc[i][j]);
  }

  float alr[8], arr[8];
#pragma unroll
  for (int j = 0; j < 8; j++) { alr[j] = als[cg * 8 + j]; arr[j] = ars[cg * 8 + j]; }

#pragma unroll
  for (int i = 0; i < 4; i++) {
    int r = rowBase + rg + 16 * i;
    float pel = 0.f, per = 0.f;
#pragma unroll
    for (int j = 0; j < 8; j++) {
      pel = fmaf(acc[i][j], alr[j], pel);
      per = fmaf(acc[i][j], arr[j], per);
    }
    pel += __shfl_xor(pel, 1, 64); pel += __shfl_xor(pel, 2, 64);
    per += __shfl_xor(per, 1, 64); per += __shfl_xor(per, 2, 64);
    if (r < N) {
      float4 o0 = make_float4(acc[i][0], acc[i][1], acc[i][2], acc[i][3]);
      float4 o1 = make_float4(acc[i][4], acc[i][5], acc[i][6], acc[i][7]);
      *(float4*)&C[r * 128 + cg * 8] = o0;
      *(float4*)&C[r * 128 + cg * 8 + 4] = o1;
      if ((cg & 3) == 0) {
        int hd = cg >> 2;
        el[r * 4 + hd] = pel;
        er[r * 4 + hd] = per;
      }
    }
  }
}

// ---------------- per-node softmax stats: m and 1/l per head ----------------
__global__ __launch_bounds__(256) void stats_kernel(const float* __restrict__ el,
                                                    const float* __restrict__ er,
                                                    const int* __restrict__ rowstart,
                                                    const int* __restrict__ csr_src,
                                                    float2* __restrict__ stats) {
  int n = (blockIdx.x * 256 + threadIdx.x) >> 6;
  int lane = threadIdx.x & 63;
  if (n >= N_NODES) return;
  int base = rowstart[n];
  int deg = rowstart[n + 1] - base;
  if (deg == 0) return;
  float4 erv = *(const float4*)&er[n * 4];
  float m0 = -INFINITY, m1 = -INFINITY, m2 = -INFINITY, m3 = -INFINITY;
  float l0 = 0.f, l1 = 0.f, l2 = 0.f, l3 = 0.f;

  for (int c0 = 0; c0 < deg; c0 += 64) {
    int e = c0 + lane;
    bool act = e < deg;
    int s = act ? csr_src[base + e] : 0;
    float sc0 = -INFINITY, sc1 = -INFINITY, sc2 = -INFINITY, sc3 = -INFINITY;
    if (act) {
      float4 elv = *(const float4*)&el[s * 4];
      sc0 = lrelu(elv.x + erv.x); sc1 = lrelu(elv.y + erv.y);
      sc2 = lrelu(elv.z + erv.z); sc3 = lrelu(elv.w + erv.w);
    }
    float nm0 = fmaxf(m0, wred_max(sc0));
    float nm1 = fmaxf(m1, wred_max(sc1));
    float nm2 = fmaxf(m2, wred_max(sc2));
    float nm3 = fmaxf(m3, wred_max(sc3));
    float p0 = act ? __expf(sc0 - nm0) : 0.f;
    float p1 = act ? __expf(sc1 - nm1) : 0.f;
    float p2 = act ? __expf(sc2 - nm2) : 0.f;
    float p3 = act ? __expf(sc3 - nm3) : 0.f;
    float cs0 = wred_sum(p0), cs1 = wred_sum(p1), cs2 = wred_sum(p2), cs3 = wred_sum(p3);
    l0 = l0 * __expf(m0 - nm0) + cs0; m0 = nm0;
    l1 = l1 * __expf(m1 - nm1) + cs1; m1 = nm1;
    l2 = l2 * __expf(m2 - nm2) + cs2; m2 = nm2;
    l3 = l3 * __expf(m3 - nm3) + cs3; m3 = nm3;
  }
  if (lane == 0) {
    stats[n * 4 + 0] = make_float2(m0, 1.f / l0);
    stats[n * 4 + 1] = make_float2(m1, 1.f / l1);
    stats[n * 4 + 2] = make_float2(m2, 1.f / l2);
    stats[n * 4 + 3] = make_float2(m3, 1.f / l3);
  }
}

// ---------------- edge-parallel normalized attention ----------------
__global__ __launch_bounds__(256) void edge_att(const float* __restrict__ el,
                                                const float* __restrict__ er,
                                                const float2* __restrict__ stats,
                                                const int* __restrict__ csr_src,
                                                const int* __restrict__ csr_dst,
                                                float* __restrict__ att) {
  int p = blockIdx.x * 256 + threadIdx.x;
  if (p >= N_EDGES) return;
  int s = csr_src[p], d = csr_dst[p];
  float4 elv = *(const float4*)&el[s * 4];
  float4 erv = *(const float4*)&er[d * 4];
  float2 st0 = stats[d * 4 + 0];
  float2 st1 = stats[d * 4 + 1];
  float2 st2 = stats[d * 4 + 2];
  float2 st3 = stats[d * 4 + 3];
  float4 a;
  a.x = __expf(lrelu(elv.x + erv.x) - st0.x) * st0.y;
  a.y = __expf(lrelu(elv.y + erv.y) - st1.x) * st1.y;
  a.z = __expf(lrelu(elv.z + erv.z) - st2.x) * st2.y;
  a.w = __expf(lrelu(elv.w + erv.w) - st3.x) * st3.y;
  *(float4*)&att[p * 4] = a;
}

// ---------------- aggregation: one 64-lane wave per node ----------------
__global__ __launch_bounds__(256) void aggregate(const float* __restrict__ h,
                                                 const float* __restrict__ att,
                                                 const int* __restrict__ rowstart,
                                                 const int* __restrict__ csr_src,
                                                 const float* __restrict__ bias,
                                                 float* __restrict__ out) {
  int n = (blockIdx.x * 256 + threadIdx.x) >> 6;
  int lane = threadIdx.x & 63;
  if (n >= N_NODES) return;
  int base = rowstart[n];
  int end = rowstart[n + 1];
  int f0 = lane * 2;
  int head = lane >> 4;
  float acc0 = 0.f, acc1 = 0.f;

  int e = base;
  for (; e + 4 <= end; e += 4) {
    int s0 = csr_src[e], s1 = csr_src[e + 1], s2 = csr_src[e + 2], s3 = csr_src[e + 3];
    float a0 = att[e * 4 + head];
    float a1 = att[(e + 1) * 4 + head];
    float a2 = att[(e + 2) * 4 + head];
    float a3 = att[(e + 3) * 4 + head];
    float2 h0 = *(const float2*)&h[(size_t)s0 * 128 + f0];
    float2 h1 = *(const float2*)&h[(size_t)s1 * 128 + f0];
    float2 h2 = *(const float2*)&h[(size_t)s2 * 128 + f0];
    float2 h3 = *(const float2*)&h[(size_t)s3 * 128 + f0];
    acc0 = fmaf(h0.x, a0, acc0); acc1 = fmaf(h0.y, a0, acc1);
    acc0 = fmaf(h1.x, a1, acc0); acc1 = fmaf(h1.y, a1, acc1);
    acc0 = fmaf(h2.x, a2, acc0); acc1 = fmaf(h2.y, a2, acc1);
    acc0 = fmaf(h3.x, a3, acc0); acc1 = fmaf(h3.y, a3, acc1);
  }
  for (; e < end; e++) {
    int s = csr_src[e];
    float a = att[e * 4 + head];
    float2 hv = *(const float2*)&h[(size_t)s * 128 + f0];
    acc0 = fmaf(hv.x, a, acc0);
    acc1 = fmaf(hv.y, a, acc1);
  }
  float2 o;
  o.x = eluf(acc0 + bias[f0]);
  o.y = eluf(acc1 + bias[f0 + 1]);
  *(float2*)&out[n * 128 + f0] = o;
}

// ---------------- final linear: C[N,40] = A[N,128] @ Wo[128,40] + bo ----------------
__global__ __launch_bounds__(256) void gemm_out_k(const float* __restrict__ A,
                                                  const float* __restrict__ Wo,
                                                  const float* __restrict__ bo,
                                                  float* __restrict__ C, int N) {
  __shared__ float As[64 * 132];
  __shared__ float Ws[128 * 44];
  int tid = threadIdx.x;
  int rowBase = blockIdx.x * 64;
  for (int i = tid; i < 128 * 40; i += 256) {
    int r = i / 40, c = i % 40;
    Ws[r * 44 + c] = Wo[i];
  }
#pragma unroll
  for (int j = 0; j < 8; j++) {
    int v = tid + 256 * j;
    int r = v >> 5, c4 = v & 31;
    int gr = rowBase + r;
    float4 val = (gr < N) ? ((const float4*)A)[gr * 32 + c4] : make_float4(0.f, 0.f, 0.f, 0.f);
    *(float4*)&As[r * 132 + c4 * 4] = val;
  }
  __syncthreads();
  int rg = tid >> 4, cg = tid & 15;
  if (cg < 10) {
    float acc[4][4] = {};
#pragma unroll 4
    for (int k = 0; k < 128; k++) {
      float a[4];
#pragma unroll
      for (int i = 0; i < 4; i++) a[i] = As[(rg + 16 * i) * 132 + k];
      float4 w = *(const float4*)&Ws[k * 44 + cg * 4];
#pragma unroll
      for (int i = 0; i < 4; i++) {
        acc[i][0] = fmaf(a[i], w.x, acc[i][0]);
        acc[i][1] = fmaf(a[i], w.y, acc[i][1]);
        acc[i][2] = fmaf(a[i], w.z, acc[i][2]);
        acc[i][3] = fmaf(a[i], w.w, acc[i][3]);
      }
    }
    float4 bv = *(const float4*)&bo[cg * 4];
#pragma unroll
    for (int i = 0; i < 4; i++) {
      int r = rowBase + rg + 16 * i;
      if (r < N) {
        float4 o = make_float4(acc[i][0] + bv.x, acc[i][1] + bv.y,
                               acc[i][2] + bv.z, acc[i][3] + bv.w);
        *(float4*)&C[r * 40 + cg * 4] = o;
      }
    }
  }
}

extern "C" void kernel_launch(void* const* d_in, const int* in_sizes, int n_in,
                              void* d_out, int out_size, void* d_ws, size_t ws_size,
                              hipStream_t stream) {
  const float* x    = (const float*)d_in[0];
  const int*   src  = (const int*)d_in[1];
  const int*   dst  = (const int*)d_in[2];
  const float* W1   = (const float*)d_in[3];
  const float* al1  = (const float*)d_in[4];
  const float* ar1  = (const float*)d_in[5];
  const float* b1   = (const float*)d_in[6];
  const float* W2   = (const float*)d_in[7];
  const float* al2  = (const float*)d_in[8];
  const float* ar2  = (const float*)d_in[9];
  const float* b2   = (const float*)d_in[10];
  const float* Wout = (const float*)d_in[11];
  const float* bout = (const float*)d_in[12];
  float* out = (float*)d_out;

  const int N = N_NODES, E = N_EDGES;
  size_t off = 0;
  auto alloc = [&](size_t bytes) {
    void* p = (char*)d_ws + off;
    off += (bytes + 255) & ~(size_t)255;
    return p;
  };
  float* h   = (float*)alloc((size_t)N * 128 * 4);
  float* o   = (float*)alloc((size_t)N * 128 * 4);
  float* el  = (float*)alloc((size_t)N * 4 * 4);
  float* er  = (float*)alloc((size_t)N * 4 * 4);
  float2* stats = (float2*)alloc((size_t)N * 4 * 8);
  float* att = (float*)alloc((size_t)E * 4 * 4);
  int* rowstart = (int*)alloc((size_t)(N + 1) * 4);
  int* deg      = (int*)alloc((size_t)N * 4);
  int* cursor   = (int*)alloc((size_t)N * 4);
  int* blockSums = (int*)alloc((size_t)SCAN_BLOCKS * 4);
  int* blockOffs = (int*)alloc((size_t)SCAN_BLOCKS * 4);
  int* csr_src  = (int*)alloc((size_t)E * 4);
  int* csr_dst  = (int*)alloc((size_t)E * 4);
  (void)ws_size; (void)in_sizes; (void)n_in; (void)out_size;

  // zero deg + cursor (contiguous region from deg through cursor)
  size_t zbytes = (size_t)((char*)cursor - (char*)deg) + (size_t)N * 4;
  hipMemsetAsync(deg, 0, zbytes, stream);

  // CSR build
  count_kernel<<<(E + 255) / 256, 256, 0, stream>>>(dst, deg);
  scan_part<<<SCAN_BLOCKS, 256, 0, stream>>>(deg, blockSums);
  scan_top<<<1, 128, 0, stream>>>(blockSums, blockOffs);
  scan_final<<<SCAN_BLOCKS, 256, 0, stream>>>(deg, blockOffs, rowstart);
  scatter_kernel<<<(E + 255) / 256, 256, 0, stream>>>(src, dst, rowstart, cursor,
                                                      csr_src, csr_dst);

  int gemmGrid = (N + 63) / 64;
  int nodeWaveGrid = (N * 64 + 255) / 256;
  int edgeGrid = (E + 255) / 256;

  // layer 1
  gemm128_elr<<<gemmGrid, 256, 0, stream>>>(x, W1, al1, ar1, h, el, er, N);
  stats_kernel<<<nodeWaveGrid, 256, 0, stream>>>(el, er, rowstart, csr_src, stats);
  edge_att<<<edgeGrid, 256, 0, stream>>>(el, er, stats, csr_src, csr_dst, att);
  aggregate<<<nodeWaveGrid, 256, 0, stream>>>(h, att, rowstart, csr_src, b1, o);

  // layer 2 (h reused as the GEMM output buffer)
  gemm128_elr<<<gemmGrid, 256, 0, stream>>>(o, W2, al2, ar2, h, el, er, N);
  stats_kernel<<<nodeWaveGrid, 256, 0, stream>>>(el, er, rowstart, csr_src, stats);
  edge_att<<<edgeGrid, 256, 0, stream>>>(el, er, stats, csr_src, csr_dst, att);
  aggregate<<<nodeWaveGrid, 256, 0, stream>>>(h, att, rowstart, csr_src, b2, o);

  // output linear
  gemm_out_k<<<gemmGrid, 256, 0, stream>>>(o, Wout, bout, out, N);
}

// Round 4
// 735.210 us; speedup vs baseline: 1.6071x; 1.0321x over previous
//
#include <hip/hip_runtime.h>
#include <math.h>

#define N_NODES 100000
#define N_EDGES 1600000
#define NEG_SLOPE 0.2f

#define SCAN_SEG 1024                       // elements per scan block
#define SCAN_BLOCKS ((N_NODES + SCAN_SEG - 1) / SCAN_SEG)  // 98

__device__ __forceinline__ float lrelu(float x) { return x > 0.f ? x : NEG_SLOPE * x; }
__device__ __forceinline__ float eluf(float x)  { return x > 0.f ? x : expm1f(x); }

__device__ __forceinline__ float wred_max(float v) {
#pragma unroll
  for (int i = 1; i < 64; i <<= 1) v = fmaxf(v, __shfl_xor(v, i, 64));
  return v;
}
__device__ __forceinline__ float wred_sum(float v) {
#pragma unroll
  for (int i = 1; i < 64; i <<= 1) v += __shfl_xor(v, i, 64);
  return v;
}

// ---------------- CSR build (by dst) ----------------
__global__ void count_kernel(const int* __restrict__ dst, int* __restrict__ deg) {
  int e = blockIdx.x * 256 + threadIdx.x;
  if (e < N_EDGES) atomicAdd(&deg[dst[e]], 1);
}

// Device-wide exclusive scan of deg -> rowstart, in 3 small kernels.
__global__ __launch_bounds__(256) void scan_part(const int* __restrict__ deg,
                                                 int* __restrict__ blockSums) {
  int b = blockIdx.x, t = threadIdx.x;
  int i0 = b * SCAN_SEG + t * 4;
  int4 v = make_int4(0, 0, 0, 0);
  if (i0 < N_NODES) v = *(const int4*)&deg[i0];
  int acc = v.x + v.y + v.z + v.w;
#pragma unroll
  for (int i = 1; i < 64; i <<= 1) acc += __shfl_xor(acc, i, 64);
  __shared__ int ws[4];
  if ((t & 63) == 0) ws[t >> 6] = acc;
  __syncthreads();
  if (t == 0) blockSums[b] = ws[0] + ws[1] + ws[2] + ws[3];
}

__global__ __launch_bounds__(128) void scan_top(const int* __restrict__ blockSums,
                                                int* __restrict__ blockOffs) {
  __shared__ int sh[128];
  int t = threadIdx.x;
  int own = (t < SCAN_BLOCKS) ? blockSums[t] : 0;
  sh[t] = own;
  __syncthreads();
  for (int off = 1; off < 128; off <<= 1) {
    int v = (t >= off) ? sh[t - off] : 0;
    __syncthreads();
    sh[t] += v;
    __syncthreads();
  }
  if (t < SCAN_BLOCKS) blockOffs[t] = sh[t] - own;  // exclusive
}

__global__ __launch_bounds__(256) void scan_final(const int* __restrict__ deg,
                                                  const int* __restrict__ blockOffs,
                                                  int* __restrict__ rowstart) {
  int b = blockIdx.x, t = threadIdx.x;
  int i0 = b * SCAN_SEG + t * 4;
  int4 v = make_int4(0, 0, 0, 0);
  bool act = i0 < N_NODES;
  if (act) v = *(const int4*)&deg[i0];
  int tsum = v.x + v.y + v.z + v.w;
  __shared__ int sh[256];
  sh[t] = tsum;
  __syncthreads();
  for (int off = 1; off < 256; off <<= 1) {
    int u = (t >= off) ? sh[t - off] : 0;
    __syncthreads();
    sh[t] += u;
    __syncthreads();
  }
  int r0 = sh[t] - tsum + blockOffs[b];
  if (act) {
    int4 o;
    o.x = r0;
    o.y = r0 + v.x;
    o.z = o.y + v.y;
    o.w = o.z + v.z;
    *(int4*)&rowstart[i0] = o;
  }
  if (b == 0 && t == 0) rowstart[N_NODES] = N_EDGES;
}

__global__ void scatter_kernel(const int* __restrict__ src, const int* __restrict__ dst,
                               const int* __restrict__ rowstart, int* __restrict__ cursor,
                               int* __restrict__ csr_src) {
  int e = blockIdx.x * 256 + threadIdx.x;
  if (e < N_EDGES) {
    int d = dst[e];
    int pos = rowstart[d] + atomicAdd(&cursor[d], 1);
    csr_src[pos] = src[e];
  }
}

// ---------------- GEMM: C[N,128] = A[N,128] @ W[128,128], fused el/er ----------------
__global__ __launch_bounds__(256) void gemm128_elr(const float* __restrict__ A,
                                                   const float* __restrict__ W,
                                                   const float* __restrict__ al,
                                                   const float* __restrict__ ar,
                                                   float* __restrict__ C,
                                                   float* __restrict__ el,
                                                   float* __restrict__ er, int N) {
  __shared__ float Ws[128 * 128];
  __shared__ float As[64 * 132];
  __shared__ float als[128], ars[128];
  int tid = threadIdx.x;
  int rowBase = blockIdx.x * 64;

  if (tid < 128) { als[tid] = al[tid]; ars[tid] = ar[tid]; }

  const float4* W4 = (const float4*)W;
  float4* Ws4 = (float4*)Ws;
#pragma unroll
  for (int i = 0; i < 16; i++) Ws4[tid + 256 * i] = W4[tid + 256 * i];

#pragma unroll
  for (int j = 0; j < 8; j++) {
    int v = tid + 256 * j;
    int r = v >> 5, c4 = v & 31;
    int gr = rowBase + r;
    float4 val = (gr < N) ? ((const float4*)A)[gr * 32 + c4] : make_float4(0.f, 0.f, 0.f, 0.f);
    *(float4*)&As[r * 132 + c4 * 4] = val;
  }
  __syncthreads();

  int rg = tid >> 4, cg = tid & 15;
  float acc[4][8] = {};
#pragma unroll 4
  for (int k = 0; k < 128; k++) {
    float a[4];
#pragma unroll
    for (int i = 0; i < 4; i++) a[i] = As[(rg + 16 * i) * 132 + k];
    float4 w0 = *(const float4*)&Ws[k * 128 + cg * 8];
    float4 w1 = *(const float4*)&Ws[k * 128 + cg * 8 + 4];
    float w[8] = {w0.x, w0.y, w0.z, w0.w, w1.x, w1.y, w1.z, w1.w};
#pragma unroll
    for (int i = 0; i < 4; i++)
#pragma unroll
      for (int j = 0; j < 8; j++) acc[i][j] = fmaf(a[i], w[j], acc[i][j]);
  }

  float alr[8], arr[8];
#pragma unroll
  for (int j = 0; j < 8; j++) { alr[j] = als[cg * 8 + j]; arr[j] = ars[cg * 8 + j]; }

#pragma unroll
  for (int i = 0; i < 4; i++) {
    int r = rowBase + rg + 16 * i;
    float pel = 0.f, per = 0.f;
#pragma unroll
    for (int j = 0; j < 8; j++) {
      pel = fmaf(acc[i][j], alr[j], pel);
      per = fmaf(acc[i][j], arr[j], per);
    }
    pel += __shfl_xor(pel, 1, 64); pel += __shfl_xor(pel, 2, 64);
    per += __shfl_xor(per, 1, 64); per += __shfl_xor(per, 2, 64);
    if (r < N) {
      float4 o0 = make_float4(acc[i][0], acc[i][1], acc[i][2], acc[i][3]);
      float4 o1 = make_float4(acc[i][4], acc[i][5], acc[i][6], acc[i][7]);
      *(float4*)&C[r * 128 + cg * 8] = o0;
      *(float4*)&C[r * 128 + cg * 8 + 4] = o1;
      if ((cg & 3) == 0) {
        int hd = cg >> 2;
        el[r * 4 + hd] = pel;
        er[r * 4 + hd] = per;
      }
    }
  }
}

// ---------------- per-node softmax stats + normalized attention ----------------
// pass 1: online max/sum per head (wave-uniform after shuffle reductions)
// pass 2: edge-vectorized write of normalized att[E,4]
__global__ __launch_bounds__(256) void stats_att_kernel(const float* __restrict__ el,
                                                        const float* __restrict__ er,
                                                        const int* __restrict__ rowstart,
                                                        const int* __restrict__ csr_src,
                                                        float* __restrict__ att) {
  int n = (blockIdx.x * 256 + threadIdx.x) >> 6;
  int lane = threadIdx.x & 63;
  if (n >= N_NODES) return;
  int base = rowstart[n];
  int deg = rowstart[n + 1] - base;
  if (deg == 0) return;
  float4 erv = *(const float4*)&er[n * 4];
  float m0 = -INFINITY, m1 = -INFINITY, m2 = -INFINITY, m3 = -INFINITY;
  float l0 = 0.f, l1 = 0.f, l2 = 0.f, l3 = 0.f;

  for (int c0 = 0; c0 < deg; c0 += 64) {
    int e = c0 + lane;
    bool act = e < deg;
    int s = act ? csr_src[base + e] : 0;
    float sc0 = -INFINITY, sc1 = -INFINITY, sc2 = -INFINITY, sc3 = -INFINITY;
    if (act) {
      float4 elv = *(const float4*)&el[s * 4];
      sc0 = lrelu(elv.x + erv.x); sc1 = lrelu(elv.y + erv.y);
      sc2 = lrelu(elv.z + erv.z); sc3 = lrelu(elv.w + erv.w);
    }
    float nm0 = fmaxf(m0, wred_max(sc0));
    float nm1 = fmaxf(m1, wred_max(sc1));
    float nm2 = fmaxf(m2, wred_max(sc2));
    float nm3 = fmaxf(m3, wred_max(sc3));
    float p0 = act ? __expf(sc0 - nm0) : 0.f;
    float p1 = act ? __expf(sc1 - nm1) : 0.f;
    float p2 = act ? __expf(sc2 - nm2) : 0.f;
    float p3 = act ? __expf(sc3 - nm3) : 0.f;
    float cs0 = wred_sum(p0), cs1 = wred_sum(p1), cs2 = wred_sum(p2), cs3 = wred_sum(p3);
    l0 = l0 * __expf(m0 - nm0) + cs0; m0 = nm0;
    l1 = l1 * __expf(m1 - nm1) + cs1; m1 = nm1;
    l2 = l2 * __expf(m2 - nm2) + cs2; m2 = nm2;
    l3 = l3 * __expf(m3 - nm3) + cs3; m3 = nm3;
  }
  float r0 = 1.f / l0, r1 = 1.f / l1, r2 = 1.f / l2, r3 = 1.f / l3;

  for (int c0 = 0; c0 < deg; c0 += 64) {
    int e = c0 + lane;
    if (e < deg) {
      int s = csr_src[base + e];
      float4 elv = *(const float4*)&el[s * 4];
      float4 a;
      a.x = __expf(lrelu(elv.x + erv.x) - m0) * r0;
      a.y = __expf(lrelu(elv.y + erv.y) - m1) * r1;
      a.z = __expf(lrelu(elv.z + erv.z) - m2) * r2;
      a.w = __expf(lrelu(elv.w + erv.w) - m3) * r3;
      *(float4*)&att[(size_t)(base + e) * 4] = a;
    }
  }
}

// ---------------- aggregation: 2 nodes per wave, 32 lanes x float4 each ----------------
__global__ __launch_bounds__(256) void aggregate(const float* __restrict__ h,
                                                 const float* __restrict__ att,
                                                 const int* __restrict__ rowstart,
                                                 const int* __restrict__ csr_src,
                                                 const float* __restrict__ bias,
                                                 float* __restrict__ out) {
  int wv = (blockIdx.x * 256 + threadIdx.x) >> 6;
  int lane = threadIdx.x & 63;
  int half = lane >> 5;
  int l = lane & 31;
  int n = wv * 2 + half;
  if (n >= N_NODES) return;
  int base = rowstart[n];
  int end = rowstart[n + 1];
  int f0 = l * 4;
  int head = l >> 3;
  float4 acc = make_float4(0.f, 0.f, 0.f, 0.f);

  int e = base;
  for (; e + 4 <= end; e += 4) {
    int s0 = csr_src[e], s1 = csr_src[e + 1], s2 = csr_src[e + 2], s3 = csr_src[e + 3];
    float a0 = att[(size_t)e * 4 + head];
    float a1 = att[(size_t)(e + 1) * 4 + head];
    float a2 = att[(size_t)(e + 2) * 4 + head];
    float a3 = att[(size_t)(e + 3) * 4 + head];
    float4 h0 = *(const float4*)&h[(size_t)s0 * 128 + f0];
    float4 h1 = *(const float4*)&h[(size_t)s1 * 128 + f0];
    float4 h2 = *(const float4*)&h[(size_t)s2 * 128 + f0];
    float4 h3 = *(const float4*)&h[(size_t)s3 * 128 + f0];
    acc.x = fmaf(h0.x, a0, acc.x); acc.y = fmaf(h0.y, a0, acc.y);
    acc.z = fmaf(h0.z, a0, acc.z); acc.w = fmaf(h0.w, a0, acc.w);
    acc.x = fmaf(h1.x, a1, acc.x); acc.y = fmaf(h1.y, a1, acc.y);
    acc.z = fmaf(h1.z, a1, acc.z); acc.w = fmaf(h1.w, a1, acc.w);
    acc.x = fmaf(h2.x, a2, acc.x); acc.y = fmaf(h2.y, a2, acc.y);
    acc.z = fmaf(h2.z, a2, acc.z); acc.w = fmaf(h2.w, a2, acc.w);
    acc.x = fmaf(h3.x, a3, acc.x); acc.y = fmaf(h3.y, a3, acc.y);
    acc.z = fmaf(h3.z, a3, acc.z); acc.w = fmaf(h3.w, a3, acc.w);
  }
  for (; e < end; e++) {
    int s = csr_src[e];
    float a = att[(size_t)e * 4 + head];
    float4 hv = *(const float4*)&h[(size_t)s * 128 + f0];
    acc.x = fmaf(hv.x, a, acc.x); acc.y = fmaf(hv.y, a, acc.y);
    acc.z = fmaf(hv.z, a, acc.z); acc.w = fmaf(hv.w, a, acc.w);
  }
  float4 bv = *(const float4*)&bias[f0];
  float4 o;
  o.x = eluf(acc.x + bv.x);
  o.y = eluf(acc.y + bv.y);
  o.z = eluf(acc.z + bv.z);
  o.w = eluf(acc.w + bv.w);
  *(float4*)&out[(size_t)n * 128 + f0] = o;
}

// ---------------- final linear: C[N,40] = A[N,128] @ Wo[128,40] + bo ----------------
__global__ __launch_bounds__(256) void gemm_out_k(const float* __restrict__ A,
                                                  const float* __restrict__ Wo,
                                                  const float* __restrict__ bo,
                                                  float* __restrict__ C, int N) {
  __shared__ float As[64 * 132];
  __shared__ float Ws[128 * 44];
  int tid = threadIdx.x;
  int rowBase = blockIdx.x * 64;
  for (int i = tid; i < 128 * 40; i += 256) {
    int r = i / 40, c = i % 40;
    Ws[r * 44 + c] = Wo[i];
  }
#pragma unroll
  for (int j = 0; j < 8; j++) {
    int v = tid + 256 * j;
    int r = v >> 5, c4 = v & 31;
    int gr = rowBase + r;
    float4 val = (gr < N) ? ((const float4*)A)[gr * 32 + c4] : make_float4(0.f, 0.f, 0.f, 0.f);
    *(float4*)&As[r * 132 + c4 * 4] = val;
  }
  __syncthreads();
  int rg = tid >> 4, cg = tid & 15;
  if (cg < 10) {
    float acc[4][4] = {};
#pragma unroll 4
    for (int k = 0; k < 128; k++) {
      float a[4];
#pragma unroll
      for (int i = 0; i < 4; i++) a[i] = As[(rg + 16 * i) * 132 + k];
      float4 w = *(const float4*)&Ws[k * 44 + cg * 4];
#pragma unroll
      for (int i = 0; i < 4; i++) {
        acc[i][0] = fmaf(a[i], w.x, acc[i][0]);
        acc[i][1] = fmaf(a[i], w.y, acc[i][1]);
        acc[i][2] = fmaf(a[i], w.z, acc[i][2]);
        acc[i][3] = fmaf(a[i], w.w, acc[i][3]);
      }
    }
    float4 bv = *(const float4*)&bo[cg * 4];
#pragma unroll
    for (int i = 0; i < 4; i++) {
      int r = rowBase + rg + 16 * i;
      if (r < N) {
        float4 o = make_float4(acc[i][0] + bv.x, acc[i][1] + bv.y,
                               acc[i][2] + bv.z, acc[i][3] + bv.w);
        *(float4*)&C[r * 40 + cg * 4] = o;
      }
    }
  }
}

extern "C" void kernel_launch(void* const* d_in, const int* in_sizes, int n_in,
                              void* d_out, int out_size, void* d_ws, size_t ws_size,
                              hipStream_t stream) {
  const float* x    = (const float*)d_in[0];
  const int*   src  = (const int*)d_in[1];
  const int*   dst  = (const int*)d_in[2];
  const float* W1   = (const float*)d_in[3];
  const float* al1  = (const float*)d_in[4];
  const float* ar1  = (const float*)d_in[5];
  const float* b1   = (const float*)d_in[6];
  const float* W2   = (const float*)d_in[7];
  const float* al2  = (const float*)d_in[8];
  const float* ar2  = (const float*)d_in[9];
  const float* b2   = (const float*)d_in[10];
  const float* Wout = (const float*)d_in[11];
  const float* bout = (const float*)d_in[12];
  float* out = (float*)d_out;

  const int N = N_NODES, E = N_EDGES;
  size_t off = 0;
  auto alloc = [&](size_t bytes) {
    void* p = (char*)d_ws + off;
    off += (bytes + 255) & ~(size_t)255;
    return p;
  };
  float* h   = (float*)alloc((size_t)N * 128 * 4);
  float* o   = (float*)alloc((size_t)N * 128 * 4);
  float* el  = (float*)alloc((size_t)N * 4 * 4);
  float* er  = (float*)alloc((size_t)N * 4 * 4);
  float* att = (float*)alloc((size_t)E * 4 * 4);
  int* rowstart = (int*)alloc((size_t)(N + 1) * 4);
  int* deg      = (int*)alloc((size_t)N * 4);
  int* cursor   = (int*)alloc((size_t)N * 4);
  int* blockSums = (int*)alloc((size_t)SCAN_BLOCKS * 4);
  int* blockOffs = (int*)alloc((size_t)SCAN_BLOCKS * 4);
  int* csr_src  = (int*)alloc((size_t)E * 4);
  (void)ws_size; (void)in_sizes; (void)n_in; (void)out_size;

  // zero deg + cursor (contiguous region from deg through cursor)
  size_t zbytes = (size_t)((char*)cursor - (char*)deg) + (size_t)N * 4;
  hipMemsetAsync(deg, 0, zbytes, stream);

  // CSR build
  count_kernel<<<(E + 255) / 256, 256, 0, stream>>>(dst, deg);
  scan_part<<<SCAN_BLOCKS, 256, 0, stream>>>(deg, blockSums);
  scan_top<<<1, 128, 0, stream>>>(blockSums, blockOffs);
  scan_final<<<SCAN_BLOCKS, 256, 0, stream>>>(deg, blockOffs, rowstart);
  scatter_kernel<<<(E + 255) / 256, 256, 0, stream>>>(src, dst, rowstart, cursor, csr_src);

  int gemmGrid = (N + 63) / 64;
  int nodeWaveGrid = (N * 64 + 255) / 256;           // 1 node per wave (stats)
  int aggGrid = ((N + 1) / 2 * 64 + 255) / 256;      // 2 nodes per wave (aggregate)

  // layer 1
  gemm128_elr<<<gemmGrid, 256, 0, stream>>>(x, W1, al1, ar1, h, el, er, N);
  stats_att_kernel<<<nodeWaveGrid, 256, 0, stream>>>(el, er, rowstart, csr_src, att);
  aggregate<<<aggGrid, 256, 0, stream>>>(h, att, rowstart, csr_src, b1, o);

  // layer 2 (h reused as the GEMM output buffer)
  gemm128_elr<<<gemmGrid, 256, 0, stream>>>(o, W2, al2, ar2, h, el, er, N);
  stats_att_kernel<<<nodeWaveGrid, 256, 0, stream>>>(el, er, rowstart, csr_src, att);
  aggregate<<<aggGrid, 256, 0, stream>>>(h, att, rowstart, csr_src, b2, o);

  // output linear
  gemm_out_k<<<gemmGrid, 256, 0, stream>>>(o, Wout, bout, out, N);
}

// Round 5
// 597.596 us; speedup vs baseline: 1.9772x; 1.2303x over previous
//
#include <hip/hip_runtime.h>
#include <math.h>

#define N_NODES 100000
#define N_EDGES 1600000
#define NEG_SLOPE 0.2f

#define NB ((N_NODES + 255) / 256)          // 391 level-1 buckets (256 nodes each)
#define NC 256                              // edge chunks
#define CHUNK ((N_EDGES + NC - 1) / NC)     // 6250 edges per chunk

__device__ __forceinline__ float lrelu(float x) { return x > 0.f ? x : NEG_SLOPE * x; }
__device__ __forceinline__ float eluf(float x)  { return x > 0.f ? x : expm1f(x); }

__device__ __forceinline__ float wred_max(float v) {
#pragma unroll
  for (int i = 1; i < 64; i <<= 1) v = fmaxf(v, __shfl_xor(v, i, 64));
  return v;
}
__device__ __forceinline__ float wred_sum(float v) {
#pragma unroll
  for (int i = 1; i < 64; i <<= 1) v += __shfl_xor(v, i, 64);
  return v;
}

// ======== atomic-free CSR build: two-level counting sort by dst ========

// p1: per-chunk histogram of dst>>8 into H[NB][NC] (LDS atomics only)
__global__ __launch_bounds__(256) void p1_hist(const int* __restrict__ dst,
                                               int* __restrict__ H) {
  __shared__ int hist[NB];
  int c = blockIdx.x, t = threadIdx.x;
  for (int i = t; i < NB; i += 256) hist[i] = 0;
  __syncthreads();
  int e0 = c * CHUNK, e1 = min(e0 + CHUNK, N_EDGES);
  for (int e = e0 + t; e < e1; e += 256) atomicAdd(&hist[dst[e] >> 8], 1);
  __syncthreads();
  for (int i = t; i < NB; i += 256) H[i * NC + c] = hist[i];
}

// p2: for each bucket b, exclusive scan of H[b][0..NC) in place; total -> colTotal[b]
__global__ __launch_bounds__(256) void p2_colscan(int* __restrict__ H,
                                                  int* __restrict__ colTotal) {
  __shared__ int sh[256];
  int b = blockIdx.x, t = threadIdx.x;
  int v = H[b * NC + t];
  sh[t] = v;
  __syncthreads();
  for (int off = 1; off < 256; off <<= 1) {
    int u = (t >= off) ? sh[t - off] : 0;
    __syncthreads();
    sh[t] += u;
    __syncthreads();
  }
  H[b * NC + t] = sh[t] - v;  // exclusive
  if (t == 255) colTotal[b] = sh[255];
}

// p3: exclusive scan of colTotal[NB] -> bucketBase[NB+1]
__global__ __launch_bounds__(512) void p3_bucketscan(const int* __restrict__ colTotal,
                                                     int* __restrict__ bucketBase) {
  __shared__ int sh[512];
  int t = threadIdx.x;
  int v = (t < NB) ? colTotal[t] : 0;
  sh[t] = v;
  __syncthreads();
  for (int off = 1; off < 512; off <<= 1) {
    int u = (t >= off) ? sh[t - off] : 0;
    __syncthreads();
    sh[t] += u;
    __syncthreads();
  }
  if (t < NB) bucketBase[t] = sh[t] - v;
  if (t == NB - 1) bucketBase[NB] = sh[t];  // == N_EDGES
}

// p4: scatter (src,dst) pairs into bucket-sorted tmp using LDS cursors
__global__ __launch_bounds__(256) void p4_scatter(const int* __restrict__ src,
                                                  const int* __restrict__ dst,
                                                  const int* __restrict__ H,
                                                  const int* __restrict__ bucketBase,
                                                  int2* __restrict__ tmp) {
  __shared__ int cur[NB];
  int c = blockIdx.x, t = threadIdx.x;
  for (int i = t; i < NB; i += 256) cur[i] = bucketBase[i] + H[i * NC + c];
  __syncthreads();
  int e0 = c * CHUNK, e1 = min(e0 + CHUNK, N_EDGES);
  for (int e = e0 + t; e < e1; e += 256) {
    int d = dst[e];
    int pos = atomicAdd(&cur[d >> 8], 1);
    tmp[pos] = make_int2(src[e], d);
  }
}

// p5: per-bucket exact CSR: LDS histogram over 256 local nodes, scan, scatter
__global__ __launch_bounds__(256) void p5_build(const int2* __restrict__ tmp,
                                                const int* __restrict__ bucketBase,
                                                int* __restrict__ rowstart,
                                                int* __restrict__ csr_src) {
  __shared__ int hist[256];
  __shared__ int sh[256];
  __shared__ int cur[256];
  int b = blockIdx.x, t = threadIdx.x;
  int ebase = bucketBase[b], eend = bucketBase[b + 1];
  hist[t] = 0;
  __syncthreads();
  for (int e = ebase + t; e < eend; e += 256) atomicAdd(&hist[tmp[e].y & 255], 1);
  __syncthreads();
  int v = hist[t];
  sh[t] = v;
  __syncthreads();
  for (int off = 1; off < 256; off <<= 1) {
    int u = (t >= off) ? sh[t - off] : 0;
    __syncthreads();
    sh[t] += u;
    __syncthreads();
  }
  int excl = sh[t] - v;
  int node = b * 256 + t;
  if (node < N_NODES) rowstart[node] = ebase + excl;
  cur[t] = excl;
  __syncthreads();
  for (int e = ebase + t; e < eend; e += 256) {
    int2 p = tmp[e];
    int pos = ebase + atomicAdd(&cur[p.y & 255], 1);
    csr_src[pos] = p.x;
  }
  if (b == 0 && t == 0) rowstart[N_NODES] = N_EDGES;
}

// ---------------- GEMM: C[N,128] = A[N,128] @ W[128,128], fused el/er ----------------
__global__ __launch_bounds__(256) void gemm128_elr(const float* __restrict__ A,
                                                   const float* __restrict__ W,
                                                   const float* __restrict__ al,
                                                   const float* __restrict__ ar,
                                                   float* __restrict__ C,
                                                   float* __restrict__ el,
                                                   float* __restrict__ er, int N) {
  __shared__ float Ws[128 * 128];
  __shared__ float As[64 * 132];
  __shared__ float als[128], ars[128];
  int tid = threadIdx.x;
  int rowBase = blockIdx.x * 64;

  if (tid < 128) { als[tid] = al[tid]; ars[tid] = ar[tid]; }

  const float4* W4 = (const float4*)W;
  float4* Ws4 = (float4*)Ws;
#pragma unroll
  for (int i = 0; i < 16; i++) Ws4[tid + 256 * i] = W4[tid + 256 * i];

#pragma unroll
  for (int j = 0; j < 8; j++) {
    int v = tid + 256 * j;
    int r = v >> 5, c4 = v & 31;
    int gr = rowBase + r;
    float4 val = (gr < N) ? ((const float4*)A)[gr * 32 + c4] : make_float4(0.f, 0.f, 0.f, 0.f);
    *(float4*)&As[r * 132 + c4 * 4] = val;
  }
  __syncthreads();

  int rg = tid >> 4, cg = tid & 15;
  float acc[4][8] = {};
#pragma unroll 4
  for (int k = 0; k < 128; k++) {
    float a[4];
#pragma unroll
    for (int i = 0; i < 4; i++) a[i] = As[(rg + 16 * i) * 132 + k];
    float4 w0 = *(const float4*)&Ws[k * 128 + cg * 8];
    float4 w1 = *(const float4*)&Ws[k * 128 + cg * 8 + 4];
    float w[8] = {w0.x, w0.y, w0.z, w0.w, w1.x, w1.y, w1.z, w1.w};
#pragma unroll
    for (int i = 0; i < 4; i++)
#pragma unroll
      for (int j = 0; j < 8; j++) acc[i][j] = fmaf(a[i], w[j], acc[i][j]);
  }

  float alr[8], arr[8];
#pragma unroll
  for (int j = 0; j < 8; j++) { alr[j] = als[cg * 8 + j]; arr[j] = ars[cg * 8 + j]; }

#pragma unroll
  for (int i = 0; i < 4; i++) {
    int r = rowBase + rg + 16 * i;
    float pel = 0.f, per = 0.f;
#pragma unroll
    for (int j = 0; j < 8; j++) {
      pel = fmaf(acc[i][j], alr[j], pel);
      per = fmaf(acc[i][j], arr[j], per);
    }
    pel += __shfl_xor(pel, 1, 64); pel += __shfl_xor(pel, 2, 64);
    per += __shfl_xor(per, 1, 64); per += __shfl_xor(per, 2, 64);
    if (r < N) {
      float4 o0 = make_float4(acc[i][0], acc[i][1], acc[i][2], acc[i][3]);
      float4 o1 = make_float4(acc[i][4], acc[i][5], acc[i][6], acc[i][7]);
      *(float4*)&C[r * 128 + cg * 8] = o0;
      *(float4*)&C[r * 128 + cg * 8 + 4] = o1;
      if ((cg & 3) == 0) {
        int hd = cg >> 2;
        el[r * 4 + hd] = pel;
        er[r * 4 + hd] = per;
      }
    }
  }
}

// ---------------- per-node softmax stats + normalized attention ----------------
__global__ __launch_bounds__(256) void stats_att_kernel(const float* __restrict__ el,
                                                        const float* __restrict__ er,
                                                        const int* __restrict__ rowstart,
                                                        const int* __restrict__ csr_src,
                                                        float* __restrict__ att) {
  int n = (blockIdx.x * 256 + threadIdx.x) >> 6;
  int lane = threadIdx.x & 63;
  if (n >= N_NODES) return;
  int base = rowstart[n];
  int deg = rowstart[n + 1] - base;
  if (deg == 0) return;
  float4 erv = *(const float4*)&er[n * 4];
  float m0 = -INFINITY, m1 = -INFINITY, m2 = -INFINITY, m3 = -INFINITY;
  float l0 = 0.f, l1 = 0.f, l2 = 0.f, l3 = 0.f;

  for (int c0 = 0; c0 < deg; c0 += 64) {
    int e = c0 + lane;
    bool act = e < deg;
    int s = act ? csr_src[base + e] : 0;
    float sc0 = -INFINITY, sc1 = -INFINITY, sc2 = -INFINITY, sc3 = -INFINITY;
    if (act) {
      float4 elv = *(const float4*)&el[s * 4];
      sc0 = lrelu(elv.x + erv.x); sc1 = lrelu(elv.y + erv.y);
      sc2 = lrelu(elv.z + erv.z); sc3 = lrelu(elv.w + erv.w);
    }
    float nm0 = fmaxf(m0, wred_max(sc0));
    float nm1 = fmaxf(m1, wred_max(sc1));
    float nm2 = fmaxf(m2, wred_max(sc2));
    float nm3 = fmaxf(m3, wred_max(sc3));
    float p0 = act ? __expf(sc0 - nm0) : 0.f;
    float p1 = act ? __expf(sc1 - nm1) : 0.f;
    float p2 = act ? __expf(sc2 - nm2) : 0.f;
    float p3 = act ? __expf(sc3 - nm3) : 0.f;
    float cs0 = wred_sum(p0), cs1 = wred_sum(p1), cs2 = wred_sum(p2), cs3 = wred_sum(p3);
    l0 = l0 * __expf(m0 - nm0) + cs0; m0 = nm0;
    l1 = l1 * __expf(m1 - nm1) + cs1; m1 = nm1;
    l2 = l2 * __expf(m2 - nm2) + cs2; m2 = nm2;
    l3 = l3 * __expf(m3 - nm3) + cs3; m3 = nm3;
  }
  float r0 = 1.f / l0, r1 = 1.f / l1, r2 = 1.f / l2, r3 = 1.f / l3;

  for (int c0 = 0; c0 < deg; c0 += 64) {
    int e = c0 + lane;
    if (e < deg) {
      int s = csr_src[base + e];
      float4 elv = *(const float4*)&el[s * 4];
      float4 a;
      a.x = __expf(lrelu(elv.x + erv.x) - m0) * r0;
      a.y = __expf(lrelu(elv.y + erv.y) - m1) * r1;
      a.z = __expf(lrelu(elv.z + erv.z) - m2) * r2;
      a.w = __expf(lrelu(elv.w + erv.w) - m3) * r3;
      *(float4*)&att[(size_t)(base + e) * 4] = a;
    }
  }
}

// ------- aggregation: 2 nodes/wave, 32 lanes x float4, predicated unroll-8 -------
__global__ __launch_bounds__(256) void aggregate(const float* __restrict__ h,
                                                 const float* __restrict__ att,
                                                 const int* __restrict__ rowstart,
                                                 const int* __restrict__ csr_src,
                                                 const float* __restrict__ bias,
                                                 float* __restrict__ out) {
  int wv = (blockIdx.x * 256 + threadIdx.x) >> 6;
  int lane = threadIdx.x & 63;
  int half = lane >> 5;
  int l = lane & 31;
  int n = wv * 2 + half;
  if (n >= N_NODES) return;
  int base = rowstart[n];
  int end = rowstart[n + 1];
  int f0 = l * 4;
  int head = l >> 3;
  float4 acc = make_float4(0.f, 0.f, 0.f, 0.f);

  int last = end - 1;
  for (int e = base; e < end; e += 8) {
    int idx[8];
    float a[8];
#pragma unroll
    for (int i = 0; i < 8; i++) {
      int ei = e + i;
      int ec = min(ei, last);
      idx[i] = csr_src[ec];
      a[i] = (ei < end) ? att[(size_t)ec * 4 + head] : 0.f;
    }
    float4 hv[8];
#pragma unroll
    for (int i = 0; i < 8; i++) hv[i] = *(const float4*)&h[(size_t)idx[i] * 128 + f0];
#pragma unroll
    for (int i = 0; i < 8; i++) {
      acc.x = fmaf(hv[i].x, a[i], acc.x);
      acc.y = fmaf(hv[i].y, a[i], acc.y);
      acc.z = fmaf(hv[i].z, a[i], acc.z);
      acc.w = fmaf(hv[i].w, a[i], acc.w);
    }
  }
  float4 bv = *(const float4*)&bias[f0];
  float4 o;
  o.x = eluf(acc.x + bv.x);
  o.y = eluf(acc.y + bv.y);
  o.z = eluf(acc.z + bv.z);
  o.w = eluf(acc.w + bv.w);
  *(float4*)&out[(size_t)n * 128 + f0] = o;
}

// ---------------- final linear: C[N,40] = A[N,128] @ Wo[128,40] + bo ----------------
__global__ __launch_bounds__(256) void gemm_out_k(const float* __restrict__ A,
                                                  const float* __restrict__ Wo,
                                                  const float* __restrict__ bo,
                                                  float* __restrict__ C, int N) {
  __shared__ float As[64 * 132];
  __shared__ float Ws[128 * 44];
  int tid = threadIdx.x;
  int rowBase = blockIdx.x * 64;
  for (int i = tid; i < 128 * 40; i += 256) {
    int r = i / 40, c = i % 40;
    Ws[r * 44 + c] = Wo[i];
  }
#pragma unroll
  for (int j = 0; j < 8; j++) {
    int v = tid + 256 * j;
    int r = v >> 5, c4 = v & 31;
    int gr = rowBase + r;
    float4 val = (gr < N) ? ((const float4*)A)[gr * 32 + c4] : make_float4(0.f, 0.f, 0.f, 0.f);
    *(float4*)&As[r * 132 + c4 * 4] = val;
  }
  __syncthreads();
  int rg = tid >> 4, cg = tid & 15;
  if (cg < 10) {
    float acc[4][4] = {};
#pragma unroll 4
    for (int k = 0; k < 128; k++) {
      float a[4];
#pragma unroll
      for (int i = 0; i < 4; i++) a[i] = As[(rg + 16 * i) * 132 + k];
      float4 w = *(const float4*)&Ws[k * 44 + cg * 4];
#pragma unroll
      for (int i = 0; i < 4; i++) {
        acc[i][0] = fmaf(a[i], w.x, acc[i][0]);
        acc[i][1] = fmaf(a[i], w.y, acc[i][1]);
        acc[i][2] = fmaf(a[i], w.z, acc[i][2]);
        acc[i][3] = fmaf(a[i], w.w, acc[i][3]);
      }
    }
    float4 bv = *(const float4*)&bo[cg * 4];
#pragma unroll
    for (int i = 0; i < 4; i++) {
      int r = rowBase + rg + 16 * i;
      if (r < N) {
        float4 o = make_float4(acc[i][0] + bv.x, acc[i][1] + bv.y,
                               acc[i][2] + bv.z, acc[i][3] + bv.w);
        *(float4*)&C[r * 40 + cg * 4] = o;
      }
    }
  }
}

extern "C" void kernel_launch(void* const* d_in, const int* in_sizes, int n_in,
                              void* d_out, int out_size, void* d_ws, size_t ws_size,
                              hipStream_t stream) {
  const float* x    = (const float*)d_in[0];
  const int*   src  = (const int*)d_in[1];
  const int*   dst  = (const int*)d_in[2];
  const float* W1   = (const float*)d_in[3];
  const float* al1  = (const float*)d_in[4];
  const float* ar1  = (const float*)d_in[5];
  const float* b1   = (const float*)d_in[6];
  const float* W2   = (const float*)d_in[7];
  const float* al2  = (const float*)d_in[8];
  const float* ar2  = (const float*)d_in[9];
  const float* b2   = (const float*)d_in[10];
  const float* Wout = (const float*)d_in[11];
  const float* bout = (const float*)d_in[12];
  float* out = (float*)d_out;

  const int N = N_NODES, E = N_EDGES;
  size_t off = 0;
  auto alloc = [&](size_t bytes) {
    void* p = (char*)d_ws + off;
    off += (bytes + 255) & ~(size_t)255;
    return p;
  };
  float* h   = (float*)alloc((size_t)N * 128 * 4);
  float* o   = (float*)alloc((size_t)N * 128 * 4);
  float* el  = (float*)alloc((size_t)N * 4 * 4);
  float* er  = (float*)alloc((size_t)N * 4 * 4);
  float* att = (float*)alloc((size_t)E * 4 * 4);
  int* rowstart   = (int*)alloc((size_t)(N + 1) * 4);
  int* H          = (int*)alloc((size_t)NB * NC * 4);
  int* colTotal   = (int*)alloc((size_t)NB * 4);
  int* bucketBase = (int*)alloc((size_t)(NB + 1) * 4);
  int2* tmp       = (int2*)alloc((size_t)E * 8);
  int* csr_src    = (int*)alloc((size_t)E * 4);
  (void)ws_size; (void)in_sizes; (void)n_in; (void)out_size;

  // CSR build (atomic-free counting sort)
  p1_hist<<<NC, 256, 0, stream>>>(dst, H);
  p2_colscan<<<NB, 256, 0, stream>>>(H, colTotal);
  p3_bucketscan<<<1, 512, 0, stream>>>(colTotal, bucketBase);
  p4_scatter<<<NC, 256, 0, stream>>>(src, dst, H, bucketBase, tmp);
  p5_build<<<NB, 256, 0, stream>>>(tmp, bucketBase, rowstart, csr_src);

  int gemmGrid = (N + 63) / 64;
  int nodeWaveGrid = (N * 64 + 255) / 256;           // 1 node per wave (stats)
  int aggGrid = ((N + 1) / 2 * 64 + 255) / 256;      // 2 nodes per wave (aggregate)

  // layer 1
  gemm128_elr<<<gemmGrid, 256, 0, stream>>>(x, W1, al1, ar1, h, el, er, N);
  stats_att_kernel<<<nodeWaveGrid, 256, 0, stream>>>(el, er, rowstart, csr_src, att);
  aggregate<<<aggGrid, 256, 0, stream>>>(h, att, rowstart, csr_src, b1, o);

  // layer 2 (h reused as the GEMM output buffer)
  gemm128_elr<<<gemmGrid, 256, 0, stream>>>(o, W2, al2, ar2, h, el, er, N);
  stats_att_kernel<<<nodeWaveGrid, 256, 0, stream>>>(el, er, rowstart, csr_src, att);
  aggregate<<<aggGrid, 256, 0, stream>>>(h, att, rowstart, csr_src, b2, o);

  // output linear
  gemm_out_k<<<gemmGrid, 256, 0, stream>>>(o, Wout, bout, out, N);
}

// Round 6
// 479.562 us; speedup vs baseline: 2.4638x; 1.2461x over previous
//
#include <hip/hip_runtime.h>
#include <hip/hip_fp16.h>
#include <math.h>

#define N_NODES 100000
#define N_EDGES 1600000
#define NEG_SLOPE 0.2f

#define NB ((N_NODES + 255) / 256)          // 391 level-1 buckets (256 nodes each)
#define NC 256                              // edge chunks
#define CHUNK ((N_EDGES + NC - 1) / NC)     // 6250 edges per chunk

__device__ __forceinline__ float lrelu(float x) { return x > 0.f ? x : NEG_SLOPE * x; }
__device__ __forceinline__ float eluf(float x)  { return x > 0.f ? x : expm1f(x); }

__device__ __forceinline__ float wred_max(float v) {
#pragma unroll
  for (int i = 1; i < 64; i <<= 1) v = fmaxf(v, __shfl_xor(v, i, 64));
  return v;
}
__device__ __forceinline__ float wred_sum(float v) {
#pragma unroll
  for (int i = 1; i < 64; i <<= 1) v += __shfl_xor(v, i, 64);
  return v;
}

// ======== atomic-free CSR build: two-level counting sort by dst ========

__global__ __launch_bounds__(256) void p1_hist(const int* __restrict__ dst,
                                               int* __restrict__ H) {
  __shared__ int hist[NB];
  int c = blockIdx.x, t = threadIdx.x;
  for (int i = t; i < NB; i += 256) hist[i] = 0;
  __syncthreads();
  int e0 = c * CHUNK, e1 = min(e0 + CHUNK, N_EDGES);
  for (int e = e0 + t; e < e1; e += 256) atomicAdd(&hist[dst[e] >> 8], 1);
  __syncthreads();
  for (int i = t; i < NB; i += 256) H[i * NC + c] = hist[i];
}

__global__ __launch_bounds__(256) void p2_colscan(int* __restrict__ H,
                                                  int* __restrict__ colTotal) {
  __shared__ int sh[256];
  int b = blockIdx.x, t = threadIdx.x;
  int v = H[b * NC + t];
  sh[t] = v;
  __syncthreads();
  for (int off = 1; off < 256; off <<= 1) {
    int u = (t >= off) ? sh[t - off] : 0;
    __syncthreads();
    sh[t] += u;
    __syncthreads();
  }
  H[b * NC + t] = sh[t] - v;  // exclusive
  if (t == 255) colTotal[b] = sh[255];
}

__global__ __launch_bounds__(512) void p3_bucketscan(const int* __restrict__ colTotal,
                                                     int* __restrict__ bucketBase) {
  __shared__ int sh[512];
  int t = threadIdx.x;
  int v = (t < NB) ? colTotal[t] : 0;
  sh[t] = v;
  __syncthreads();
  for (int off = 1; off < 512; off <<= 1) {
    int u = (t >= off) ? sh[t - off] : 0;
    __syncthreads();
    sh[t] += u;
    __syncthreads();
  }
  if (t < NB) bucketBase[t] = sh[t] - v;
  if (t == NB - 1) bucketBase[NB] = sh[t];  // == N_EDGES
}

__global__ __launch_bounds__(256) void p4_scatter(const int* __restrict__ src,
                                                  const int* __restrict__ dst,
                                                  const int* __restrict__ H,
                                                  const int* __restrict__ bucketBase,
                                                  int2* __restrict__ tmp) {
  __shared__ int cur[NB];
  int c = blockIdx.x, t = threadIdx.x;
  for (int i = t; i < NB; i += 256) cur[i] = bucketBase[i] + H[i * NC + c];
  __syncthreads();
  int e0 = c * CHUNK, e1 = min(e0 + CHUNK, N_EDGES);
  for (int e = e0 + t; e < e1; e += 256) {
    int d = dst[e];
    int pos = atomicAdd(&cur[d >> 8], 1);
    tmp[pos] = make_int2(src[e], d);
  }
}

__global__ __launch_bounds__(256) void p5_build(const int2* __restrict__ tmp,
                                                const int* __restrict__ bucketBase,
                                                int* __restrict__ rowstart,
                                                int* __restrict__ csr_src) {
  __shared__ int hist[256];
  __shared__ int sh[256];
  __shared__ int cur[256];
  int b = blockIdx.x, t = threadIdx.x;
  int ebase = bucketBase[b], eend = bucketBase[b + 1];
  hist[t] = 0;
  __syncthreads();
  for (int e = ebase + t; e < eend; e += 256) atomicAdd(&hist[tmp[e].y & 255], 1);
  __syncthreads();
  int v = hist[t];
  sh[t] = v;
  __syncthreads();
  for (int off = 1; off < 256; off <<= 1) {
    int u = (t >= off) ? sh[t - off] : 0;
    __syncthreads();
    sh[t] += u;
    __syncthreads();
  }
  int excl = sh[t] - v;
  int node = b * 256 + t;
  if (node < N_NODES) rowstart[node] = ebase + excl;
  cur[t] = excl;
  __syncthreads();
  for (int e = ebase + t; e < eend; e += 256) {
    int2 p = tmp[e];
    int pos = ebase + atomicAdd(&cur[p.y & 255], 1);
    csr_src[pos] = p.x;
  }
  if (b == 0 && t == 0) rowstart[N_NODES] = N_EDGES;
}

// ------- GEMM: Chalf[N,128] = A[N,128] @ W[128,128] (fp16 out), fused el/er -------
// h is only consumed as message values in aggregate -> fp16 storage halves the
// random-gather traffic. el/er computed here from fp32 accumulators.
__global__ __launch_bounds__(256) void gemm128_elr(const float* __restrict__ A,
                                                   const float* __restrict__ W,
                                                   const float* __restrict__ al,
                                                   const float* __restrict__ ar,
                                                   __half* __restrict__ C,
                                                   float* __restrict__ el,
                                                   float* __restrict__ er, int N) {
  __shared__ float Ws[128 * 128];
  __shared__ float As[64 * 132];
  __shared__ float als[128], ars[128];
  int tid = threadIdx.x;
  int rowBase = blockIdx.x * 64;

  if (tid < 128) { als[tid] = al[tid]; ars[tid] = ar[tid]; }

  const float4* W4 = (const float4*)W;
  float4* Ws4 = (float4*)Ws;
#pragma unroll
  for (int i = 0; i < 16; i++) Ws4[tid + 256 * i] = W4[tid + 256 * i];

#pragma unroll
  for (int j = 0; j < 8; j++) {
    int v = tid + 256 * j;
    int r = v >> 5, c4 = v & 31;
    int gr = rowBase + r;
    float4 val = (gr < N) ? ((const float4*)A)[gr * 32 + c4] : make_float4(0.f, 0.f, 0.f, 0.f);
    *(float4*)&As[r * 132 + c4 * 4] = val;
  }
  __syncthreads();

  int rg = tid >> 4, cg = tid & 15;
  float acc[4][8] = {};
#pragma unroll 4
  for (int k = 0; k < 128; k++) {
    float a[4];
#pragma unroll
    for (int i = 0; i < 4; i++) a[i] = As[(rg + 16 * i) * 132 + k];
    float4 w0 = *(const float4*)&Ws[k * 128 + cg * 8];
    float4 w1 = *(const float4*)&Ws[k * 128 + cg * 8 + 4];
    float w[8] = {w0.x, w0.y, w0.z, w0.w, w1.x, w1.y, w1.z, w1.w};
#pragma unroll
    for (int i = 0; i < 4; i++)
#pragma unroll
      for (int j = 0; j < 8; j++) acc[i][j] = fmaf(a[i], w[j], acc[i][j]);
  }

  float alr[8], arr[8];
#pragma unroll
  for (int j = 0; j < 8; j++) { alr[j] = als[cg * 8 + j]; arr[j] = ars[cg * 8 + j]; }

#pragma unroll
  for (int i = 0; i < 4; i++) {
    int r = rowBase + rg + 16 * i;
    float pel = 0.f, per = 0.f;
#pragma unroll
    for (int j = 0; j < 8; j++) {
      pel = fmaf(acc[i][j], alr[j], pel);
      per = fmaf(acc[i][j], arr[j], per);
    }
    pel += __shfl_xor(pel, 1, 64); pel += __shfl_xor(pel, 2, 64);
    per += __shfl_xor(per, 1, 64); per += __shfl_xor(per, 2, 64);
    if (r < N) {
      __half2 pk[4];
      pk[0] = __float22half2_rn(make_float2(acc[i][0], acc[i][1]));
      pk[1] = __float22half2_rn(make_float2(acc[i][2], acc[i][3]));
      pk[2] = __float22half2_rn(make_float2(acc[i][4], acc[i][5]));
      pk[3] = __float22half2_rn(make_float2(acc[i][6], acc[i][7]));
      *(float4*)&C[(size_t)r * 128 + cg * 8] = *(float4*)pk;  // 8 halfs = 16 B
      if ((cg & 3) == 0) {
        int hd = cg >> 2;
        el[r * 4 + hd] = pel;
        er[r * 4 + hd] = per;
      }
    }
  }
}

// ---------------- per-node softmax stats + normalized attention ----------------
__global__ __launch_bounds__(256) void stats_att_kernel(const float* __restrict__ el,
                                                        const float* __restrict__ er,
                                                        const int* __restrict__ rowstart,
                                                        const int* __restrict__ csr_src,
                                                        float* __restrict__ att) {
  int n = (blockIdx.x * 256 + threadIdx.x) >> 6;
  int lane = threadIdx.x & 63;
  if (n >= N_NODES) return;
  int base = rowstart[n];
  int deg = rowstart[n + 1] - base;
  if (deg == 0) return;
  float4 erv = *(const float4*)&er[n * 4];
  float m0 = -INFINITY, m1 = -INFINITY, m2 = -INFINITY, m3 = -INFINITY;
  float l0 = 0.f, l1 = 0.f, l2 = 0.f, l3 = 0.f;

  for (int c0 = 0; c0 < deg; c0 += 64) {
    int e = c0 + lane;
    bool act = e < deg;
    int s = act ? csr_src[base + e] : 0;
    float sc0 = -INFINITY, sc1 = -INFINITY, sc2 = -INFINITY, sc3 = -INFINITY;
    if (act) {
      float4 elv = *(const float4*)&el[s * 4];
      sc0 = lrelu(elv.x + erv.x); sc1 = lrelu(elv.y + erv.y);
      sc2 = lrelu(elv.z + erv.z); sc3 = lrelu(elv.w + erv.w);
    }
    float nm0 = fmaxf(m0, wred_max(sc0));
    float nm1 = fmaxf(m1, wred_max(sc1));
    float nm2 = fmaxf(m2, wred_max(sc2));
    float nm3 = fmaxf(m3, wred_max(sc3));
    float p0 = act ? __expf(sc0 - nm0) : 0.f;
    float p1 = act ? __expf(sc1 - nm1) : 0.f;
    float p2 = act ? __expf(sc2 - nm2) : 0.f;
    float p3 = act ? __expf(sc3 - nm3) : 0.f;
    float cs0 = wred_sum(p0), cs1 = wred_sum(p1), cs2 = wred_sum(p2), cs3 = wred_sum(p3);
    l0 = l0 * __expf(m0 - nm0) + cs0; m0 = nm0;
    l1 = l1 * __expf(m1 - nm1) + cs1; m1 = nm1;
    l2 = l2 * __expf(m2 - nm2) + cs2; m2 = nm2;
    l3 = l3 * __expf(m3 - nm3) + cs3; m3 = nm3;
  }
  float r0 = 1.f / l0, r1 = 1.f / l1, r2 = 1.f / l2, r3 = 1.f / l3;

  for (int c0 = 0; c0 < deg; c0 += 64) {
    int e = c0 + lane;
    if (e < deg) {
      int s = csr_src[base + e];
      float4 elv = *(const float4*)&el[s * 4];
      float4 a;
      a.x = __expf(lrelu(elv.x + erv.x) - m0) * r0;
      a.y = __expf(lrelu(elv.y + erv.y) - m1) * r1;
      a.z = __expf(lrelu(elv.z + erv.z) - m2) * r2;
      a.w = __expf(lrelu(elv.w + erv.w) - m3) * r3;
      *(float4*)&att[(size_t)(base + e) * 4] = a;
    }
  }
}

// --- aggregation: 2 nodes/wave, 32 lanes x 4 fp16 feats, predicated unroll-8 ---
__global__ __launch_bounds__(256) void aggregate(const __half* __restrict__ h,
                                                 const float* __restrict__ att,
                                                 const int* __restrict__ rowstart,
                                                 const int* __restrict__ csr_src,
                                                 const float* __restrict__ bias,
                                                 float* __restrict__ out) {
  int wv = (blockIdx.x * 256 + threadIdx.x) >> 6;
  int lane = threadIdx.x & 63;
  int half_ = lane >> 5;
  int l = lane & 31;
  int n = wv * 2 + half_;
  if (n >= N_NODES) return;
  int base = rowstart[n];
  int end = rowstart[n + 1];
  int f0 = l * 4;
  int head = l >> 3;
  float4 acc = make_float4(0.f, 0.f, 0.f, 0.f);

  int last = end - 1;
  for (int e = base; e < end; e += 8) {
    int idx[8];
    float a[8];
#pragma unroll
    for (int i = 0; i < 8; i++) {
      int ei = e + i;
      int ec = min(ei, last);
      idx[i] = csr_src[ec];
      a[i] = (ei < end) ? att[(size_t)ec * 4 + head] : 0.f;
    }
    float2 raw[8];
#pragma unroll
    for (int i = 0; i < 8; i++)
      raw[i] = *(const float2*)&h[(size_t)idx[i] * 128 + f0];  // 4 halfs = 8 B
#pragma unroll
    for (int i = 0; i < 8; i++) {
      const __half2* hp = (const __half2*)&raw[i];
      float2 lo = __half22float2(hp[0]);
      float2 hi = __half22float2(hp[1]);
      acc.x = fmaf(lo.x, a[i], acc.x);
      acc.y = fmaf(lo.y, a[i], acc.y);
      acc.z = fmaf(hi.x, a[i], acc.z);
      acc.w = fmaf(hi.y, a[i], acc.w);
    }
  }
  float4 bv = *(const float4*)&bias[f0];
  float4 o;
  o.x = eluf(acc.x + bv.x);
  o.y = eluf(acc.y + bv.y);
  o.z = eluf(acc.z + bv.z);
  o.w = eluf(acc.w + bv.w);
  *(float4*)&out[(size_t)n * 128 + f0] = o;
}

// ---------------- final linear: C[N,40] = A[N,128] @ Wo[128,40] + bo ----------------
__global__ __launch_bounds__(256) void gemm_out_k(const float* __restrict__ A,
                                                  const float* __restrict__ Wo,
                                                  const float* __restrict__ bo,
                                                  float* __restrict__ C, int N) {
  __shared__ float As[64 * 132];
  __shared__ float Ws[128 * 44];
  int tid = threadIdx.x;
  int rowBase = blockIdx.x * 64;
  for (int i = tid; i < 128 * 40; i += 256) {
    int r = i / 40, c = i % 40;
    Ws[r * 44 + c] = Wo[i];
  }
#pragma unroll
  for (int j = 0; j < 8; j++) {
    int v = tid + 256 * j;
    int r = v >> 5, c4 = v & 31;
    int gr = rowBase + r;
    float4 val = (gr < N) ? ((const float4*)A)[gr * 32 + c4] : make_float4(0.f, 0.f, 0.f, 0.f);
    *(float4*)&As[r * 132 + c4 * 4] = val;
  }
  __syncthreads();
  int rg = tid >> 4, cg = tid & 15;
  if (cg < 10) {
    float acc[4][4] = {};
#pragma unroll 4
    for (int k = 0; k < 128; k++) {
      float a[4];
#pragma unroll
      for (int i = 0; i < 4; i++) a[i] = As[(rg + 16 * i) * 132 + k];
      float4 w = *(const float4*)&Ws[k * 44 + cg * 4];
#pragma unroll
      for (int i = 0; i < 4; i++) {
        acc[i][0] = fmaf(a[i], w.x, acc[i][0]);
        acc[i][1] = fmaf(a[i], w.y, acc[i][1]);
        acc[i][2] = fmaf(a[i], w.z, acc[i][2]);
        acc[i][3] = fmaf(a[i], w.w, acc[i][3]);
      }
    }
    float4 bv = *(const float4*)&bo[cg * 4];
#pragma unroll
    for (int i = 0; i < 4; i++) {
      int r = rowBase + rg + 16 * i;
      if (r < N) {
        float4 o = make_float4(acc[i][0] + bv.x, acc[i][1] + bv.y,
                               acc[i][2] + bv.z, acc[i][3] + bv.w);
        *(float4*)&C[r * 40 + cg * 4] = o;
      }
    }
  }
}

extern "C" void kernel_launch(void* const* d_in, const int* in_sizes, int n_in,
                              void* d_out, int out_size, void* d_ws, size_t ws_size,
                              hipStream_t stream) {
  const float* x    = (const float*)d_in[0];
  const int*   src  = (const int*)d_in[1];
  const int*   dst  = (const int*)d_in[2];
  const float* W1   = (const float*)d_in[3];
  const float* al1  = (const float*)d_in[4];
  const float* ar1  = (const float*)d_in[5];
  const float* b1   = (const float*)d_in[6];
  const float* W2   = (const float*)d_in[7];
  const float* al2  = (const float*)d_in[8];
  const float* ar2  = (const float*)d_in[9];
  const float* b2   = (const float*)d_in[10];
  const float* Wout = (const float*)d_in[11];
  const float* bout = (const float*)d_in[12];
  float* out = (float*)d_out;

  const int N = N_NODES, E = N_EDGES;
  size_t off = 0;
  auto alloc = [&](size_t bytes) {
    void* p = (char*)d_ws + off;
    off += (bytes + 255) & ~(size_t)255;
    return p;
  };
  __half* hh = (__half*)alloc((size_t)N * 128 * 2);
  float* o   = (float*)alloc((size_t)N * 128 * 4);
  float* el  = (float*)alloc((size_t)N * 4 * 4);
  float* er  = (float*)alloc((size_t)N * 4 * 4);
  float* att = (float*)alloc((size_t)E * 4 * 4);
  int* rowstart   = (int*)alloc((size_t)(N + 1) * 4);
  int* H          = (int*)alloc((size_t)NB * NC * 4);
  int* colTotal   = (int*)alloc((size_t)NB * 4);
  int* bucketBase = (int*)alloc((size_t)(NB + 1) * 4);
  int2* tmp       = (int2*)alloc((size_t)E * 8);
  int* csr_src    = (int*)alloc((size_t)E * 4);
  (void)ws_size; (void)in_sizes; (void)n_in; (void)out_size;

  // CSR build (atomic-free counting sort)
  p1_hist<<<NC, 256, 0, stream>>>(dst, H);
  p2_colscan<<<NB, 256, 0, stream>>>(H, colTotal);
  p3_bucketscan<<<1, 512, 0, stream>>>(colTotal, bucketBase);
  p4_scatter<<<NC, 256, 0, stream>>>(src, dst, H, bucketBase, tmp);
  p5_build<<<NB, 256, 0, stream>>>(tmp, bucketBase, rowstart, csr_src);

  int gemmGrid = (N + 63) / 64;
  int nodeWaveGrid = (N * 64 + 255) / 256;           // 1 node per wave (stats)
  int aggGrid = ((N + 1) / 2 * 64 + 255) / 256;      // 2 nodes per wave (aggregate)

  // layer 1
  gemm128_elr<<<gemmGrid, 256, 0, stream>>>(x, W1, al1, ar1, hh, el, er, N);
  stats_att_kernel<<<nodeWaveGrid, 256, 0, stream>>>(el, er, rowstart, csr_src, att);
  aggregate<<<aggGrid, 256, 0, stream>>>(hh, att, rowstart, csr_src, b1, o);

  // layer 2
  gemm128_elr<<<gemmGrid, 256, 0, stream>>>(o, W2, al2, ar2, hh, el, er, N);
  stats_att_kernel<<<nodeWaveGrid, 256, 0, stream>>>(el, er, rowstart, csr_src, att);
  aggregate<<<aggGrid, 256, 0, stream>>>(hh, att, rowstart, csr_src, b2, o);

  // output linear
  gemm_out_k<<<gemmGrid, 256, 0, stream>>>(o, Wout, bout, out, N);
}

// Round 7
// 439.781 us; speedup vs baseline: 2.6867x; 1.0905x over previous
//
#include <hip/hip_runtime.h>
#include <hip/hip_fp16.h>
#include <math.h>

#define N_NODES 100000
#define N_EDGES 1600000
#define NEG_SLOPE 0.2f

#define NB ((N_NODES + 255) / 256)          // 391 level-1 buckets (256 nodes each)
#define NC 256                              // edge chunks
#define CHUNK ((N_EDGES + NC - 1) / NC)     // 6250 edges per chunk

__device__ __forceinline__ float lrelu(float x) { return x > 0.f ? x : NEG_SLOPE * x; }
__device__ __forceinline__ float eluf(float x)  { return x > 0.f ? x : expm1f(x); }

__device__ __forceinline__ float wred_max(float v) {
#pragma unroll
  for (int i = 1; i < 64; i <<= 1) v = fmaxf(v, __shfl_xor(v, i, 64));
  return v;
}
__device__ __forceinline__ float wred_sum(float v) {
#pragma unroll
  for (int i = 1; i < 64; i <<= 1) v += __shfl_xor(v, i, 64);
  return v;
}

// ======== atomic-free CSR build: two-level counting sort by dst ========

__global__ __launch_bounds__(256) void p1_hist(const int* __restrict__ dst,
                                               int* __restrict__ H) {
  __shared__ int hist[NB];
  int c = blockIdx.x, t = threadIdx.x;
  for (int i = t; i < NB; i += 256) hist[i] = 0;
  __syncthreads();
  int e0 = c * CHUNK, e1 = min(e0 + CHUNK, N_EDGES);
  for (int e = e0 + t; e < e1; e += 256) atomicAdd(&hist[dst[e] >> 8], 1);
  __syncthreads();
  for (int i = t; i < NB; i += 256) H[i * NC + c] = hist[i];
}

__global__ __launch_bounds__(256) void p2_colscan(int* __restrict__ H,
                                                  int* __restrict__ colTotal) {
  __shared__ int sh[256];
  int b = blockIdx.x, t = threadIdx.x;
  int v = H[b * NC + t];
  sh[t] = v;
  __syncthreads();
  for (int off = 1; off < 256; off <<= 1) {
    int u = (t >= off) ? sh[t - off] : 0;
    __syncthreads();
    sh[t] += u;
    __syncthreads();
  }
  H[b * NC + t] = sh[t] - v;  // exclusive
  if (t == 255) colTotal[b] = sh[255];
}

__global__ __launch_bounds__(512) void p3_bucketscan(const int* __restrict__ colTotal,
                                                     int* __restrict__ bucketBase) {
  __shared__ int sh[512];
  int t = threadIdx.x;
  int v = (t < NB) ? colTotal[t] : 0;
  sh[t] = v;
  __syncthreads();
  for (int off = 1; off < 512; off <<= 1) {
    int u = (t >= off) ? sh[t - off] : 0;
    __syncthreads();
    sh[t] += u;
    __syncthreads();
  }
  if (t < NB) bucketBase[t] = sh[t] - v;
  if (t == NB - 1) bucketBase[NB] = sh[t];  // == N_EDGES
}

__global__ __launch_bounds__(256) void p4_scatter(const int* __restrict__ src,
                                                  const int* __restrict__ dst,
                                                  const int* __restrict__ H,
                                                  const int* __restrict__ bucketBase,
                                                  int2* __restrict__ tmp) {
  __shared__ int cur[NB];
  int c = blockIdx.x, t = threadIdx.x;
  for (int i = t; i < NB; i += 256) cur[i] = bucketBase[i] + H[i * NC + c];
  __syncthreads();
  int e0 = c * CHUNK, e1 = min(e0 + CHUNK, N_EDGES);
  for (int e = e0 + t; e < e1; e += 256) {
    int d = dst[e];
    int pos = atomicAdd(&cur[d >> 8], 1);
    tmp[pos] = make_int2(src[e], d);
  }
}

__global__ __launch_bounds__(256) void p5_build(const int2* __restrict__ tmp,
                                                const int* __restrict__ bucketBase,
                                                int* __restrict__ rowstart,
                                                int* __restrict__ csr_src) {
  __shared__ int hist[256];
  __shared__ int sh[256];
  __shared__ int cur[256];
  int b = blockIdx.x, t = threadIdx.x;
  int ebase = bucketBase[b], eend = bucketBase[b + 1];
  hist[t] = 0;
  __syncthreads();
  for (int e = ebase + t; e < eend; e += 256) atomicAdd(&hist[tmp[e].y & 255], 1);
  __syncthreads();
  int v = hist[t];
  sh[t] = v;
  __syncthreads();
  for (int off = 1; off < 256; off <<= 1) {
    int u = (t >= off) ? sh[t - off] : 0;
    __syncthreads();
    sh[t] += u;
    __syncthreads();
  }
  int excl = sh[t] - v;
  int node = b * 256 + t;
  if (node < N_NODES) rowstart[node] = ebase + excl;
  cur[t] = excl;
  __syncthreads();
  for (int e = ebase + t; e < eend; e += 256) {
    int2 p = tmp[e];
    int pos = ebase + atomicAdd(&cur[p.y & 255], 1);
    csr_src[pos] = p.x;
  }
  if (b == 0 && t == 0) rowstart[N_NODES] = N_EDGES;
}

// ======== GEMM: Chalf[N,128] = A[N,128] @ W[128,128] (fp16 out), fused el/er ========
// 128x128 tile, K-step 32: As[128][33] + Ws[32][132] ~ 34KB -> 4 blocks/CU.
// Thread (ty,tx): rows ty*8..+8, cols {4tx..+4, 64+4tx..+4}.
// Ws float4 reads: stride 16B -> 2-way bank alias = free. As b32 reads broadcast.
__global__ __launch_bounds__(256) void gemm128_elr(const float* __restrict__ A,
                                                   const float* __restrict__ W,
                                                   const float* __restrict__ al,
                                                   const float* __restrict__ ar,
                                                   __half* __restrict__ C,
                                                   float* __restrict__ el,
                                                   float* __restrict__ er, int N) {
  __shared__ float As[128 * 33];
  __shared__ float Ws[32 * 132];
  __shared__ float als[128], ars[128];
  int tid = threadIdx.x;
  int tx = tid & 15, ty = tid >> 4;
  int rowBase = blockIdx.x * 128;

  if (tid < 128) { als[tid] = al[tid]; ars[tid] = ar[tid]; }

  float acc0[8][4] = {};
  float acc1[8][4] = {};

  const float4* A4 = (const float4*)A;
  const float4* W4 = (const float4*)W;

  for (int kc = 0; kc < 128; kc += 32) {
    __syncthreads();  // protect LDS from previous iteration's readers
    // stage As: 128 rows x 32 K-cols (scalar stores: rows are 132B apart)
#pragma unroll
    for (int i = 0; i < 4; i++) {
      int v = tid + 256 * i;        // 0..1023
      int r = v >> 3, c4 = v & 7;   // row, float4-col
      int gr = rowBase + r;
      float4 val = (gr < N) ? A4[(size_t)gr * 32 + (kc >> 2) + c4]
                            : make_float4(0.f, 0.f, 0.f, 0.f);
      float* dstp = &As[r * 33 + c4 * 4];
      dstp[0] = val.x; dstp[1] = val.y; dstp[2] = val.z; dstp[3] = val.w;
    }
    // stage Ws: 32 K-rows x 128 cols (row stride 132 floats = 528B, 16B-aligned)
#pragma unroll
    for (int i = 0; i < 4; i++) {
      int v = tid + 256 * i;
      int r = v >> 5, c4 = v & 31;
      float4 val = W4[(size_t)(kc + r) * 32 + c4];
      *(float4*)&Ws[r * 132 + c4 * 4] = val;
    }
    __syncthreads();

#pragma unroll 4
    for (int k = 0; k < 32; k++) {
      float a[8];
#pragma unroll
      for (int i = 0; i < 8; i++) a[i] = As[(ty * 8 + i) * 33 + k];
      float4 w0 = *(const float4*)&Ws[k * 132 + tx * 4];
      float4 w1 = *(const float4*)&Ws[k * 132 + 64 + tx * 4];
#pragma unroll
      for (int i = 0; i < 8; i++) {
        acc0[i][0] = fmaf(a[i], w0.x, acc0[i][0]);
        acc0[i][1] = fmaf(a[i], w0.y, acc0[i][1]);
        acc0[i][2] = fmaf(a[i], w0.z, acc0[i][2]);
        acc0[i][3] = fmaf(a[i], w0.w, acc0[i][3]);
        acc1[i][0] = fmaf(a[i], w1.x, acc1[i][0]);
        acc1[i][1] = fmaf(a[i], w1.y, acc1[i][1]);
        acc1[i][2] = fmaf(a[i], w1.z, acc1[i][2]);
        acc1[i][3] = fmaf(a[i], w1.w, acc1[i][3]);
      }
    }
  }

  // epilogue: fp16 C write + fused el/er
  float alr0[4], arr0[4], alr1[4], arr1[4];
#pragma unroll
  for (int j = 0; j < 4; j++) {
    alr0[j] = als[4 * tx + j];      arr0[j] = ars[4 * tx + j];
    alr1[j] = als[64 + 4 * tx + j]; arr1[j] = ars[64 + 4 * tx + j];
  }
#pragma unroll
  for (int i = 0; i < 8; i++) {
    float pel0 = 0.f, per0 = 0.f, pel1 = 0.f, per1 = 0.f;
#pragma unroll
    for (int j = 0; j < 4; j++) {
      pel0 = fmaf(acc0[i][j], alr0[j], pel0);
      per0 = fmaf(acc0[i][j], arr0[j], per0);
      pel1 = fmaf(acc1[i][j], alr1[j], pel1);
      per1 = fmaf(acc1[i][j], arr1[j], per1);
    }
#pragma unroll
    for (int m = 1; m < 8; m <<= 1) {
      pel0 += __shfl_xor(pel0, m, 64);
      per0 += __shfl_xor(per0, m, 64);
      pel1 += __shfl_xor(pel1, m, 64);
      per1 += __shfl_xor(per1, m, 64);
    }
    int row = rowBase + ty * 8 + i;
    if (row < N) {
      __half2 p0 = __float22half2_rn(make_float2(acc0[i][0], acc0[i][1]));
      __half2 p1 = __float22half2_rn(make_float2(acc0[i][2], acc0[i][3]));
      __half2 q0 = __float22half2_rn(make_float2(acc1[i][0], acc1[i][1]));
      __half2 q1 = __float22half2_rn(make_float2(acc1[i][2], acc1[i][3]));
      float2 pk0, pk1;
      ((__half2*)&pk0)[0] = p0; ((__half2*)&pk0)[1] = p1;
      ((__half2*)&pk1)[0] = q0; ((__half2*)&pk1)[1] = q1;
      *(float2*)&C[(size_t)row * 128 + 4 * tx] = pk0;
      *(float2*)&C[(size_t)row * 128 + 64 + 4 * tx] = pk1;
      if ((tx & 7) == 0) {
        int hb = tx >> 3;  // 0 or 1
        el[row * 4 + hb] = pel0;     er[row * 4 + hb] = per0;
        el[row * 4 + 2 + hb] = pel1; er[row * 4 + 2 + hb] = per1;
      }
    }
  }
}

// ---------------- per-node softmax stats + normalized attention ----------------
__global__ __launch_bounds__(256) void stats_att_kernel(const float* __restrict__ el,
                                                        const float* __restrict__ er,
                                                        const int* __restrict__ rowstart,
                                                        const int* __restrict__ csr_src,
                                                        float* __restrict__ att) {
  int n = (blockIdx.x * 256 + threadIdx.x) >> 6;
  int lane = threadIdx.x & 63;
  if (n >= N_NODES) return;
  int base = rowstart[n];
  int deg = rowstart[n + 1] - base;
  if (deg == 0) return;
  float4 erv = *(const float4*)&er[n * 4];
  float m0 = -INFINITY, m1 = -INFINITY, m2 = -INFINITY, m3 = -INFINITY;
  float l0 = 0.f, l1 = 0.f, l2 = 0.f, l3 = 0.f;

  for (int c0 = 0; c0 < deg; c0 += 64) {
    int e = c0 + lane;
    bool act = e < deg;
    int s = act ? csr_src[base + e] : 0;
    float sc0 = -INFINITY, sc1 = -INFINITY, sc2 = -INFINITY, sc3 = -INFINITY;
    if (act) {
      float4 elv = *(const float4*)&el[s * 4];
      sc0 = lrelu(elv.x + erv.x); sc1 = lrelu(elv.y + erv.y);
      sc2 = lrelu(elv.z + erv.z); sc3 = lrelu(elv.w + erv.w);
    }
    float nm0 = fmaxf(m0, wred_max(sc0));
    float nm1 = fmaxf(m1, wred_max(sc1));
    float nm2 = fmaxf(m2, wred_max(sc2));
    float nm3 = fmaxf(m3, wred_max(sc3));
    float p0 = act ? __expf(sc0 - nm0) : 0.f;
    float p1 = act ? __expf(sc1 - nm1) : 0.f;
    float p2 = act ? __expf(sc2 - nm2) : 0.f;
    float p3 = act ? __expf(sc3 - nm3) : 0.f;
    float cs0 = wred_sum(p0), cs1 = wred_sum(p1), cs2 = wred_sum(p2), cs3 = wred_sum(p3);
    l0 = l0 * __expf(m0 - nm0) + cs0; m0 = nm0;
    l1 = l1 * __expf(m1 - nm1) + cs1; m1 = nm1;
    l2 = l2 * __expf(m2 - nm2) + cs2; m2 = nm2;
    l3 = l3 * __expf(m3 - nm3) + cs3; m3 = nm3;
  }
  float r0 = 1.f / l0, r1 = 1.f / l1, r2 = 1.f / l2, r3 = 1.f / l3;

  for (int c0 = 0; c0 < deg; c0 += 64) {
    int e = c0 + lane;
    if (e < deg) {
      int s = csr_src[base + e];
      float4 elv = *(const float4*)&el[s * 4];
      float4 a;
      a.x = __expf(lrelu(elv.x + erv.x) - m0) * r0;
      a.y = __expf(lrelu(elv.y + erv.y) - m1) * r1;
      a.z = __expf(lrelu(elv.z + erv.z) - m2) * r2;
      a.w = __expf(lrelu(elv.w + erv.w) - m3) * r3;
      *(float4*)&att[(size_t)(base + e) * 4] = a;
    }
  }
}

// --- aggregation: 2 nodes/wave, 32 lanes x 4 fp16 feats, predicated unroll-8 ---
__global__ __launch_bounds__(256) void aggregate(const __half* __restrict__ h,
                                                 const float* __restrict__ att,
                                                 const int* __restrict__ rowstart,
                                                 const int* __restrict__ csr_src,
                                                 const float* __restrict__ bias,
                                                 float* __restrict__ out) {
  int wv = (blockIdx.x * 256 + threadIdx.x) >> 6;
  int lane = threadIdx.x & 63;
  int half_ = lane >> 5;
  int l = lane & 31;
  int n = wv * 2 + half_;
  if (n >= N_NODES) return;
  int base = rowstart[n];
  int end = rowstart[n + 1];
  int f0 = l * 4;
  int head = l >> 3;
  float4 acc = make_float4(0.f, 0.f, 0.f, 0.f);

  int last = end - 1;
  for (int e = base; e < end; e += 8) {
    int idx[8];
    float a[8];
#pragma unroll
    for (int i = 0; i < 8; i++) {
      int ei = e + i;
      int ec = min(ei, last);
      idx[i] = csr_src[ec];
      a[i] = (ei < end) ? att[(size_t)ec * 4 + head] : 0.f;
    }
    float2 raw[8];
#pragma unroll
    for (int i = 0; i < 8; i++)
      raw[i] = *(const float2*)&h[(size_t)idx[i] * 128 + f0];  // 4 halfs = 8 B
#pragma unroll
    for (int i = 0; i < 8; i++) {
      const __half2* hp = (const __half2*)&raw[i];
      float2 lo = __half22float2(hp[0]);
      float2 hi = __half22float2(hp[1]);
      acc.x = fmaf(lo.x, a[i], acc.x);
      acc.y = fmaf(lo.y, a[i], acc.y);
      acc.z = fmaf(hi.x, a[i], acc.z);
      acc.w = fmaf(hi.y, a[i], acc.w);
    }
  }
  float4 bv = *(const float4*)&bias[f0];
  float4 o;
  o.x = eluf(acc.x + bv.x);
  o.y = eluf(acc.y + bv.y);
  o.z = eluf(acc.z + bv.z);
  o.w = eluf(acc.w + bv.w);
  *(float4*)&out[(size_t)n * 128 + f0] = o;
}

// ---------------- final linear: C[N,40] = A[N,128] @ Wo[128,40] + bo ----------------
__global__ __launch_bounds__(256) void gemm_out_k(const float* __restrict__ A,
                                                  const float* __restrict__ Wo,
                                                  const float* __restrict__ bo,
                                                  float* __restrict__ C, int N) {
  __shared__ float As[64 * 132];
  __shared__ float Ws[128 * 44];
  int tid = threadIdx.x;
  int rowBase = blockIdx.x * 64;
  for (int i = tid; i < 128 * 40; i += 256) {
    int r = i / 40, c = i % 40;
    Ws[r * 44 + c] = Wo[i];
  }
#pragma unroll
  for (int j = 0; j < 8; j++) {
    int v = tid + 256 * j;
    int r = v >> 5, c4 = v & 31;
    int gr = rowBase + r;
    float4 val = (gr < N) ? ((const float4*)A)[gr * 32 + c4] : make_float4(0.f, 0.f, 0.f, 0.f);
    *(float4*)&As[r * 132 + c4 * 4] = val;
  }
  __syncthreads();
  int rg = tid >> 4, cg = tid & 15;
  if (cg < 10) {
    float acc[4][4] = {};
#pragma unroll 4
    for (int k = 0; k < 128; k++) {
      float a[4];
#pragma unroll
      for (int i = 0; i < 4; i++) a[i] = As[(rg + 16 * i) * 132 + k];
      float4 w = *(const float4*)&Ws[k * 44 + cg * 4];
#pragma unroll
      for (int i = 0; i < 4; i++) {
        acc[i][0] = fmaf(a[i], w.x, acc[i][0]);
        acc[i][1] = fmaf(a[i], w.y, acc[i][1]);
        acc[i][2] = fmaf(a[i], w.z, acc[i][2]);
        acc[i][3] = fmaf(a[i], w.w, acc[i][3]);
      }
    }
    float4 bv = *(const float4*)&bo[cg * 4];
#pragma unroll
    for (int i = 0; i < 4; i++) {
      int r = rowBase + rg + 16 * i;
      if (r < N) {
        float4 o = make_float4(acc[i][0] + bv.x, acc[i][1] + bv.y,
                               acc[i][2] + bv.z, acc[i][3] + bv.w);
        *(float4*)&C[r * 40 + cg * 4] = o;
      }
    }
  }
}

extern "C" void kernel_launch(void* const* d_in, const int* in_sizes, int n_in,
                              void* d_out, int out_size, void* d_ws, size_t ws_size,
                              hipStream_t stream) {
  const float* x    = (const float*)d_in[0];
  const int*   src  = (const int*)d_in[1];
  const int*   dst  = (const int*)d_in[2];
  const float* W1   = (const float*)d_in[3];
  const float* al1  = (const float*)d_in[4];
  const float* ar1  = (const float*)d_in[5];
  const float* b1   = (const float*)d_in[6];
  const float* W2   = (const float*)d_in[7];
  const float* al2  = (const float*)d_in[8];
  const float* ar2  = (const float*)d_in[9];
  const float* b2   = (const float*)d_in[10];
  const float* Wout = (const float*)d_in[11];
  const float* bout = (const float*)d_in[12];
  float* out = (float*)d_out;

  const int N = N_NODES, E = N_EDGES;
  size_t off = 0;
  auto alloc = [&](size_t bytes) {
    void* p = (char*)d_ws + off;
    off += (bytes + 255) & ~(size_t)255;
    return p;
  };
  __half* hh = (__half*)alloc((size_t)N * 128 * 2);
  float* o   = (float*)alloc((size_t)N * 128 * 4);
  float* el  = (float*)alloc((size_t)N * 4 * 4);
  float* er  = (float*)alloc((size_t)N * 4 * 4);
  float* att = (float*)alloc((size_t)E * 4 * 4);
  int* rowstart   = (int*)alloc((size_t)(N + 1) * 4);
  int* H          = (int*)alloc((size_t)NB * NC * 4);
  int* colTotal   = (int*)alloc((size_t)NB * 4);
  int* bucketBase = (int*)alloc((size_t)(NB + 1) * 4);
  int2* tmp       = (int2*)alloc((size_t)E * 8);
  int* csr_src    = (int*)alloc((size_t)E * 4);
  (void)ws_size; (void)in_sizes; (void)n_in; (void)out_size;

  // CSR build (atomic-free counting sort)
  p1_hist<<<NC, 256, 0, stream>>>(dst, H);
  p2_colscan<<<NB, 256, 0, stream>>>(H, colTotal);
  p3_bucketscan<<<1, 512, 0, stream>>>(colTotal, bucketBase);
  p4_scatter<<<NC, 256, 0, stream>>>(src, dst, H, bucketBase, tmp);
  p5_build<<<NB, 256, 0, stream>>>(tmp, bucketBase, rowstart, csr_src);

  int gemmGrid = (N + 127) / 128;
  int outGrid  = (N + 63) / 64;
  int nodeWaveGrid = (N * 64 + 255) / 256;           // 1 node per wave (stats)
  int aggGrid = ((N + 1) / 2 * 64 + 255) / 256;      // 2 nodes per wave (aggregate)

  // layer 1
  gemm128_elr<<<gemmGrid, 256, 0, stream>>>(x, W1, al1, ar1, hh, el, er, N);
  stats_att_kernel<<<nodeWaveGrid, 256, 0, stream>>>(el, er, rowstart, csr_src, att);
  aggregate<<<aggGrid, 256, 0, stream>>>(hh, att, rowstart, csr_src, b1, o);

  // layer 2
  gemm128_elr<<<gemmGrid, 256, 0, stream>>>(o, W2, al2, ar2, hh, el, er, N);
  stats_att_kernel<<<nodeWaveGrid, 256, 0, stream>>>(el, er, rowstart, csr_src, att);
  aggregate<<<aggGrid, 256, 0, stream>>>(hh, att, rowstart, csr_src, b2, o);

  // output linear
  gemm_out_k<<<outGrid, 256, 0, stream>>>(o, Wout, bout, out, N);
}

// Round 8
// 356.476 us; speedup vs baseline: 3.3145x; 1.2337x over previous
//
#include <hip/hip_runtime.h>
#include <hip/hip_fp16.h>
#include <math.h>

#define N_NODES 100000
#define N_EDGES 1600000
#define NEG_SLOPE 0.2f

#define NB ((N_NODES + 255) / 256)          // 391 level-1 buckets (256 nodes each)
#define NC 256                              // edge chunks
#define CHUNK ((N_EDGES + NC - 1) / NC)     // 6250 edges per chunk

__device__ __forceinline__ float lrelu(float x) { return x > 0.f ? x : NEG_SLOPE * x; }
__device__ __forceinline__ float eluf(float x)  { return x > 0.f ? x : expm1f(x); }

// 32-lane reductions (2 independent nodes per wave; xor masks stay in-half)
__device__ __forceinline__ float wred32_max(float v) {
#pragma unroll
  for (int i = 1; i < 32; i <<= 1) v = fmaxf(v, __shfl_xor(v, i, 64));
  return v;
}
__device__ __forceinline__ float wred32_sum(float v) {
#pragma unroll
  for (int i = 1; i < 32; i <<= 1) v += __shfl_xor(v, i, 64);
  return v;
}

// ======== atomic-free CSR build: two-level counting sort by dst ========

__global__ __launch_bounds__(256) void p1_hist(const int* __restrict__ dst,
                                               int* __restrict__ H) {
  __shared__ int hist[NB];
  int c = blockIdx.x, t = threadIdx.x;
  for (int i = t; i < NB; i += 256) hist[i] = 0;
  __syncthreads();
  int e0 = c * CHUNK, e1 = min(e0 + CHUNK, N_EDGES);
  for (int e = e0 + t; e < e1; e += 256) atomicAdd(&hist[dst[e] >> 8], 1);
  __syncthreads();
  for (int i = t; i < NB; i += 256) H[i * NC + c] = hist[i];
}

__global__ __launch_bounds__(256) void p2_colscan(int* __restrict__ H,
                                                  int* __restrict__ colTotal) {
  __shared__ int sh[256];
  int b = blockIdx.x, t = threadIdx.x;
  int v = H[b * NC + t];
  sh[t] = v;
  __syncthreads();
  for (int off = 1; off < 256; off <<= 1) {
    int u = (t >= off) ? sh[t - off] : 0;
    __syncthreads();
    sh[t] += u;
    __syncthreads();
  }
  H[b * NC + t] = sh[t] - v;  // exclusive
  if (t == 255) colTotal[b] = sh[255];
}

__global__ __launch_bounds__(512) void p3_bucketscan(const int* __restrict__ colTotal,
                                                     int* __restrict__ bucketBase) {
  __shared__ int sh[512];
  int t = threadIdx.x;
  int v = (t < NB) ? colTotal[t] : 0;
  sh[t] = v;
  __syncthreads();
  for (int off = 1; off < 512; off <<= 1) {
    int u = (t >= off) ? sh[t - off] : 0;
    __syncthreads();
    sh[t] += u;
    __syncthreads();
  }
  if (t < NB) bucketBase[t] = sh[t] - v;
  if (t == NB - 1) bucketBase[NB] = sh[t];  // == N_EDGES
}

// tmp packs (src << 8) | (dst & 255): src < 2^24 so it fits one int
__global__ __launch_bounds__(256) void p4_scatter(const int* __restrict__ src,
                                                  const int* __restrict__ dst,
                                                  const int* __restrict__ H,
                                                  const int* __restrict__ bucketBase,
                                                  int* __restrict__ tmp) {
  __shared__ int cur[NB];
  int c = blockIdx.x, t = threadIdx.x;
  for (int i = t; i < NB; i += 256) cur[i] = bucketBase[i] + H[i * NC + c];
  __syncthreads();
  int e0 = c * CHUNK, e1 = min(e0 + CHUNK, N_EDGES);
  for (int e = e0 + t; e < e1; e += 256) {
    int d = dst[e];
    int pos = atomicAdd(&cur[d >> 8], 1);
    tmp[pos] = (src[e] << 8) | (d & 255);
  }
}

__global__ __launch_bounds__(256) void p5_build(const int* __restrict__ tmp,
                                                const int* __restrict__ bucketBase,
                                                int* __restrict__ rowstart,
                                                int* __restrict__ csr_src) {
  __shared__ int hist[256];
  __shared__ int sh[256];
  __shared__ int cur[256];
  int b = blockIdx.x, t = threadIdx.x;
  int ebase = bucketBase[b], eend = bucketBase[b + 1];
  hist[t] = 0;
  __syncthreads();
  for (int e = ebase + t; e < eend; e += 256) atomicAdd(&hist[tmp[e] & 255], 1);
  __syncthreads();
  int v = hist[t];
  sh[t] = v;
  __syncthreads();
  for (int off = 1; off < 256; off <<= 1) {
    int u = (t >= off) ? sh[t - off] : 0;
    __syncthreads();
    sh[t] += u;
    __syncthreads();
  }
  int excl = sh[t] - v;
  int node = b * 256 + t;
  if (node < N_NODES) rowstart[node] = ebase + excl;
  cur[t] = excl;
  __syncthreads();
  for (int e = ebase + t; e < eend; e += 256) {
    int p = tmp[e];
    int pos = ebase + atomicAdd(&cur[p & 255], 1);
    csr_src[pos] = p >> 8;
  }
  if (b == 0 && t == 0) rowstart[N_NODES] = N_EDGES;
}

// ======== GEMM: Chalf[N,128] = A[N,128] @ W[128,128] (fp16 out), fused el/er ========
// 64x128 tile, K-step 32: As[64][33] + Ws[32][132] ~ 26KB -> 6 blocks/CU, 1563 blocks.
// Thread (ty=tid>>4, tx=tid&15): rows ty*4..+4, cols {4tx..+4, 64+4tx..+4}.
__global__ __launch_bounds__(256) void gemm128_elr(const float* __restrict__ A,
                                                   const float* __restrict__ W,
                                                   const float* __restrict__ al,
                                                   const float* __restrict__ ar,
                                                   __half* __restrict__ C,
                                                   float* __restrict__ el,
                                                   float* __restrict__ er, int N) {
  __shared__ float As[64 * 33];
  __shared__ float Ws[32 * 132];
  __shared__ float als[128], ars[128];
  int tid = threadIdx.x;
  int tx = tid & 15, ty = tid >> 4;
  int rowBase = blockIdx.x * 64;

  if (tid < 128) { als[tid] = al[tid]; ars[tid] = ar[tid]; }

  float acc0[4][4] = {};
  float acc1[4][4] = {};

  const float4* A4 = (const float4*)A;
  const float4* W4 = (const float4*)W;

  for (int kc = 0; kc < 128; kc += 32) {
    __syncthreads();
    // stage As: 64 rows x 32 K-cols
#pragma unroll
    for (int i = 0; i < 2; i++) {
      int v = tid + 256 * i;        // 0..511
      int r = v >> 3, c4 = v & 7;
      int gr = rowBase + r;
      float4 val = (gr < N) ? A4[(size_t)gr * 32 + (kc >> 2) + c4]
                            : make_float4(0.f, 0.f, 0.f, 0.f);
      float* dstp = &As[r * 33 + c4 * 4];
      dstp[0] = val.x; dstp[1] = val.y; dstp[2] = val.z; dstp[3] = val.w;
    }
    // stage Ws: 32 K-rows x 128 cols
#pragma unroll
    for (int i = 0; i < 4; i++) {
      int v = tid + 256 * i;
      int r = v >> 5, c4 = v & 31;
      float4 val = W4[(size_t)(kc + r) * 32 + c4];
      *(float4*)&Ws[r * 132 + c4 * 4] = val;
    }
    __syncthreads();

#pragma unroll 4
    for (int k = 0; k < 32; k++) {
      float a[4];
#pragma unroll
      for (int i = 0; i < 4; i++) a[i] = As[(ty * 4 + i) * 33 + k];
      float4 w0 = *(const float4*)&Ws[k * 132 + tx * 4];
      float4 w1 = *(const float4*)&Ws[k * 132 + 64 + tx * 4];
#pragma unroll
      for (int i = 0; i < 4; i++) {
        acc0[i][0] = fmaf(a[i], w0.x, acc0[i][0]);
        acc0[i][1] = fmaf(a[i], w0.y, acc0[i][1]);
        acc0[i][2] = fmaf(a[i], w0.z, acc0[i][2]);
        acc0[i][3] = fmaf(a[i], w0.w, acc0[i][3]);
        acc1[i][0] = fmaf(a[i], w1.x, acc1[i][0]);
        acc1[i][1] = fmaf(a[i], w1.y, acc1[i][1]);
        acc1[i][2] = fmaf(a[i], w1.z, acc1[i][2]);
        acc1[i][3] = fmaf(a[i], w1.w, acc1[i][3]);
      }
    }
  }

  // epilogue: fp16 C write + fused el/er
  float alr0[4], arr0[4], alr1[4], arr1[4];
#pragma unroll
  for (int j = 0; j < 4; j++) {
    alr0[j] = als[4 * tx + j];      arr0[j] = ars[4 * tx + j];
    alr1[j] = als[64 + 4 * tx + j]; arr1[j] = ars[64 + 4 * tx + j];
  }
#pragma unroll
  for (int i = 0; i < 4; i++) {
    float pel0 = 0.f, per0 = 0.f, pel1 = 0.f, per1 = 0.f;
#pragma unroll
    for (int j = 0; j < 4; j++) {
      pel0 = fmaf(acc0[i][j], alr0[j], pel0);
      per0 = fmaf(acc0[i][j], arr0[j], per0);
      pel1 = fmaf(acc1[i][j], alr1[j], pel1);
      per1 = fmaf(acc1[i][j], arr1[j], per1);
    }
#pragma unroll
    for (int m = 1; m < 8; m <<= 1) {
      pel0 += __shfl_xor(pel0, m, 64);
      per0 += __shfl_xor(per0, m, 64);
      pel1 += __shfl_xor(pel1, m, 64);
      per1 += __shfl_xor(per1, m, 64);
    }
    int row = rowBase + ty * 4 + i;
    if (row < N) {
      __half2 p0 = __float22half2_rn(make_float2(acc0[i][0], acc0[i][1]));
      __half2 p1 = __float22half2_rn(make_float2(acc0[i][2], acc0[i][3]));
      __half2 q0 = __float22half2_rn(make_float2(acc1[i][0], acc1[i][1]));
      __half2 q1 = __float22half2_rn(make_float2(acc1[i][2], acc1[i][3]));
      float2 pk0, pk1;
      ((__half2*)&pk0)[0] = p0; ((__half2*)&pk0)[1] = p1;
      ((__half2*)&pk1)[0] = q0; ((__half2*)&pk1)[1] = q1;
      *(float2*)&C[(size_t)row * 128 + 4 * tx] = pk0;
      *(float2*)&C[(size_t)row * 128 + 64 + 4 * tx] = pk1;
      if ((tx & 7) == 0) {
        int hb = tx >> 3;  // 0 or 1
        el[row * 4 + hb] = pel0;     er[row * 4 + hb] = per0;
        el[row * 4 + 2 + hb] = pel1; er[row * 4 + 2 + hb] = per1;
      }
    }
  }
}

// ==== fused softmax + aggregation: 2 nodes/wave, 32 lanes x 4 fp16 feats ====
// pass 1: online max/sum per head over incoming edges (el gather, L2-resident)
// pass 2: w = exp(lrelu(el+er)-m) per edge in-register; acc += w*h; scale by 1/l.
__global__ __launch_bounds__(256) void agg_fused(const __half* __restrict__ h,
                                                 const float* __restrict__ el,
                                                 const float* __restrict__ er,
                                                 const int* __restrict__ rowstart,
                                                 const int* __restrict__ csr_src,
                                                 const float* __restrict__ bias,
                                                 float* __restrict__ out) {
  int wv = (blockIdx.x * 256 + threadIdx.x) >> 6;
  int lane = threadIdx.x & 63;
  int half_ = lane >> 5;
  int l = lane & 31;
  int n = wv * 2 + half_;
  if (n >= N_NODES) return;
  int base = rowstart[n];
  int end = rowstart[n + 1];
  int deg = end - base;
  int f0 = l * 4;
  int head = l >> 3;
  float4 acc = make_float4(0.f, 0.f, 0.f, 0.f);

  if (deg > 0) {
    float4 erv = *(const float4*)&er[n * 4];
    float m0 = -INFINITY, m1 = -INFINITY, m2 = -INFINITY, m3 = -INFINITY;
    float l0 = 0.f, l1 = 0.f, l2 = 0.f, l3 = 0.f;

    for (int c0 = 0; c0 < deg; c0 += 32) {
      int e = c0 + l;
      bool act = e < deg;
      int s = act ? csr_src[base + e] : 0;
      float4 elv = *(const float4*)&el[s * 4];
      float sc0 = act ? lrelu(elv.x + erv.x) : -INFINITY;
      float sc1 = act ? lrelu(elv.y + erv.y) : -INFINITY;
      float sc2 = act ? lrelu(elv.z + erv.z) : -INFINITY;
      float sc3 = act ? lrelu(elv.w + erv.w) : -INFINITY;
      float nm0 = fmaxf(m0, wred32_max(sc0));
      float nm1 = fmaxf(m1, wred32_max(sc1));
      float nm2 = fmaxf(m2, wred32_max(sc2));
      float nm3 = fmaxf(m3, wred32_max(sc3));
      float p0 = act ? __expf(sc0 - nm0) : 0.f;
      float p1 = act ? __expf(sc1 - nm1) : 0.f;
      float p2 = act ? __expf(sc2 - nm2) : 0.f;
      float p3 = act ? __expf(sc3 - nm3) : 0.f;
      float cs0 = wred32_sum(p0), cs1 = wred32_sum(p1);
      float cs2 = wred32_sum(p2), cs3 = wred32_sum(p3);
      l0 = l0 * __expf(m0 - nm0) + cs0; m0 = nm0;
      l1 = l1 * __expf(m1 - nm1) + cs1; m1 = nm1;
      l2 = l2 * __expf(m2 - nm2) + cs2; m2 = nm2;
      l3 = l3 * __expf(m3 - nm3) + cs3; m3 = nm3;
    }
    // per-lane head-selected stats
    float mh = (head == 0) ? m0 : (head == 1) ? m1 : (head == 2) ? m2 : m3;
    float lh = (head == 0) ? l0 : (head == 1) ? l1 : (head == 2) ? l2 : l3;
    float eh = (head == 0) ? erv.x : (head == 1) ? erv.y : (head == 2) ? erv.z : erv.w;
    float rh = 1.f / lh;

    int last = end - 1;
    for (int e = base; e < end; e += 8) {
      int idx[8];
      float w[8];
#pragma unroll
      for (int i = 0; i < 8; i++) {
        int ei = e + i;
        int ec = min(ei, last);
        idx[i] = csr_src[ec];
        float ev = el[idx[i] * 4 + head];      // L2-resident scalar gather
        float sc = lrelu(ev + eh);
        w[i] = (ei < end) ? __expf(sc - mh) : 0.f;
      }
      float2 raw[8];
#pragma unroll
      for (int i = 0; i < 8; i++)
        raw[i] = *(const float2*)&h[(size_t)idx[i] * 128 + f0];  // 4 halfs = 8 B
#pragma unroll
      for (int i = 0; i < 8; i++) {
        const __half2* hp = (const __half2*)&raw[i];
        float2 lo = __half22float2(hp[0]);
        float2 hi = __half22float2(hp[1]);
        acc.x = fmaf(lo.x, w[i], acc.x);
        acc.y = fmaf(lo.y, w[i], acc.y);
        acc.z = fmaf(hi.x, w[i], acc.z);
        acc.w = fmaf(hi.y, w[i], acc.w);
      }
    }
    acc.x *= rh; acc.y *= rh; acc.z *= rh; acc.w *= rh;
  }
  float4 bv = *(const float4*)&bias[f0];
  float4 o;
  o.x = eluf(acc.x + bv.x);
  o.y = eluf(acc.y + bv.y);
  o.z = eluf(acc.z + bv.z);
  o.w = eluf(acc.w + bv.w);
  *(float4*)&out[(size_t)n * 128 + f0] = o;
}

// ---------------- final linear: C[N,40] = A[N,128] @ Wo[128,40] + bo ----------------
__global__ __launch_bounds__(256) void gemm_out_k(const float* __restrict__ A,
                                                  const float* __restrict__ Wo,
                                                  const float* __restrict__ bo,
                                                  float* __restrict__ C, int N) {
  __shared__ float As[64 * 132];
  __shared__ float Ws[128 * 44];
  int tid = threadIdx.x;
  int rowBase = blockIdx.x * 64;
  for (int i = tid; i < 128 * 40; i += 256) {
    int r = i / 40, c = i % 40;
    Ws[r * 44 + c] = Wo[i];
  }
#pragma unroll
  for (int j = 0; j < 8; j++) {
    int v = tid + 256 * j;
    int r = v >> 5, c4 = v & 31;
    int gr = rowBase + r;
    float4 val = (gr < N) ? ((const float4*)A)[gr * 32 + c4] : make_float4(0.f, 0.f, 0.f, 0.f);
    *(float4*)&As[r * 132 + c4 * 4] = val;
  }
  __syncthreads();
  int rg = tid >> 4, cg = tid & 15;
  if (cg < 10) {
    float acc[4][4] = {};
#pragma unroll 4
    for (int k = 0; k < 128; k++) {
      float a[4];
#pragma unroll
      for (int i = 0; i < 4; i++) a[i] = As[(rg + 16 * i) * 132 + k];
      float4 w = *(const float4*)&Ws[k * 44 + cg * 4];
#pragma unroll
      for (int i = 0; i < 4; i++) {
        acc[i][0] = fmaf(a[i], w.x, acc[i][0]);
        acc[i][1] = fmaf(a[i], w.y, acc[i][1]);
        acc[i][2] = fmaf(a[i], w.z, acc[i][2]);
        acc[i][3] = fmaf(a[i], w.w, acc[i][3]);
      }
    }
    float4 bv = *(const float4*)&bo[cg * 4];
#pragma unroll
    for (int i = 0; i < 4; i++) {
      int r = rowBase + rg + 16 * i;
      if (r < N) {
        float4 o = make_float4(acc[i][0] + bv.x, acc[i][1] + bv.y,
                               acc[i][2] + bv.z, acc[i][3] + bv.w);
        *(float4*)&C[r * 40 + cg * 4] = o;
      }
    }
  }
}

extern "C" void kernel_launch(void* const* d_in, const int* in_sizes, int n_in,
                              void* d_out, int out_size, void* d_ws, size_t ws_size,
                              hipStream_t stream) {
  const float* x    = (const float*)d_in[0];
  const int*   src  = (const int*)d_in[1];
  const int*   dst  = (const int*)d_in[2];
  const float* W1   = (const float*)d_in[3];
  const float* al1  = (const float*)d_in[4];
  const float* ar1  = (const float*)d_in[5];
  const float* b1   = (const float*)d_in[6];
  const float* W2   = (const float*)d_in[7];
  const float* al2  = (const float*)d_in[8];
  const float* ar2  = (const float*)d_in[9];
  const float* b2   = (const float*)d_in[10];
  const float* Wout = (const float*)d_in[11];
  const float* bout = (const float*)d_in[12];
  float* out = (float*)d_out;

  const int N = N_NODES, E = N_EDGES;
  size_t off = 0;
  auto alloc = [&](size_t bytes) {
    void* p = (char*)d_ws + off;
    off += (bytes + 255) & ~(size_t)255;
    return p;
  };
  __half* hh = (__half*)alloc((size_t)N * 128 * 2);
  float* o   = (float*)alloc((size_t)N * 128 * 4);
  float* el  = (float*)alloc((size_t)N * 4 * 4);
  float* er  = (float*)alloc((size_t)N * 4 * 4);
  int* rowstart   = (int*)alloc((size_t)(N + 1) * 4);
  int* H          = (int*)alloc((size_t)NB * NC * 4);
  int* colTotal   = (int*)alloc((size_t)NB * 4);
  int* bucketBase = (int*)alloc((size_t)(NB + 1) * 4);
  int* tmp        = (int*)alloc((size_t)E * 4);
  int* csr_src    = (int*)alloc((size_t)E * 4);
  (void)ws_size; (void)in_sizes; (void)n_in; (void)out_size;

  // CSR build (atomic-free counting sort)
  p1_hist<<<NC, 256, 0, stream>>>(dst, H);
  p2_colscan<<<NB, 256, 0, stream>>>(H, colTotal);
  p3_bucketscan<<<1, 512, 0, stream>>>(colTotal, bucketBase);
  p4_scatter<<<NC, 256, 0, stream>>>(src, dst, H, bucketBase, tmp);
  p5_build<<<NB, 256, 0, stream>>>(tmp, bucketBase, rowstart, csr_src);

  int gemmGrid = (N + 63) / 64;
  int outGrid  = (N + 63) / 64;
  int aggGrid = ((N + 1) / 2 * 64 + 255) / 256;      // 2 nodes per wave

  // layer 1
  gemm128_elr<<<gemmGrid, 256, 0, stream>>>(x, W1, al1, ar1, hh, el, er, N);
  agg_fused<<<aggGrid, 256, 0, stream>>>(hh, el, er, rowstart, csr_src, b1, o);

  // layer 2
  gemm128_elr<<<gemmGrid, 256, 0, stream>>>(o, W2, al2, ar2, hh, el, er, N);
  agg_fused<<<aggGrid, 256, 0, stream>>>(hh, el, er, rowstart, csr_src, b2, o);

  // output linear
  gemm_out_k<<<outGrid, 256, 0, stream>>>(o, Wout, bout, out, N);
}

// Round 9
// 353.500 us; speedup vs baseline: 3.3424x; 1.0084x over previous
//
#include <hip/hip_runtime.h>
#include <hip/hip_fp16.h>
#include <math.h>

#define N_NODES 100000
#define N_EDGES 1600000
#define NEG_SLOPE 0.2f

#define NB ((N_NODES + 255) / 256)          // 391 level-1 buckets (256 nodes each)
#define NC 256                              // edge chunks
#define CHUNK ((N_EDGES + NC - 1) / NC)     // 6250 edges per chunk

__device__ __forceinline__ float lrelu(float x) { return x > 0.f ? x : NEG_SLOPE * x; }
__device__ __forceinline__ float eluf(float x)  { return x > 0.f ? x : expm1f(x); }

// 32-lane sum (2 independent nodes per wave; xor masks stay in-half)
__device__ __forceinline__ float wred32_sum(float v) {
#pragma unroll
  for (int i = 1; i < 32; i <<= 1) v += __shfl_xor(v, i, 64);
  return v;
}

// ======== atomic-free CSR build: two-level counting sort by dst ========

__global__ __launch_bounds__(256) void p1_hist(const int* __restrict__ dst,
                                               int* __restrict__ H) {
  __shared__ int hist[NB];
  int c = blockIdx.x, t = threadIdx.x;
  for (int i = t; i < NB; i += 256) hist[i] = 0;
  __syncthreads();
  int e0 = c * CHUNK, e1 = min(e0 + CHUNK, N_EDGES);
  for (int e = e0 + t; e < e1; e += 256) atomicAdd(&hist[dst[e] >> 8], 1);
  __syncthreads();
  for (int i = t; i < NB; i += 256) H[i * NC + c] = hist[i];
}

__global__ __launch_bounds__(256) void p2_colscan(int* __restrict__ H,
                                                  int* __restrict__ colTotal) {
  __shared__ int sh[256];
  int b = blockIdx.x, t = threadIdx.x;
  int v = H[b * NC + t];
  sh[t] = v;
  __syncthreads();
  for (int off = 1; off < 256; off <<= 1) {
    int u = (t >= off) ? sh[t - off] : 0;
    __syncthreads();
    sh[t] += u;
    __syncthreads();
  }
  H[b * NC + t] = sh[t] - v;  // exclusive
  if (t == 255) colTotal[b] = sh[255];
}

__global__ __launch_bounds__(512) void p3_bucketscan(const int* __restrict__ colTotal,
                                                     int* __restrict__ bucketBase) {
  __shared__ int sh[512];
  int t = threadIdx.x;
  int v = (t < NB) ? colTotal[t] : 0;
  sh[t] = v;
  __syncthreads();
  for (int off = 1; off < 512; off <<= 1) {
    int u = (t >= off) ? sh[t - off] : 0;
    __syncthreads();
    sh[t] += u;
    __syncthreads();
  }
  if (t < NB) bucketBase[t] = sh[t] - v;
  if (t == NB - 1) bucketBase[NB] = sh[t];  // == N_EDGES
}

// tmp packs (src << 8) | (dst & 255): src < 2^24 so it fits one int
__global__ __launch_bounds__(256) void p4_scatter(const int* __restrict__ src,
                                                  const int* __restrict__ dst,
                                                  const int* __restrict__ H,
                                                  const int* __restrict__ bucketBase,
                                                  int* __restrict__ tmp) {
  __shared__ int cur[NB];
  int c = blockIdx.x, t = threadIdx.x;
  for (int i = t; i < NB; i += 256) cur[i] = bucketBase[i] + H[i * NC + c];
  __syncthreads();
  int e0 = c * CHUNK, e1 = min(e0 + CHUNK, N_EDGES);
  for (int e = e0 + t; e < e1; e += 256) {
    int d = dst[e];
    int pos = atomicAdd(&cur[d >> 8], 1);
    tmp[pos] = (src[e] << 8) | (d & 255);
  }
}

__global__ __launch_bounds__(256) void p5_build(const int* __restrict__ tmp,
                                                const int* __restrict__ bucketBase,
                                                int* __restrict__ rowstart,
                                                int* __restrict__ csr_src) {
  __shared__ int hist[256];
  __shared__ int sh[256];
  __shared__ int cur[256];
  int b = blockIdx.x, t = threadIdx.x;
  int ebase = bucketBase[b], eend = bucketBase[b + 1];
  hist[t] = 0;
  __syncthreads();
  for (int e = ebase + t; e < eend; e += 256) atomicAdd(&hist[tmp[e] & 255], 1);
  __syncthreads();
  int v = hist[t];
  sh[t] = v;
  __syncthreads();
  for (int off = 1; off < 256; off <<= 1) {
    int u = (t >= off) ? sh[t - off] : 0;
    __syncthreads();
    sh[t] += u;
    __syncthreads();
  }
  int excl = sh[t] - v;
  int node = b * 256 + t;
  if (node < N_NODES) rowstart[node] = ebase + excl;
  cur[t] = excl;
  __syncthreads();
  for (int e = ebase + t; e < eend; e += 256) {
    int p = tmp[e];
    int pos = ebase + atomicAdd(&cur[p & 255], 1);
    csr_src[pos] = p >> 8;
  }
  if (b == 0 && t == 0) rowstart[N_NODES] = N_EDGES;
}

// ======== GEMM: Chalf[N,128] = A[N,128] @ W[128,128] (fp16 out), fused el/er ========
// 64x128 tile, K-step 32: As[64][33] + Ws[32][132] ~ 26KB -> 6 blocks/CU, 1563 blocks.
__global__ __launch_bounds__(256) void gemm128_elr(const float* __restrict__ A,
                                                   const float* __restrict__ W,
                                                   const float* __restrict__ al,
                                                   const float* __restrict__ ar,
                                                   __half* __restrict__ C,
                                                   float* __restrict__ el,
                                                   float* __restrict__ er, int N) {
  __shared__ float As[64 * 33];
  __shared__ float Ws[32 * 132];
  __shared__ float als[128], ars[128];
  int tid = threadIdx.x;
  int tx = tid & 15, ty = tid >> 4;
  int rowBase = blockIdx.x * 64;

  if (tid < 128) { als[tid] = al[tid]; ars[tid] = ar[tid]; }

  float acc0[4][4] = {};
  float acc1[4][4] = {};

  const float4* A4 = (const float4*)A;
  const float4* W4 = (const float4*)W;

  for (int kc = 0; kc < 128; kc += 32) {
    __syncthreads();
#pragma unroll
    for (int i = 0; i < 2; i++) {
      int v = tid + 256 * i;        // 0..511
      int r = v >> 3, c4 = v & 7;
      int gr = rowBase + r;
      float4 val = (gr < N) ? A4[(size_t)gr * 32 + (kc >> 2) + c4]
                            : make_float4(0.f, 0.f, 0.f, 0.f);
      float* dstp = &As[r * 33 + c4 * 4];
      dstp[0] = val.x; dstp[1] = val.y; dstp[2] = val.z; dstp[3] = val.w;
    }
#pragma unroll
    for (int i = 0; i < 4; i++) {
      int v = tid + 256 * i;
      int r = v >> 5, c4 = v & 31;
      float4 val = W4[(size_t)(kc + r) * 32 + c4];
      *(float4*)&Ws[r * 132 + c4 * 4] = val;
    }
    __syncthreads();

#pragma unroll 4
    for (int k = 0; k < 32; k++) {
      float a[4];
#pragma unroll
      for (int i = 0; i < 4; i++) a[i] = As[(ty * 4 + i) * 33 + k];
      float4 w0 = *(const float4*)&Ws[k * 132 + tx * 4];
      float4 w1 = *(const float4*)&Ws[k * 132 + 64 + tx * 4];
#pragma unroll
      for (int i = 0; i < 4; i++) {
        acc0[i][0] = fmaf(a[i], w0.x, acc0[i][0]);
        acc0[i][1] = fmaf(a[i], w0.y, acc0[i][1]);
        acc0[i][2] = fmaf(a[i], w0.z, acc0[i][2]);
        acc0[i][3] = fmaf(a[i], w0.w, acc0[i][3]);
        acc1[i][0] = fmaf(a[i], w1.x, acc1[i][0]);
        acc1[i][1] = fmaf(a[i], w1.y, acc1[i][1]);
        acc1[i][2] = fmaf(a[i], w1.z, acc1[i][2]);
        acc1[i][3] = fmaf(a[i], w1.w, acc1[i][3]);
      }
    }
  }

  float alr0[4], arr0[4], alr1[4], arr1[4];
#pragma unroll
  for (int j = 0; j < 4; j++) {
    alr0[j] = als[4 * tx + j];      arr0[j] = ars[4 * tx + j];
    alr1[j] = als[64 + 4 * tx + j]; arr1[j] = ars[64 + 4 * tx + j];
  }
#pragma unroll
  for (int i = 0; i < 4; i++) {
    float pel0 = 0.f, per0 = 0.f, pel1 = 0.f, per1 = 0.f;
#pragma unroll
    for (int j = 0; j < 4; j++) {
      pel0 = fmaf(acc0[i][j], alr0[j], pel0);
      per0 = fmaf(acc0[i][j], arr0[j], per0);
      pel1 = fmaf(acc1[i][j], alr1[j], pel1);
      per1 = fmaf(acc1[i][j], arr1[j], per1);
    }
#pragma unroll
    for (int m = 1; m < 8; m <<= 1) {
      pel0 += __shfl_xor(pel0, m, 64);
      per0 += __shfl_xor(per0, m, 64);
      pel1 += __shfl_xor(pel1, m, 64);
      per1 += __shfl_xor(per1, m, 64);
    }
    int row = rowBase + ty * 4 + i;
    if (row < N) {
      __half2 p0 = __float22half2_rn(make_float2(acc0[i][0], acc0[i][1]));
      __half2 p1 = __float22half2_rn(make_float2(acc0[i][2], acc0[i][3]));
      __half2 q0 = __float22half2_rn(make_float2(acc1[i][0], acc1[i][1]));
      __half2 q1 = __float22half2_rn(make_float2(acc1[i][2], acc1[i][3]));
      float2 pk0, pk1;
      ((__half2*)&pk0)[0] = p0; ((__half2*)&pk0)[1] = p1;
      ((__half2*)&pk1)[0] = q0; ((__half2*)&pk1)[1] = q1;
      *(float2*)&C[(size_t)row * 128 + 4 * tx] = pk0;
      *(float2*)&C[(size_t)row * 128 + 64 + 4 * tx] = pk1;
      if ((tx & 7) == 0) {
        int hb = tx >> 3;
        el[row * 4 + hb] = pel0;     er[row * 4 + hb] = per0;
        el[row * 4 + 2 + hb] = pel1; er[row * 4 + 2 + hb] = per1;
      }
    }
  }
}

// ==== fused softmax+aggregation, single pass over edges ====
// 2 nodes/wave, 32 lanes/node. Per 32-edge tile: lane computes w (exp, no max
// subtraction -- scores bounded; clamp guards inf) for ONE edge, publishes
// w[32][4]+idx[32] to wave-local LDS, accumulates per-lane partial sum-of-w;
// then all lanes gather h with broadcast w/idx from LDS. Normalize at end.
__global__ __launch_bounds__(256) void agg_fused(const __half* __restrict__ h,
                                                 const float* __restrict__ el,
                                                 const float* __restrict__ er,
                                                 const int* __restrict__ rowstart,
                                                 const int* __restrict__ csr_src,
                                                 const float* __restrict__ bias,
                                                 float* __restrict__ out) {
  __shared__ float wlds[8][32][4];
  __shared__ int   ilds[8][32];
  int tid = threadIdx.x;
  int wv = (blockIdx.x * 256 + tid) >> 6;
  int lane = tid & 63;
  int half_ = lane >> 5;
  int l = lane & 31;
  int slot = ((tid >> 6) << 1) | half_;   // 0..7 node slot within block
  int n = wv * 2 + half_;
  if (n >= N_NODES) return;
  int base = rowstart[n];
  int deg = rowstart[n + 1] - base;
  int f0 = l * 4;
  int head = l >> 3;
  float4 acc = make_float4(0.f, 0.f, 0.f, 0.f);

  if (deg > 0) {
    float4 erv = *(const float4*)&er[n * 4];
    float ls0 = 0.f, ls1 = 0.f, ls2 = 0.f, ls3 = 0.f;

    for (int t0 = 0; t0 < deg; t0 += 32) {
      int e = t0 + l;
      bool act = e < deg;
      int s = act ? csr_src[base + e] : 0;
      float4 elv = *(const float4*)&el[s * 4];
      float w0 = act ? __expf(fminf(lrelu(elv.x + erv.x), 30.f)) : 0.f;
      float w1 = act ? __expf(fminf(lrelu(elv.y + erv.y), 30.f)) : 0.f;
      float w2 = act ? __expf(fminf(lrelu(elv.z + erv.z), 30.f)) : 0.f;
      float w3 = act ? __expf(fminf(lrelu(elv.w + erv.w), 30.f)) : 0.f;
      ls0 += w0; ls1 += w1; ls2 += w2; ls3 += w3;
      *(float4*)&wlds[slot][l][0] = make_float4(w0, w1, w2, w3);
      ilds[slot][l] = s;
      __builtin_amdgcn_wave_barrier();   // LDS writes visible (wave lockstep)

      int nt = min(32, deg - t0);
#pragma unroll 8
      for (int i = 0; i < nt; i++) {
        int si = ilds[slot][i];          // broadcast read
        float wi = wlds[slot][i][head];  // broadcast within 8-lane head group
        float2 raw = *(const float2*)&h[(size_t)si * 128 + f0];  // 4 halfs
        const __half2* hp = (const __half2*)&raw;
        float2 lo = __half22float2(hp[0]);
        float2 hi = __half22float2(hp[1]);
        acc.x = fmaf(lo.x, wi, acc.x);
        acc.y = fmaf(lo.y, wi, acc.y);
        acc.z = fmaf(hi.x, wi, acc.z);
        acc.w = fmaf(hi.y, wi, acc.w);
      }
      __builtin_amdgcn_wave_barrier();   // done reading before next tile's writes
    }

    float L0 = wred32_sum(ls0);
    float L1 = wred32_sum(ls1);
    float L2 = wred32_sum(ls2);
    float L3 = wred32_sum(ls3);
    float lh = (head == 0) ? L0 : (head == 1) ? L1 : (head == 2) ? L2 : L3;
    float rh = 1.f / lh;
    acc.x *= rh; acc.y *= rh; acc.z *= rh; acc.w *= rh;
  }
  float4 bv = *(const float4*)&bias[f0];
  float4 o;
  o.x = eluf(acc.x + bv.x);
  o.y = eluf(acc.y + bv.y);
  o.z = eluf(acc.z + bv.z);
  o.w = eluf(acc.w + bv.w);
  *(float4*)&out[(size_t)n * 128 + f0] = o;
}

// ---------------- final linear: C[N,40] = A[N,128] @ Wo[128,40] + bo ----------------
__global__ __launch_bounds__(256) void gemm_out_k(const float* __restrict__ A,
                                                  const float* __restrict__ Wo,
                                                  const float* __restrict__ bo,
                                                  float* __restrict__ C, int N) {
  __shared__ float As[64 * 132];
  __shared__ float Ws[128 * 44];
  int tid = threadIdx.x;
  int rowBase = blockIdx.x * 64;
  for (int i = tid; i < 128 * 40; i += 256) {
    int r = i / 40, c = i % 40;
    Ws[r * 44 + c] = Wo[i];
  }
#pragma unroll
  for (int j = 0; j < 8; j++) {
    int v = tid + 256 * j;
    int r = v >> 5, c4 = v & 31;
    int gr = rowBase + r;
    float4 val = (gr < N) ? ((const float4*)A)[gr * 32 + c4] : make_float4(0.f, 0.f, 0.f, 0.f);
    *(float4*)&As[r * 132 + c4 * 4] = val;
  }
  __syncthreads();
  int rg = tid >> 4, cg = tid & 15;
  if (cg < 10) {
    float acc[4][4] = {};
#pragma unroll 4
    for (int k = 0; k < 128; k++) {
      float a[4];
#pragma unroll
      for (int i = 0; i < 4; i++) a[i] = As[(rg + 16 * i) * 132 + k];
      float4 w = *(const float4*)&Ws[k * 44 + cg * 4];
#pragma unroll
      for (int i = 0; i < 4; i++) {
        acc[i][0] = fmaf(a[i], w.x, acc[i][0]);
        acc[i][1] = fmaf(a[i], w.y, acc[i][1]);
        acc[i][2] = fmaf(a[i], w.z, acc[i][2]);
        acc[i][3] = fmaf(a[i], w.w, acc[i][3]);
      }
    }
    float4 bv = *(const float4*)&bo[cg * 4];
#pragma unroll
    for (int i = 0; i < 4; i++) {
      int r = rowBase + rg + 16 * i;
      if (r < N) {
        float4 o = make_float4(acc[i][0] + bv.x, acc[i][1] + bv.y,
                               acc[i][2] + bv.z, acc[i][3] + bv.w);
        *(float4*)&C[r * 40 + cg * 4] = o;
      }
    }
  }
}

extern "C" void kernel_launch(void* const* d_in, const int* in_sizes, int n_in,
                              void* d_out, int out_size, void* d_ws, size_t ws_size,
                              hipStream_t stream) {
  const float* x    = (const float*)d_in[0];
  const int*   src  = (const int*)d_in[1];
  const int*   dst  = (const int*)d_in[2];
  const float* W1   = (const float*)d_in[3];
  const float* al1  = (const float*)d_in[4];
  const float* ar1  = (const float*)d_in[5];
  const float* b1   = (const float*)d_in[6];
  const float* W2   = (const float*)d_in[7];
  const float* al2  = (const float*)d_in[8];
  const float* ar2  = (const float*)d_in[9];
  const float* b2   = (const float*)d_in[10];
  const float* Wout = (const float*)d_in[11];
  const float* bout = (const float*)d_in[12];
  float* out = (float*)d_out;

  const int N = N_NODES, E = N_EDGES;
  size_t off = 0;
  auto alloc = [&](size_t bytes) {
    void* p = (char*)d_ws + off;
    off += (bytes + 255) & ~(size_t)255;
    return p;
  };
  __half* hh = (__half*)alloc((size_t)N * 128 * 2);
  float* o   = (float*)alloc((size_t)N * 128 * 4);
  float* el  = (float*)alloc((size_t)N * 4 * 4);
  float* er  = (float*)alloc((size_t)N * 4 * 4);
  int* rowstart   = (int*)alloc((size_t)(N + 1) * 4);
  int* H          = (int*)alloc((size_t)NB * NC * 4);
  int* colTotal   = (int*)alloc((size_t)NB * 4);
  int* bucketBase = (int*)alloc((size_t)(NB + 1) * 4);
  int* tmp        = (int*)alloc((size_t)E * 4);
  int* csr_src    = (int*)alloc((size_t)E * 4);
  (void)ws_size; (void)in_sizes; (void)n_in; (void)out_size;

  // CSR build (atomic-free counting sort)
  p1_hist<<<NC, 256, 0, stream>>>(dst, H);
  p2_colscan<<<NB, 256, 0, stream>>>(H, colTotal);
  p3_bucketscan<<<1, 512, 0, stream>>>(colTotal, bucketBase);
  p4_scatter<<<NC, 256, 0, stream>>>(src, dst, H, bucketBase, tmp);
  p5_build<<<NB, 256, 0, stream>>>(tmp, bucketBase, rowstart, csr_src);

  int gemmGrid = (N + 63) / 64;
  int outGrid  = (N + 63) / 64;
  int aggGrid = ((N + 1) / 2 * 64 + 255) / 256;      // 2 nodes per wave

  // layer 1
  gemm128_elr<<<gemmGrid, 256, 0, stream>>>(x, W1, al1, ar1, hh, el, er, N);
  agg_fused<<<aggGrid, 256, 0, stream>>>(hh, el, er, rowstart, csr_src, b1, o);

  // layer 2
  gemm128_elr<<<gemmGrid, 256, 0, stream>>>(o, W2, al2, ar2, hh, el, er, N);
  agg_fused<<<aggGrid, 256, 0, stream>>>(hh, el, er, rowstart, csr_src, b2, o);

  // output linear
  gemm_out_k<<<outGrid, 256, 0, stream>>>(o, Wout, bout, out, N);
}

// Round 10
// 337.570 us; speedup vs baseline: 3.5002x; 1.0472x over previous
//
#include <hip/hip_runtime.h>
#include <hip/hip_fp16.h>
#include <math.h>

#define N_NODES 100000
#define N_EDGES 1600000
#define NEG_SLOPE 0.2f

#define NB ((N_NODES + 255) / 256)          // 391 level-1 buckets (256 nodes each)
#define NC 256                              // edge chunks
#define CHUNK ((N_EDGES + NC - 1) / NC)     // 6250 edges per chunk

__device__ __forceinline__ float lrelu(float x) { return x > 0.f ? x : NEG_SLOPE * x; }
__device__ __forceinline__ float eluf(float x)  { return x > 0.f ? x : expm1f(x); }

// ======== atomic-free CSR build: two-level counting sort by dst ========

__global__ __launch_bounds__(256) void p1_hist(const int* __restrict__ dst,
                                               int* __restrict__ H) {
  __shared__ int hist[NB];
  int c = blockIdx.x, t = threadIdx.x;
  for (int i = t; i < NB; i += 256) hist[i] = 0;
  __syncthreads();
  int e0 = c * CHUNK, e1 = min(e0 + CHUNK, N_EDGES);
  for (int e = e0 + t; e < e1; e += 256) atomicAdd(&hist[dst[e] >> 8], 1);
  __syncthreads();
  for (int i = t; i < NB; i += 256) H[i * NC + c] = hist[i];
}

__global__ __launch_bounds__(256) void p2_colscan(int* __restrict__ H,
                                                  int* __restrict__ colTotal) {
  __shared__ int sh[256];
  int b = blockIdx.x, t = threadIdx.x;
  int v = H[b * NC + t];
  sh[t] = v;
  __syncthreads();
  for (int off = 1; off < 256; off <<= 1) {
    int u = (t >= off) ? sh[t - off] : 0;
    __syncthreads();
    sh[t] += u;
    __syncthreads();
  }
  H[b * NC + t] = sh[t] - v;  // exclusive
  if (t == 255) colTotal[b] = sh[255];
}

__global__ __launch_bounds__(512) void p3_bucketscan(const int* __restrict__ colTotal,
                                                     int* __restrict__ bucketBase) {
  __shared__ int sh[512];
  int t = threadIdx.x;
  int v = (t < NB) ? colTotal[t] : 0;
  sh[t] = v;
  __syncthreads();
  for (int off = 1; off < 512; off <<= 1) {
    int u = (t >= off) ? sh[t - off] : 0;
    __syncthreads();
    sh[t] += u;
    __syncthreads();
  }
  if (t < NB) bucketBase[t] = sh[t] - v;
  if (t == NB - 1) bucketBase[NB] = sh[t];  // == N_EDGES
}

// tmp packs (src << 8) | (dst & 255): src < 2^24 so it fits one int
__global__ __launch_bounds__(256) void p4_scatter(const int* __restrict__ src,
                                                  const int* __restrict__ dst,
                                                  const int* __restrict__ H,
                                                  const int* __restrict__ bucketBase,
                                                  int* __restrict__ tmp) {
  __shared__ int cur[NB];
  int c = blockIdx.x, t = threadIdx.x;
  for (int i = t; i < NB; i += 256) cur[i] = bucketBase[i] + H[i * NC + c];
  __syncthreads();
  int e0 = c * CHUNK, e1 = min(e0 + CHUNK, N_EDGES);
  for (int e = e0 + t; e < e1; e += 256) {
    int d = dst[e];
    int pos = atomicAdd(&cur[d >> 8], 1);
    tmp[pos] = (src[e] << 8) | (d & 255);
  }
}

__global__ __launch_bounds__(256) void p5_build(const int* __restrict__ tmp,
                                                const int* __restrict__ bucketBase,
                                                int* __restrict__ rowstart,
                                                int* __restrict__ csr_src) {
  __shared__ int hist[256];
  __shared__ int sh[256];
  __shared__ int cur[256];
  int b = blockIdx.x, t = threadIdx.x;
  int ebase = bucketBase[b], eend = bucketBase[b + 1];
  hist[t] = 0;
  __syncthreads();
  for (int e = ebase + t; e < eend; e += 256) atomicAdd(&hist[tmp[e] & 255], 1);
  __syncthreads();
  int v = hist[t];
  sh[t] = v;
  __syncthreads();
  for (int off = 1; off < 256; off <<= 1) {
    int u = (t >= off) ? sh[t - off] : 0;
    __syncthreads();
    sh[t] += u;
    __syncthreads();
  }
  int excl = sh[t] - v;
  int node = b * 256 + t;
  if (node < N_NODES) rowstart[node] = ebase + excl;
  cur[t] = excl;
  __syncthreads();
  for (int e = ebase + t; e < eend; e += 256) {
    int p = tmp[e];
    int pos = ebase + atomicAdd(&cur[p & 255], 1);
    csr_src[pos] = p >> 8;
  }
  if (b == 0 && t == 0) rowstart[N_NODES] = N_EDGES;
}

// ======== GEMM: Chalf[N,128] = A[N,128] @ W[128,128] (fp16 out), fused el/er ========
// 64x128 tile, K-step 32: As[64][33] + Ws[32][132] ~ 26KB -> 6 blocks/CU, 1563 blocks.
__global__ __launch_bounds__(256) void gemm128_elr(const float* __restrict__ A,
                                                   const float* __restrict__ W,
                                                   const float* __restrict__ al,
                                                   const float* __restrict__ ar,
                                                   __half* __restrict__ C,
                                                   float* __restrict__ el,
                                                   float* __restrict__ er, int N) {
  __shared__ float As[64 * 33];
  __shared__ float Ws[32 * 132];
  __shared__ float als[128], ars[128];
  int tid = threadIdx.x;
  int tx = tid & 15, ty = tid >> 4;
  int rowBase = blockIdx.x * 64;

  if (tid < 128) { als[tid] = al[tid]; ars[tid] = ar[tid]; }

  float acc0[4][4] = {};
  float acc1[4][4] = {};

  const float4* A4 = (const float4*)A;
  const float4* W4 = (const float4*)W;

  for (int kc = 0; kc < 128; kc += 32) {
    __syncthreads();
#pragma unroll
    for (int i = 0; i < 2; i++) {
      int v = tid + 256 * i;        // 0..511
      int r = v >> 3, c4 = v & 7;
      int gr = rowBase + r;
      float4 val = (gr < N) ? A4[(size_t)gr * 32 + (kc >> 2) + c4]
                            : make_float4(0.f, 0.f, 0.f, 0.f);
      float* dstp = &As[r * 33 + c4 * 4];
      dstp[0] = val.x; dstp[1] = val.y; dstp[2] = val.z; dstp[3] = val.w;
    }
#pragma unroll
    for (int i = 0; i < 4; i++) {
      int v = tid + 256 * i;
      int r = v >> 5, c4 = v & 31;
      float4 val = W4[(size_t)(kc + r) * 32 + c4];
      *(float4*)&Ws[r * 132 + c4 * 4] = val;
    }
    __syncthreads();

#pragma unroll 4
    for (int k = 0; k < 32; k++) {
      float a[4];
#pragma unroll
      for (int i = 0; i < 4; i++) a[i] = As[(ty * 4 + i) * 33 + k];
      float4 w0 = *(const float4*)&Ws[k * 132 + tx * 4];
      float4 w1 = *(const float4*)&Ws[k * 132 + 64 + tx * 4];
#pragma unroll
      for (int i = 0; i < 4; i++) {
        acc0[i][0] = fmaf(a[i], w0.x, acc0[i][0]);
        acc0[i][1] = fmaf(a[i], w0.y, acc0[i][1]);
        acc0[i][2] = fmaf(a[i], w0.z, acc0[i][2]);
        acc0[i][3] = fmaf(a[i], w0.w, acc0[i][3]);
        acc1[i][0] = fmaf(a[i], w1.x, acc1[i][0]);
        acc1[i][1] = fmaf(a[i], w1.y, acc1[i][1]);
        acc1[i][2] = fmaf(a[i], w1.z, acc1[i][2]);
        acc1[i][3] = fmaf(a[i], w1.w, acc1[i][3]);
      }
    }
  }

  float alr0[4], arr0[4], alr1[4], arr1[4];
#pragma unroll
  for (int j = 0; j < 4; j++) {
    alr0[j] = als[4 * tx + j];      arr0[j] = ars[4 * tx + j];
    alr1[j] = als[64 + 4 * tx + j]; arr1[j] = ars[64 + 4 * tx + j];
  }
#pragma unroll
  for (int i = 0; i < 4; i++) {
    float pel0 = 0.f, per0 = 0.f, pel1 = 0.f, per1 = 0.f;
#pragma unroll
    for (int j = 0; j < 4; j++) {
      pel0 = fmaf(acc0[i][j], alr0[j], pel0);
      per0 = fmaf(acc0[i][j], arr0[j], per0);
      pel1 = fmaf(acc1[i][j], alr1[j], pel1);
      per1 = fmaf(acc1[i][j], arr1[j], per1);
    }
#pragma unroll
    for (int m = 1; m < 8; m <<= 1) {
      pel0 += __shfl_xor(pel0, m, 64);
      per0 += __shfl_xor(per0, m, 64);
      pel1 += __shfl_xor(pel1, m, 64);
      per1 += __shfl_xor(per1, m, 64);
    }
    int row = rowBase + ty * 4 + i;
    if (row < N) {
      __half2 p0 = __float22half2_rn(make_float2(acc0[i][0], acc0[i][1]));
      __half2 p1 = __float22half2_rn(make_float2(acc0[i][2], acc0[i][3]));
      __half2 q0 = __float22half2_rn(make_float2(acc1[i][0], acc1[i][1]));
      __half2 q1 = __float22half2_rn(make_float2(acc1[i][2], acc1[i][3]));
      float2 pk0, pk1;
      ((__half2*)&pk0)[0] = p0; ((__half2*)&pk0)[1] = p1;
      ((__half2*)&pk1)[0] = q0; ((__half2*)&pk1)[1] = q1;
      *(float2*)&C[(size_t)row * 128 + 4 * tx] = pk0;
      *(float2*)&C[(size_t)row * 128 + 64 + 4 * tx] = pk1;
      if ((tx & 7) == 0) {
        int hb = tx >> 3;
        el[row * 4 + hb] = pel0;     er[row * 4 + hb] = per0;
        el[row * 4 + 2 + hb] = pel1; er[row * 4 + 2 + hb] = per1;
      }
    }
  }
}

// ==== fused softmax+aggregation v3: 4 nodes/wave, 16 lanes x 8 fp16 feats ====
// Per 16-edge tile: lane computes w (exp, clamp-guarded, no max subtraction)
// for ONE edge, publishes w[16][4]+idx[16] to wave-local LDS; then all lanes
// gather h rows (16B/lane) with broadcast w/idx and accumulate, summing the
// denominator per lane inline (no cross-lane reduction). Normalize at end.
__global__ __launch_bounds__(256) void agg_fused(const __half* __restrict__ h,
                                                 const float* __restrict__ el,
                                                 const float* __restrict__ er,
                                                 const int* __restrict__ rowstart,
                                                 const int* __restrict__ csr_src,
                                                 const float* __restrict__ bias,
                                                 float* __restrict__ out) {
  __shared__ float wlds[16][17][4];   // slot stride 68 floats: conflict-free reads
  __shared__ int   ilds[16][17];
  int tid = threadIdx.x;
  int slot = tid >> 4;                // 0..15 node slot within block
  int l = tid & 15;                   // lane within node group
  int n = blockIdx.x * 16 + slot;
  if (n >= N_NODES) return;
  int base = rowstart[n];
  int deg = rowstart[n + 1] - base;
  int f0 = l * 8;                     // 8 fp16 features per lane
  int head = l >> 2;                  // f0/32
  float acc[8] = {};
  float lsum = 0.f;

  if (deg > 0) {
    float4 erv = *(const float4*)&er[n * 4];

    for (int t0 = 0; t0 < deg; t0 += 16) {
      int e = t0 + l;
      bool act = e < deg;
      int s = act ? csr_src[base + e] : 0;
      float4 elv = *(const float4*)&el[s * 4];
      float w0 = act ? __expf(fminf(lrelu(elv.x + erv.x), 30.f)) : 0.f;
      float w1 = act ? __expf(fminf(lrelu(elv.y + erv.y), 30.f)) : 0.f;
      float w2 = act ? __expf(fminf(lrelu(elv.z + erv.z), 30.f)) : 0.f;
      float w3 = act ? __expf(fminf(lrelu(elv.w + erv.w), 30.f)) : 0.f;
      *(float4*)&wlds[slot][l][0] = make_float4(w0, w1, w2, w3);
      ilds[slot][l] = s;
      __builtin_amdgcn_wave_barrier();   // LDS writes visible (wave lockstep)

      int nt = min(16, deg - t0);
#pragma unroll 4
      for (int i = 0; i < nt; i++) {
        int si = ilds[slot][i];          // broadcast read
        float wi = wlds[slot][i][head];  // broadcast within 4-lane head group
        lsum += wi;
        float4 raw = *(const float4*)&h[(size_t)si * 128 + f0];  // 8 halfs
        const __half2* hp = (const __half2*)&raw;
        float2 c0 = __half22float2(hp[0]);
        float2 c1 = __half22float2(hp[1]);
        float2 c2 = __half22float2(hp[2]);
        float2 c3 = __half22float2(hp[3]);
        acc[0] = fmaf(c0.x, wi, acc[0]); acc[1] = fmaf(c0.y, wi, acc[1]);
        acc[2] = fmaf(c1.x, wi, acc[2]); acc[3] = fmaf(c1.y, wi, acc[3]);
        acc[4] = fmaf(c2.x, wi, acc[4]); acc[5] = fmaf(c2.y, wi, acc[5]);
        acc[6] = fmaf(c3.x, wi, acc[6]); acc[7] = fmaf(c3.y, wi, acc[7]);
      }
      __builtin_amdgcn_wave_barrier();   // done reading before next tile's writes
    }
    float rh = 1.f / lsum;
#pragma unroll
    for (int j = 0; j < 8; j++) acc[j] *= rh;
  }
  float4 b0 = *(const float4*)&bias[f0];
  float4 b1 = *(const float4*)&bias[f0 + 4];
  float4 o0, o1;
  o0.x = eluf(acc[0] + b0.x); o0.y = eluf(acc[1] + b0.y);
  o0.z = eluf(acc[2] + b0.z); o0.w = eluf(acc[3] + b0.w);
  o1.x = eluf(acc[4] + b1.x); o1.y = eluf(acc[5] + b1.y);
  o1.z = eluf(acc[6] + b1.z); o1.w = eluf(acc[7] + b1.w);
  *(float4*)&out[(size_t)n * 128 + f0] = o0;
  *(float4*)&out[(size_t)n * 128 + f0 + 4] = o1;
}

// ---------------- final linear: C[N,40] = A[N,128] @ Wo[128,40] + bo ----------------
__global__ __launch_bounds__(256) void gemm_out_k(const float* __restrict__ A,
                                                  const float* __restrict__ Wo,
                                                  const float* __restrict__ bo,
                                                  float* __restrict__ C, int N) {
  __shared__ float As[64 * 132];
  __shared__ float Ws[128 * 44];
  int tid = threadIdx.x;
  int rowBase = blockIdx.x * 64;
  for (int i = tid; i < 128 * 40; i += 256) {
    int r = i / 40, c = i % 40;
    Ws[r * 44 + c] = Wo[i];
  }
#pragma unroll
  for (int j = 0; j < 8; j++) {
    int v = tid + 256 * j;
    int r = v >> 5, c4 = v & 31;
    int gr = rowBase + r;
    float4 val = (gr < N) ? ((const float4*)A)[gr * 32 + c4] : make_float4(0.f, 0.f, 0.f, 0.f);
    *(float4*)&As[r * 132 + c4 * 4] = val;
  }
  __syncthreads();
  int rg = tid >> 4, cg = tid & 15;
  if (cg < 10) {
    float acc[4][4] = {};
#pragma unroll 4
    for (int k = 0; k < 128; k++) {
      float a[4];
#pragma unroll
      for (int i = 0; i < 4; i++) a[i] = As[(rg + 16 * i) * 132 + k];
      float4 w = *(const float4*)&Ws[k * 44 + cg * 4];
#pragma unroll
      for (int i = 0; i < 4; i++) {
        acc[i][0] = fmaf(a[i], w.x, acc[i][0]);
        acc[i][1] = fmaf(a[i], w.y, acc[i][1]);
        acc[i][2] = fmaf(a[i], w.z, acc[i][2]);
        acc[i][3] = fmaf(a[i], w.w, acc[i][3]);
      }
    }
    float4 bv = *(const float4*)&bo[cg * 4];
#pragma unroll
    for (int i = 0; i < 4; i++) {
      int r = rowBase + rg + 16 * i;
      if (r < N) {
        float4 o = make_float4(acc[i][0] + bv.x, acc[i][1] + bv.y,
                               acc[i][2] + bv.z, acc[i][3] + bv.w);
        *(float4*)&C[r * 40 + cg * 4] = o;
      }
    }
  }
}

extern "C" void kernel_launch(void* const* d_in, const int* in_sizes, int n_in,
                              void* d_out, int out_size, void* d_ws, size_t ws_size,
                              hipStream_t stream) {
  const float* x    = (const float*)d_in[0];
  const int*   src  = (const int*)d_in[1];
  const int*   dst  = (const int*)d_in[2];
  const float* W1   = (const float*)d_in[3];
  const float* al1  = (const float*)d_in[4];
  const float* ar1  = (const float*)d_in[5];
  const float* b1   = (const float*)d_in[6];
  const float* W2   = (const float*)d_in[7];
  const float* al2  = (const float*)d_in[8];
  const float* ar2  = (const float*)d_in[9];
  const float* b2   = (const float*)d_in[10];
  const float* Wout = (const float*)d_in[11];
  const float* bout = (const float*)d_in[12];
  float* out = (float*)d_out;

  const int N = N_NODES, E = N_EDGES;
  size_t off = 0;
  auto alloc = [&](size_t bytes) {
    void* p = (char*)d_ws + off;
    off += (bytes + 255) & ~(size_t)255;
    return p;
  };
  __half* hh = (__half*)alloc((size_t)N * 128 * 2);
  float* o   = (float*)alloc((size_t)N * 128 * 4);
  float* el  = (float*)alloc((size_t)N * 4 * 4);
  float* er  = (float*)alloc((size_t)N * 4 * 4);
  int* rowstart   = (int*)alloc((size_t)(N + 1) * 4);
  int* H          = (int*)alloc((size_t)NB * NC * 4);
  int* colTotal   = (int*)alloc((size_t)NB * 4);
  int* bucketBase = (int*)alloc((size_t)(NB + 1) * 4);
  int* tmp        = (int*)alloc((size_t)E * 4);
  int* csr_src    = (int*)alloc((size_t)E * 4);
  (void)ws_size; (void)in_sizes; (void)n_in; (void)out_size;

  // CSR build (atomic-free counting sort)
  p1_hist<<<NC, 256, 0, stream>>>(dst, H);
  p2_colscan<<<NB, 256, 0, stream>>>(H, colTotal);
  p3_bucketscan<<<1, 512, 0, stream>>>(colTotal, bucketBase);
  p4_scatter<<<NC, 256, 0, stream>>>(src, dst, H, bucketBase, tmp);
  p5_build<<<NB, 256, 0, stream>>>(tmp, bucketBase, rowstart, csr_src);

  int gemmGrid = (N + 63) / 64;
  int outGrid  = (N + 63) / 64;
  int aggGrid  = (N + 15) / 16;      // 16 nodes per 256-thread block

  // layer 1
  gemm128_elr<<<gemmGrid, 256, 0, stream>>>(x, W1, al1, ar1, hh, el, er, N);
  agg_fused<<<aggGrid, 256, 0, stream>>>(hh, el, er, rowstart, csr_src, b1, o);

  // layer 2
  gemm128_elr<<<gemmGrid, 256, 0, stream>>>(o, W2, al2, ar2, hh, el, er, N);
  agg_fused<<<aggGrid, 256, 0, stream>>>(hh, el, er, rowstart, csr_src, b2, o);

  // output linear
  gemm_out_k<<<outGrid, 256, 0, stream>>>(o, Wout, bout, out, N);
}

// Round 11
// 323.391 us; speedup vs baseline: 3.6536x; 1.0438x over previous
//
#include <hip/hip_runtime.h>
#include <hip/hip_fp16.h>
#include <math.h>

#define N_NODES 100000
#define N_EDGES 1600000
#define NEG_SLOPE 0.2f

#define NB ((N_NODES + 255) / 256)          // 391 level-1 buckets (256 nodes each)
#define NC 256                              // edge chunks
#define CHUNK ((N_EDGES + NC - 1) / NC)     // 6250 edges per chunk

__device__ __forceinline__ float lrelu(float x) { return x > 0.f ? x : NEG_SLOPE * x; }
__device__ __forceinline__ float eluf(float x)  { return x > 0.f ? x : expm1f(x); }

// ======== atomic-free CSR build: two-level counting sort by dst ========

__global__ __launch_bounds__(256) void p1_hist(const int* __restrict__ dst,
                                               int* __restrict__ H) {
  __shared__ int hist[NB];
  int c = blockIdx.x, t = threadIdx.x;
  for (int i = t; i < NB; i += 256) hist[i] = 0;
  __syncthreads();
  int e0 = c * CHUNK, e1 = min(e0 + CHUNK, N_EDGES);
  for (int e = e0 + t; e < e1; e += 256) atomicAdd(&hist[dst[e] >> 8], 1);
  __syncthreads();
  for (int i = t; i < NB; i += 256) H[i * NC + c] = hist[i];
}

__global__ __launch_bounds__(256) void p2_colscan(int* __restrict__ H,
                                                  int* __restrict__ colTotal) {
  __shared__ int sh[256];
  int b = blockIdx.x, t = threadIdx.x;
  int v = H[b * NC + t];
  sh[t] = v;
  __syncthreads();
  for (int off = 1; off < 256; off <<= 1) {
    int u = (t >= off) ? sh[t - off] : 0;
    __syncthreads();
    sh[t] += u;
    __syncthreads();
  }
  H[b * NC + t] = sh[t] - v;  // exclusive
  if (t == 255) colTotal[b] = sh[255];
}

__global__ __launch_bounds__(512) void p3_bucketscan(const int* __restrict__ colTotal,
                                                     int* __restrict__ bucketBase) {
  __shared__ int sh[512];
  int t = threadIdx.x;
  int v = (t < NB) ? colTotal[t] : 0;
  sh[t] = v;
  __syncthreads();
  for (int off = 1; off < 512; off <<= 1) {
    int u = (t >= off) ? sh[t - off] : 0;
    __syncthreads();
    sh[t] += u;
    __syncthreads();
  }
  if (t < NB) bucketBase[t] = sh[t] - v;
  if (t == NB - 1) bucketBase[NB] = sh[t];  // == N_EDGES
}

// tmp packs (src << 8) | (dst & 255): src < 2^24 so it fits one int
__global__ __launch_bounds__(256) void p4_scatter(const int* __restrict__ src,
                                                  const int* __restrict__ dst,
                                                  const int* __restrict__ H,
                                                  const int* __restrict__ bucketBase,
                                                  int* __restrict__ tmp) {
  __shared__ int cur[NB];
  int c = blockIdx.x, t = threadIdx.x;
  for (int i = t; i < NB; i += 256) cur[i] = bucketBase[i] + H[i * NC + c];
  __syncthreads();
  int e0 = c * CHUNK, e1 = min(e0 + CHUNK, N_EDGES);
  for (int e = e0 + t; e < e1; e += 256) {
    int d = dst[e];
    int pos = atomicAdd(&cur[d >> 8], 1);
    tmp[pos] = (src[e] << 8) | (d & 255);
  }
}

__global__ __launch_bounds__(256) void p5_build(const int* __restrict__ tmp,
                                                const int* __restrict__ bucketBase,
                                                int* __restrict__ rowstart,
                                                int* __restrict__ csr_src) {
  __shared__ int hist[256];
  __shared__ int sh[256];
  __shared__ int cur[256];
  int b = blockIdx.x, t = threadIdx.x;
  int ebase = bucketBase[b], eend = bucketBase[b + 1];
  hist[t] = 0;
  __syncthreads();
  for (int e = ebase + t; e < eend; e += 256) atomicAdd(&hist[tmp[e] & 255], 1);
  __syncthreads();
  int v = hist[t];
  sh[t] = v;
  __syncthreads();
  for (int off = 1; off < 256; off <<= 1) {
    int u = (t >= off) ? sh[t - off] : 0;
    __syncthreads();
    sh[t] += u;
    __syncthreads();
  }
  int excl = sh[t] - v;
  int node = b * 256 + t;
  if (node < N_NODES) rowstart[node] = ebase + excl;
  cur[t] = excl;
  __syncthreads();
  for (int e = ebase + t; e < eend; e += 256) {
    int p = tmp[e];
    int pos = ebase + atomicAdd(&cur[p & 255], 1);
    csr_src[pos] = p >> 8;
  }
  if (b == 0 && t == 0) rowstart[N_NODES] = N_EDGES;
}

// ======== GEMM: Chalf[N,128] = A[N,128] @ W[128,128] (fp16 out), fused el/er ========
// 64x128 tile, K-step 32: As[64][33] + Ws[32][132] ~ 26KB -> 6 blocks/CU.
// FP16IN: A rows are fp16 (layer-2 input); staged+converted to fp32 LDS.
template <bool FP16IN>
__global__ __launch_bounds__(256) void gemm128_elr(const void* __restrict__ Av,
                                                   const float* __restrict__ W,
                                                   const float* __restrict__ al,
                                                   const float* __restrict__ ar,
                                                   __half* __restrict__ C,
                                                   float* __restrict__ el,
                                                   float* __restrict__ er, int N) {
  __shared__ float As[64 * 33];
  __shared__ float Ws[32 * 132];
  __shared__ float als[128], ars[128];
  int tid = threadIdx.x;
  int tx = tid & 15, ty = tid >> 4;
  int rowBase = blockIdx.x * 64;

  if (tid < 128) { als[tid] = al[tid]; ars[tid] = ar[tid]; }

  float acc0[4][4] = {};
  float acc1[4][4] = {};

  const float4* W4 = (const float4*)W;

  for (int kc = 0; kc < 128; kc += 32) {
    __syncthreads();
    if constexpr (FP16IN) {
      // one float4 = 8 halfs per thread: 64 rows x 32 cols
      const __half* A = (const __half*)Av;
      int r = tid >> 2, c8 = (tid & 3) * 8;
      int gr = min(rowBase + r, N - 1);
      float4 raw = *(const float4*)&A[(size_t)gr * 128 + kc + c8];
      const __half2* hp = (const __half2*)&raw;
      float2 f0 = __half22float2(hp[0]);
      float2 f1 = __half22float2(hp[1]);
      float2 f2 = __half22float2(hp[2]);
      float2 f3 = __half22float2(hp[3]);
      float* dstp = &As[r * 33 + c8];
      dstp[0] = f0.x; dstp[1] = f0.y; dstp[2] = f1.x; dstp[3] = f1.y;
      dstp[4] = f2.x; dstp[5] = f2.y; dstp[6] = f3.x; dstp[7] = f3.y;
    } else {
      const float4* A4 = (const float4*)Av;
#pragma unroll
      for (int i = 0; i < 2; i++) {
        int v = tid + 256 * i;        // 0..511
        int r = v >> 3, c4 = v & 7;
        int gr = min(rowBase + r, N - 1);
        float4 val = A4[(size_t)gr * 32 + (kc >> 2) + c4];
        float* dstp = &As[r * 33 + c4 * 4];
        dstp[0] = val.x; dstp[1] = val.y; dstp[2] = val.z; dstp[3] = val.w;
      }
    }
#pragma unroll
    for (int i = 0; i < 4; i++) {
      int v = tid + 256 * i;
      int r = v >> 5, c4 = v & 31;
      float4 val = W4[(size_t)(kc + r) * 32 + c4];
      *(float4*)&Ws[r * 132 + c4 * 4] = val;
    }
    __syncthreads();

#pragma unroll 4
    for (int k = 0; k < 32; k++) {
      float a[4];
#pragma unroll
      for (int i = 0; i < 4; i++) a[i] = As[(ty * 4 + i) * 33 + k];
      float4 w0 = *(const float4*)&Ws[k * 132 + tx * 4];
      float4 w1 = *(const float4*)&Ws[k * 132 + 64 + tx * 4];
#pragma unroll
      for (int i = 0; i < 4; i++) {
        acc0[i][0] = fmaf(a[i], w0.x, acc0[i][0]);
        acc0[i][1] = fmaf(a[i], w0.y, acc0[i][1]);
        acc0[i][2] = fmaf(a[i], w0.z, acc0[i][2]);
        acc0[i][3] = fmaf(a[i], w0.w, acc0[i][3]);
        acc1[i][0] = fmaf(a[i], w1.x, acc1[i][0]);
        acc1[i][1] = fmaf(a[i], w1.y, acc1[i][1]);
        acc1[i][2] = fmaf(a[i], w1.z, acc1[i][2]);
        acc1[i][3] = fmaf(a[i], w1.w, acc1[i][3]);
      }
    }
  }

  float alr0[4], arr0[4], alr1[4], arr1[4];
#pragma unroll
  for (int j = 0; j < 4; j++) {
    alr0[j] = als[4 * tx + j];      arr0[j] = ars[4 * tx + j];
    alr1[j] = als[64 + 4 * tx + j]; arr1[j] = ars[64 + 4 * tx + j];
  }
#pragma unroll
  for (int i = 0; i < 4; i++) {
    float pel0 = 0.f, per0 = 0.f, pel1 = 0.f, per1 = 0.f;
#pragma unroll
    for (int j = 0; j < 4; j++) {
      pel0 = fmaf(acc0[i][j], alr0[j], pel0);
      per0 = fmaf(acc0[i][j], arr0[j], per0);
      pel1 = fmaf(acc1[i][j], alr1[j], pel1);
      per1 = fmaf(acc1[i][j], arr1[j], per1);
    }
#pragma unroll
    for (int m = 1; m < 8; m <<= 1) {
      pel0 += __shfl_xor(pel0, m, 64);
      per0 += __shfl_xor(per0, m, 64);
      pel1 += __shfl_xor(pel1, m, 64);
      per1 += __shfl_xor(per1, m, 64);
    }
    int row = rowBase + ty * 4 + i;
    if (row < N) {
      __half2 p0 = __float22half2_rn(make_float2(acc0[i][0], acc0[i][1]));
      __half2 p1 = __float22half2_rn(make_float2(acc0[i][2], acc0[i][3]));
      __half2 q0 = __float22half2_rn(make_float2(acc1[i][0], acc1[i][1]));
      __half2 q1 = __float22half2_rn(make_float2(acc1[i][2], acc1[i][3]));
      float2 pk0, pk1;
      ((__half2*)&pk0)[0] = p0; ((__half2*)&pk0)[1] = p1;
      ((__half2*)&pk1)[0] = q0; ((__half2*)&pk1)[1] = q1;
      *(float2*)&C[(size_t)row * 128 + 4 * tx] = pk0;
      *(float2*)&C[(size_t)row * 128 + 64 + 4 * tx] = pk1;
      if ((tx & 7) == 0) {
        int hb = tx >> 3;
        el[row * 4 + hb] = pel0;     er[row * 4 + hb] = per0;
        el[row * 4 + 2 + hb] = pel1; er[row * 4 + 2 + hb] = per1;
      }
    }
  }
}

// ==== fused softmax+aggregation: 4 nodes/wave, 16 lanes x 8 fp16 feats ====
// fp16 output (ELU applied then packed): halves write + downstream reads.
__global__ __launch_bounds__(256) void agg_fused(const __half* __restrict__ h,
                                                 const float* __restrict__ el,
                                                 const float* __restrict__ er,
                                                 const int* __restrict__ rowstart,
                                                 const int* __restrict__ csr_src,
                                                 const float* __restrict__ bias,
                                                 __half* __restrict__ out) {
  __shared__ float wlds[16][17][4];   // slot stride 68 floats: conflict-free reads
  __shared__ int   ilds[16][17];
  int tid = threadIdx.x;
  int slot = tid >> 4;                // 0..15 node slot within block
  int l = tid & 15;                   // lane within node group
  int n = blockIdx.x * 16 + slot;
  if (n >= N_NODES) return;
  int base = rowstart[n];
  int deg = rowstart[n + 1] - base;
  int f0 = l * 8;                     // 8 fp16 features per lane
  int head = l >> 2;                  // f0/32
  float acc[8] = {};
  float lsum = 0.f;

  if (deg > 0) {
    float4 erv = *(const float4*)&er[n * 4];

    for (int t0 = 0; t0 < deg; t0 += 16) {
      int e = t0 + l;
      bool act = e < deg;
      int s = act ? csr_src[base + e] : 0;
      float4 elv = *(const float4*)&el[s * 4];
      float w0 = act ? __expf(fminf(lrelu(elv.x + erv.x), 30.f)) : 0.f;
      float w1 = act ? __expf(fminf(lrelu(elv.y + erv.y), 30.f)) : 0.f;
      float w2 = act ? __expf(fminf(lrelu(elv.z + erv.z), 30.f)) : 0.f;
      float w3 = act ? __expf(fminf(lrelu(elv.w + erv.w), 30.f)) : 0.f;
      *(float4*)&wlds[slot][l][0] = make_float4(w0, w1, w2, w3);
      ilds[slot][l] = s;
      __builtin_amdgcn_wave_barrier();   // LDS writes visible (wave lockstep)

      int nt = min(16, deg - t0);
#pragma unroll 4
      for (int i = 0; i < nt; i++) {
        int si = ilds[slot][i];          // broadcast read
        float wi = wlds[slot][i][head];  // broadcast within 4-lane head group
        lsum += wi;
        float4 raw = *(const float4*)&h[(size_t)si * 128 + f0];  // 8 halfs
        const __half2* hp = (const __half2*)&raw;
        float2 c0 = __half22float2(hp[0]);
        float2 c1 = __half22float2(hp[1]);
        float2 c2 = __half22float2(hp[2]);
        float2 c3 = __half22float2(hp[3]);
        acc[0] = fmaf(c0.x, wi, acc[0]); acc[1] = fmaf(c0.y, wi, acc[1]);
        acc[2] = fmaf(c1.x, wi, acc[2]); acc[3] = fmaf(c1.y, wi, acc[3]);
        acc[4] = fmaf(c2.x, wi, acc[4]); acc[5] = fmaf(c2.y, wi, acc[5]);
        acc[6] = fmaf(c3.x, wi, acc[6]); acc[7] = fmaf(c3.y, wi, acc[7]);
      }
      __builtin_amdgcn_wave_barrier();   // done reading before next tile's writes
    }
    float rh = 1.f / lsum;
#pragma unroll
    for (int j = 0; j < 8; j++) acc[j] *= rh;
  }
  float4 b0 = *(const float4*)&bias[f0];
  float4 b1 = *(const float4*)&bias[f0 + 4];
  float r0 = eluf(acc[0] + b0.x), r1 = eluf(acc[1] + b0.y);
  float r2 = eluf(acc[2] + b0.z), r3 = eluf(acc[3] + b0.w);
  float r4 = eluf(acc[4] + b1.x), r5 = eluf(acc[5] + b1.y);
  float r6 = eluf(acc[6] + b1.z), r7 = eluf(acc[7] + b1.w);
  __half2 pk[4];
  pk[0] = __float22half2_rn(make_float2(r0, r1));
  pk[1] = __float22half2_rn(make_float2(r2, r3));
  pk[2] = __float22half2_rn(make_float2(r4, r5));
  pk[3] = __float22half2_rn(make_float2(r6, r7));
  *(float4*)&out[(size_t)n * 128 + f0] = *(float4*)pk;   // 8 halfs = 16 B
}

// ---------------- final linear: C[N,40] = Ahalf[N,128] @ Wo[128,40] + bo ----------------
__global__ __launch_bounds__(256) void gemm_out_k(const __half* __restrict__ A,
                                                  const float* __restrict__ Wo,
                                                  const float* __restrict__ bo,
                                                  float* __restrict__ C, int N) {
  __shared__ float As[64 * 132];
  __shared__ float Ws[128 * 44];
  int tid = threadIdx.x;
  int rowBase = blockIdx.x * 64;
  for (int i = tid; i < 128 * 40; i += 256) {
    int r = i / 40, c = i % 40;
    Ws[r * 44 + c] = Wo[i];
  }
  // stage 64 rows x 128 cols of fp16 A -> fp32 LDS: 4 x (8 halfs) per thread
#pragma unroll
  for (int j = 0; j < 4; j++) {
    int v = tid + 256 * j;            // 0..1023
    int r = v >> 4, c8 = (v & 15) * 8;
    int gr = min(rowBase + r, N - 1);
    float4 raw = *(const float4*)&A[(size_t)gr * 128 + c8];
    const __half2* hp = (const __half2*)&raw;
    float2 f0 = __half22float2(hp[0]);
    float2 f1 = __half22float2(hp[1]);
    float2 f2 = __half22float2(hp[2]);
    float2 f3 = __half22float2(hp[3]);
    float* dstp = &As[r * 132 + c8];
    dstp[0] = f0.x; dstp[1] = f0.y; dstp[2] = f1.x; dstp[3] = f1.y;
    dstp[4] = f2.x; dstp[5] = f2.y; dstp[6] = f3.x; dstp[7] = f3.y;
  }
  __syncthreads();
  int rg = tid >> 4, cg = tid & 15;
  if (cg < 10) {
    float acc[4][4] = {};
#pragma unroll 4
    for (int k = 0; k < 128; k++) {
      float a[4];
#pragma unroll
      for (int i = 0; i < 4; i++) a[i] = As[(rg + 16 * i) * 132 + k];
      float4 w = *(const float4*)&Ws[k * 44 + cg * 4];
#pragma unroll
      for (int i = 0; i < 4; i++) {
        acc[i][0] = fmaf(a[i], w.x, acc[i][0]);
        acc[i][1] = fmaf(a[i], w.y, acc[i][1]);
        acc[i][2] = fmaf(a[i], w.z, acc[i][2]);
        acc[i][3] = fmaf(a[i], w.w, acc[i][3]);
      }
    }
    float4 bv = *(const float4*)&bo[cg * 4];
#pragma unroll
    for (int i = 0; i < 4; i++) {
      int r = rowBase + rg + 16 * i;
      if (r < N) {
        float4 o = make_float4(acc[i][0] + bv.x, acc[i][1] + bv.y,
                               acc[i][2] + bv.z, acc[i][3] + bv.w);
        *(float4*)&C[r * 40 + cg * 4] = o;
      }
    }
  }
}

extern "C" void kernel_launch(void* const* d_in, const int* in_sizes, int n_in,
                              void* d_out, int out_size, void* d_ws, size_t ws_size,
                              hipStream_t stream) {
  const float* x    = (const float*)d_in[0];
  const int*   src  = (const int*)d_in[1];
  const int*   dst  = (const int*)d_in[2];
  const float* W1   = (const float*)d_in[3];
  const float* al1  = (const float*)d_in[4];
  const float* ar1  = (const float*)d_in[5];
  const float* b1   = (const float*)d_in[6];
  const float* W2   = (const float*)d_in[7];
  const float* al2  = (const float*)d_in[8];
  const float* ar2  = (const float*)d_in[9];
  const float* b2   = (const float*)d_in[10];
  const float* Wout = (const float*)d_in[11];
  const float* bout = (const float*)d_in[12];
  float* out = (float*)d_out;

  const int N = N_NODES, E = N_EDGES;
  size_t off = 0;
  auto alloc = [&](size_t bytes) {
    void* p = (char*)d_ws + off;
    off += (bytes + 255) & ~(size_t)255;
    return p;
  };
  __half* hh  = (__half*)alloc((size_t)N * 128 * 2);
  __half* o16 = (__half*)alloc((size_t)N * 128 * 2);
  float* el  = (float*)alloc((size_t)N * 4 * 4);
  float* er  = (float*)alloc((size_t)N * 4 * 4);
  int* rowstart   = (int*)alloc((size_t)(N + 1) * 4);
  int* H          = (int*)alloc((size_t)NB * NC * 4);
  int* colTotal   = (int*)alloc((size_t)NB * 4);
  int* bucketBase = (int*)alloc((size_t)(NB + 1) * 4);
  int* tmp        = (int*)alloc((size_t)E * 4);
  int* csr_src    = (int*)alloc((size_t)E * 4);
  (void)ws_size; (void)in_sizes; (void)n_in; (void)out_size;

  // CSR build (atomic-free counting sort)
  p1_hist<<<NC, 256, 0, stream>>>(dst, H);
  p2_colscan<<<NB, 256, 0, stream>>>(H, colTotal);
  p3_bucketscan<<<1, 512, 0, stream>>>(colTotal, bucketBase);
  p4_scatter<<<NC, 256, 0, stream>>>(src, dst, H, bucketBase, tmp);
  p5_build<<<NB, 256, 0, stream>>>(tmp, bucketBase, rowstart, csr_src);

  int gemmGrid = (N + 63) / 64;
  int outGrid  = (N + 63) / 64;
  int aggGrid  = (N + 15) / 16;      // 16 nodes per 256-thread block

  // layer 1 (fp32 input x)
  gemm128_elr<false><<<gemmGrid, 256, 0, stream>>>(x, W1, al1, ar1, hh, el, er, N);
  agg_fused<<<aggGrid, 256, 0, stream>>>(hh, el, er, rowstart, csr_src, b1, o16);

  // layer 2 (fp16 input o16)
  gemm128_elr<true><<<gemmGrid, 256, 0, stream>>>(o16, W2, al2, ar2, hh, el, er, N);
  agg_fused<<<aggGrid, 256, 0, stream>>>(hh, el, er, rowstart, csr_src, b2, o16);

  // output linear (fp16 input)
  gemm_out_k<<<outGrid, 256, 0, stream>>>(o16, Wout, bout, out, N);
}